// Round 9
// baseline (1543.960 us; speedup 1.0000x reference)
//
#include <hip/hip_runtime.h>

// ---------------------------------------------------------------------------
// SimplicialAttentionTransformer: 3 streams x (embed-add, 2x[QKV gemm,
// CSR-ordered edge scores (+fused max partials), GLOBAL softmax over edges,
// CSR segment-sum, proj gemm, LN], head gemm). bf16 residual stream (no f32
// X buffer). bf16 MFMA GEMM: 256x256 tile, 8 waves (wave-tile 128x64),
// 2-phase-per-K-tile schedule, double-buffered global_load_lds staging
// (XOR-swizzled source), raw s_barrier phases, setprio around MFMA clusters,
// swapped-operand MFMA + permuted weights -> 16 consecutive cols/lane.
// ---------------------------------------------------------------------------

typedef __attribute__((ext_vector_type(8))) __bf16 bf16x8;
typedef __attribute__((ext_vector_type(4))) float f32x4;
typedef __attribute__((ext_vector_type(8))) unsigned short ushort8v;
typedef __attribute__((ext_vector_type(4))) unsigned short ushort4v;

__device__ __forceinline__ float b2f(unsigned short u) {
  union { unsigned u; float f; } x; x.u = (unsigned)u << 16; return x.f;
}
__device__ __forceinline__ unsigned short f2b(float f) {
  union { float f; unsigned u; } x; x.f = f;
  unsigned r = x.u + 0x7fffu + ((x.u >> 16) & 1u);   // RNE
  return (unsigned short)(r >> 16);
}

// ======================= xb = bf16(a + b + c) ==============================
__global__ __launch_bounds__(256) void init_x_kernel(
    const float4* __restrict__ a, const float4* __restrict__ b,
    const float4* __restrict__ c, unsigned short* __restrict__ xb,
    long long n4)
{
  long long stride = (long long)gridDim.x * 256;
  for (long long i = (long long)blockIdx.x * 256 + threadIdx.x; i < n4; i += stride) {
    float4 av = a[i], bv = b[i], cv = c[i];
    ushort4v o;
    o.x = f2b(av.x + bv.x + cv.x); o.y = f2b(av.y + bv.y + cv.y);
    o.z = f2b(av.z + bv.z + cv.z); o.w = f2b(av.w + bv.w + cv.w);
    *(ushort4v*)(xb + i * 4) = o;
  }
}

// ============== weight transpose fp32[512][512] -> bf16 WT[perm(c)][r] =====
// perm swaps bits [5:4] <-> [3:2] within each 64-col block (involution).
__global__ __launch_bounds__(256) void transpose_w_kernel(
    const float* __restrict__ W, unsigned short* __restrict__ WT)
{
  __shared__ float t[32][33];
  const float* src = W + (size_t)blockIdx.z * 262144;
  unsigned short* dst = WT + (size_t)blockIdx.z * 262144;
  int bx = blockIdx.x * 32, by = blockIdx.y * 32;
  int tx = threadIdx.x, ty = threadIdx.y;   // block 32x8
  #pragma unroll
  for (int i = 0; i < 32; i += 8)
    t[ty + i][tx] = src[(size_t)(by + ty + i) * 512 + bx + tx];
  __syncthreads();
  #pragma unroll
  for (int i = 0; i < 32; i += 8) {
    int c = bx + ty + i;
    int p = (c & ~0x3C) | ((c & 0x30) >> 2) | ((c & 0x0C) << 2);
    dst[(size_t)p * 512 + by + tx] = f2b(t[tx][ty + i]);
  }
}

// ========================== bf16 GEMM:  C = A @ WTs^T + bias ===============
__device__ __forceinline__ void stage16(const void* g, void* lds_uniform) {
  __builtin_amdgcn_global_load_lds(
      (const __attribute__((address_space(1))) void*)g,
      (__attribute__((address_space(3))) void*)lds_uniform, 16, 0, 0);
}

template<int OUT_BF16>
__global__ __launch_bounds__(512, 2) void gemm_bt_kernel(
    const unsigned short* __restrict__ A,
    const unsigned short* __restrict__ BT,
    const float* __restrict__ bias,
    void* __restrict__ Cv,
    int M, int Ncols)
{
  constexpr int K = 512;
  // 128KB: buf b at shorts [b*32768, +16384)=A(256x64), [+16384,+32768)=B
  __shared__ unsigned short smem[65536];

  // bijective XCD-chunked swizzle (m204)
  const int nwg = gridDim.x, orig = blockIdx.x;
  const int xcd = orig & 7, lin = orig >> 3;
  const int q = nwg >> 3, r8 = nwg & 7;
  const int wgid = (xcd < r8 ? xcd * (q + 1) : r8 * (q + 1) + (xcd - r8) * q) + lin;

  const int tiles_n = Ncols >> 8;
  const int tm = wgid / tiles_n;
  const int tn = wgid - tm * tiles_n;
  const int row0 = tm << 8, col0 = tn << 8;
  const int lane = threadIdx.x & 63, wid = threadIdx.x >> 6;
  const int wr = (wid >> 2) << 7;   // M-half: 0 / 128
  const int wc = (wid & 3) << 6;    // N-quarter: 0/64/128/192

  f32x4 acc[8][4];
  #pragma unroll
  for (int i = 0; i < 8; ++i)
    #pragma unroll
    for (int j = 0; j < 4; ++j) acc[i][j] = (f32x4)0.f;

  // staging plan: 32 segs of 1KB per operand; wave owns segs (i<<3)|wid.
  int srow[4], scsw[4], sseg[4];
  #pragma unroll
  for (int i = 0; i < 4; ++i) {
    int seg = (i << 3) | wid;
    int idx = (seg << 6) | lane;     // row = idx>>3 (0..255), chunk = idx&7
    int row = idx >> 3, ch = idx & 7;
    sseg[i] = seg; srow[i] = row; scsw[i] = ch ^ (row & 7);  // pre-swizzled src
  }

  #define STG_PAIR(buf, kb_, i)                                               \
    { int ra = row0 + srow[i]; ra = (ra < M) ? ra : (M - 1);                  \
      stage16(A + (size_t)ra * K + (kb_) + (scsw[i] << 3),                    \
              smem + (buf) * 32768 + (sseg[i] << 9));                         \
      int rb = col0 + srow[i];                                                \
      stage16(BT + (size_t)rb * K + (kb_) + (scsw[i] << 3),                   \
              smem + (buf) * 32768 + 16384 + (sseg[i] << 9)); }

  STG_PAIR(0, 0, 0) STG_PAIR(0, 0, 1) STG_PAIR(0, 0, 2) STG_PAIR(0, 0, 3)
  __syncthreads();

  const int lm = lane & 15;
  const int kbl = (lane >> 4) << 4;

  #pragma unroll
  for (int kt = 0; kt < 8; ++kt) {
    const int cur = kt & 1, nxt = cur ^ 1, kb1 = (kt + 1) << 6;
    const char* Asb = (const char*)(smem + cur * 32768);
    const char* Bsb = Asb + 32768;   // bytes

    auto rdA = [&](int mi, int kk) -> bf16x8 {
      int r = wr + (mi << 4) + lm;
      int kb = (kk << 6) + kbl;
      return *(const bf16x8*)(Asb + (r << 7) + (kb ^ ((r & 7) << 4)));
    };
    auto rdB = [&](int ni, int kk) -> bf16x8 {
      int r = wc + (ni << 4) + lm;
      int kb = (kk << 6) + kbl;
      return *(const bf16x8*)(Bsb + (r << 7) + (kb ^ ((r & 7) << 4)));
    };

    bf16x8 av[8], bv[4];

    // ---- phase A (kk=0): 12 ds_reads, stage pairs 0,1 of t+1, 32 MFMA
    #pragma unroll
    for (int i = 0; i < 8; ++i) av[i] = rdA(i, 0);
    #pragma unroll
    for (int i = 0; i < 4; ++i) bv[i] = rdB(i, 0);
    if (kt < 7) { STG_PAIR(nxt, kb1, 0) STG_PAIR(nxt, kb1, 1) }
    __builtin_amdgcn_s_barrier();
    __builtin_amdgcn_s_setprio(1);
    #pragma unroll
    for (int mi = 0; mi < 8; ++mi)
      #pragma unroll
      for (int ni = 0; ni < 4; ++ni)
        acc[mi][ni] = __builtin_amdgcn_mfma_f32_16x16x32_bf16(
            bv[ni], av[mi], acc[mi][ni], 0, 0, 0);
    __builtin_amdgcn_s_setprio(0);
    __builtin_amdgcn_s_barrier();

    // ---- phase B (kk=1): 12 ds_reads, stage pairs 2,3 of t+1, 32 MFMA
    #pragma unroll
    for (int i = 0; i < 8; ++i) av[i] = rdA(i, 1);
    #pragma unroll
    for (int i = 0; i < 4; ++i) bv[i] = rdB(i, 1);
    if (kt < 7) { STG_PAIR(nxt, kb1, 2) STG_PAIR(nxt, kb1, 3) }
    __builtin_amdgcn_s_barrier();
    __builtin_amdgcn_s_setprio(1);
    #pragma unroll
    for (int mi = 0; mi < 8; ++mi)
      #pragma unroll
      for (int ni = 0; ni < 4; ++ni)
        acc[mi][ni] = __builtin_amdgcn_mfma_f32_16x16x32_bf16(
            bv[ni], av[mi], acc[mi][ni], 0, 0, 0);
    __builtin_amdgcn_s_setprio(0);

    // K-tile boundary: drain (t+1 landed; everyone done reading cur)
    __syncthreads();
  }
  #undef STG_PAIR

  const int mrow = lane & 15;
  const int t4 = (lane >> 4) << 4;       // lane's orig-col base within 64
  float bsv[16];
  #pragma unroll
  for (int ni = 0; ni < 4; ++ni) {
    float4 bvv = *(const float4*)(bias + col0 + wc + t4 + (ni << 2));
    bsv[4*ni+0] = bvv.x; bsv[4*ni+1] = bvv.y; bsv[4*ni+2] = bvv.z; bsv[4*ni+3] = bvv.w;
  }

  if (OUT_BF16) {
    unsigned short* C = (unsigned short*)Cv;
    #pragma unroll
    for (int mi = 0; mi < 8; ++mi) {
      int rowg = row0 + wr + (mi << 4) + mrow;
      if (rowg < M) {
        ushort8v o0, o1;
        #pragma unroll
        for (int r = 0; r < 4; ++r) {
          o0[r]     = f2b(acc[mi][0][r] + bsv[r]);
          o0[4 + r] = f2b(acc[mi][1][r] + bsv[4 + r]);
          o1[r]     = f2b(acc[mi][2][r] + bsv[8 + r]);
          o1[4 + r] = f2b(acc[mi][3][r] + bsv[12 + r]);
        }
        unsigned short* cp = C + (size_t)rowg * Ncols + col0 + wc + t4;
        *(ushort8v*)cp = o0;
        *(ushort8v*)(cp + 8) = o1;
      }
    }
  } else {
    float* C = (float*)Cv;
    #pragma unroll
    for (int mi = 0; mi < 8; ++mi) {
      int rowg = row0 + wr + (mi << 4) + mrow;
      if (rowg < M) {
        float* cp = C + (size_t)rowg * Ncols + col0 + wc + t4;
        #pragma unroll
        for (int ni = 0; ni < 4; ++ni) {
          float4 v;
          v.x = acc[mi][ni][0] + bsv[4*ni+0];
          v.y = acc[mi][ni][1] + bsv[4*ni+1];
          v.z = acc[mi][ni][2] + bsv[4*ni+2];
          v.w = acc[mi][ni][3] + bsv[4*ni+3];
          *(float4*)(cp + (ni << 2)) = v;
        }
      }
    }
  }
}

// ====== CSR-ordered edge scores + fused per-wave max partials ==============
// One wave per dst node n: q[n] in regs, k gathered per in-edge; xor-reduce
// broadcasts each score to all 8 lanes of a head group, so a running max is
// tracked for free. Empty/out-of-range waves emit -1e30 (safe: the global
// softmax shift is invariant to the exact shift value).
__global__ __launch_bounds__(256) void csr_scores_kernel(
    const unsigned short* __restrict__ qkv, const int* __restrict__ srcs,
    const int* __restrict__ rowptr, int N, float* __restrict__ sc,
    float* __restrict__ partm)
{
  int wid = threadIdx.x >> 6, lane = threadIdx.x & 63;
  int n = (blockIdx.x << 2) | wid;
  float mx = -1e30f;
  if (n < N) {
    int beg = rowptr[n], end = rowptr[n + 1];
    if (beg < end) {
      ushort8v qv = *(const ushort8v*)(qkv + (size_t)n * 1536 + (lane << 3));
      float qf[8];
      #pragma unroll
      for (int j = 0; j < 8; ++j) qf[j] = b2f(qv[j]);
      int i = beg;
      for (; i + 2 <= end; i += 2) {       // 2-edge ILP
        int s0 = srcs[i], s1 = srcs[i + 1];
        ushort8v k0 = *(const ushort8v*)(qkv + (size_t)s0 * 1536 + 512 + (lane << 3));
        ushort8v k1 = *(const ushort8v*)(qkv + (size_t)s1 * 1536 + 512 + (lane << 3));
        float p0 = 0.f, p1 = 0.f;
        #pragma unroll
        for (int j = 0; j < 8; ++j) { p0 += qf[j] * b2f(k0[j]); p1 += qf[j] * b2f(k1[j]); }
        p0 += __shfl_xor(p0, 1); p1 += __shfl_xor(p1, 1);
        p0 += __shfl_xor(p0, 2); p1 += __shfl_xor(p1, 2);
        p0 += __shfl_xor(p0, 4); p1 += __shfl_xor(p1, 4);
        p0 *= 0.125f; p1 *= 0.125f;
        mx = fmaxf(mx, fmaxf(p0, p1));
        if (!(lane & 7)) {
          sc[(size_t)i * 8 + (lane >> 3)] = p0;
          sc[(size_t)(i + 1) * 8 + (lane >> 3)] = p1;
        }
      }
      if (i < end) {
        int s0 = srcs[i];
        ushort8v k0 = *(const ushort8v*)(qkv + (size_t)s0 * 1536 + 512 + (lane << 3));
        float p0 = 0.f;
        #pragma unroll
        for (int j = 0; j < 8; ++j) p0 += qf[j] * b2f(k0[j]);
        p0 += __shfl_xor(p0, 1);
        p0 += __shfl_xor(p0, 2);
        p0 += __shfl_xor(p0, 4);
        p0 *= 0.125f;
        mx = fmaxf(mx, p0);
        if (!(lane & 7)) sc[(size_t)i * 8 + (lane >> 3)] = p0;
      }
    }
  }
  if (!(lane & 7))
    partm[(((size_t)blockIdx.x << 2) | wid) * 8 + (lane >> 3)] = mx;
}

// ==================== global softmax over edge axis (per head) ==============
template<int OP>   // 0 = max, 1 = sum
__device__ __forceinline__ void reduce8_block(float (&v)[8], float* red) {
  int lane = threadIdx.x & 63, wid = threadIdx.x >> 6;
  #pragma unroll
  for (int h = 0; h < 8; ++h)
    #pragma unroll
    for (int off = 1; off < 64; off <<= 1) {
      float o = __shfl_xor(v[h], off);
      v[h] = OP ? (v[h] + o) : fmaxf(v[h], o);
    }
  if (lane == 0) {
    #pragma unroll
    for (int h = 0; h < 8; ++h) red[h * 4 + wid] = v[h];
  }
  __syncthreads();
  if (threadIdx.x == 0) {
    #pragma unroll
    for (int h = 0; h < 8; ++h) {
      float r = red[h * 4];
      #pragma unroll
      for (int w = 1; w < 4; ++w)
        r = OP ? (r + red[h * 4 + w]) : fmaxf(r, red[h * 4 + w]);
      v[h] = r;
    }
  }
}

// reduce per-wave max partials (nslots x 8) -> gmax[8]; single block
__global__ __launch_bounds__(256) void gmax_kernel(
    const float* __restrict__ partm, int nslots, float* __restrict__ gmax)
{
  __shared__ float red[32];
  float v[8];
  #pragma unroll
  for (int h = 0; h < 8; ++h) v[h] = -1e30f;
  for (int i = threadIdx.x; i < nslots; i += 256) {
    #pragma unroll
    for (int h = 0; h < 8; ++h) v[h] = fmaxf(v[h], partm[(size_t)i * 8 + h]);
  }
  reduce8_block<0>(v, red);
  if (threadIdx.x == 0) {
    #pragma unroll
    for (int h = 0; h < 8; ++h) gmax[h] = v[h];
  }
}

// exp pass: w = exp(sc - gmax) in place; per-block sums -> parts
__global__ __launch_bounds__(256) void sm_exp_partial_kernel(
    float* __restrict__ sc, int E, const float* __restrict__ gmax,
    float* __restrict__ parts)
{
  __shared__ float red[32];
  float gm[8], v[8];
  #pragma unroll
  for (int h = 0; h < 8; ++h) { gm[h] = gmax[h]; v[h] = 0.f; }
  int stride = gridDim.x * 256;
  for (int e = blockIdx.x * 256 + threadIdx.x; e < E; e += stride) {
    #pragma unroll
    for (int h = 0; h < 8; ++h) {
      float w = __expf(sc[(size_t)e * 8 + h] - gm[h]);
      sc[(size_t)e * 8 + h] = w;           // in-place exp
      v[h] += w;
    }
  }
  reduce8_block<1>(v, red);
  if (threadIdx.x == 0) {
    #pragma unroll
    for (int h = 0; h < 8; ++h) parts[blockIdx.x * 8 + h] = v[h];
  }
}

template<int OP>   // 1: out = 1/sum
__global__ __launch_bounds__(256) void sm_final_kernel(
    const float* __restrict__ part, float* __restrict__ out)
{
  __shared__ float red[32];
  float v[8];
  #pragma unroll
  for (int h = 0; h < 8; ++h) v[h] = part[threadIdx.x * 8 + h];
  reduce8_block<OP>(v, red);
  if (threadIdx.x == 0) {
    #pragma unroll
    for (int h = 0; h < 8; ++h) out[h] = OP ? (1.0f / v[h]) : v[h];
  }
}

// =============================== CSR build ==================================
__global__ __launch_bounds__(256) void hist_kernel(
    const int* __restrict__ ei, int E, int* __restrict__ deg)
{
  int e = blockIdx.x * 256 + threadIdx.x;
  if (e < E) atomicAdd(&deg[ei[E + e]], 1);
}

__global__ __launch_bounds__(1024) void scan_part_kernel(
    const int* __restrict__ deg, int N, int* __restrict__ rowptr,
    int* __restrict__ bsums)
{
  __shared__ int wsum[16];
  int i = blockIdx.x * 1024 + threadIdx.x;
  int lane = threadIdx.x & 63, wid = threadIdx.x >> 6;
  int sv = (i < N) ? deg[i] : 0;
  #pragma unroll
  for (int off = 1; off < 64; off <<= 1) {
    int t = __shfl_up(sv, off);
    if (lane >= off) sv += t;
  }
  if (lane == 63) wsum[wid] = sv;
  __syncthreads();
  if (threadIdx.x < 16) {
    int ws = wsum[threadIdx.x];
    #pragma unroll
    for (int off = 1; off < 16; off <<= 1) {
      int t = __shfl_up(ws, off);
      if (threadIdx.x >= off) ws += t;
    }
    wsum[threadIdx.x] = ws;
  }
  __syncthreads();
  if (wid > 0) sv += wsum[wid - 1];
  if (i < N) rowptr[i + 1] = sv;
  if (threadIdx.x == 1023) bsums[blockIdx.x] = sv;
}

__global__ __launch_bounds__(64) void scan_bsums_kernel(int* bsums, int nb)
{
  int lane = threadIdx.x;
  int v = (lane < nb) ? bsums[lane] : 0;
  #pragma unroll
  for (int off = 1; off < 64; off <<= 1) {
    int t = __shfl_up(v, off);
    if (lane >= off) v += t;
  }
  int ex = __shfl_up(v, 1);
  if (lane == 0) ex = 0;
  if (lane < nb) bsums[lane] = ex;     // exclusive offsets, in place
}

__global__ __launch_bounds__(1024) void scan_add_kernel(
    int* __restrict__ rowptr, const int* __restrict__ bsums, int N)
{
  int i = blockIdx.x * 1024 + threadIdx.x;
  if (i == 0) rowptr[0] = 0;
  if (i < N && blockIdx.x > 0) rowptr[i + 1] += bsums[blockIdx.x];
}

__global__ __launch_bounds__(256) void scatter_kernel(
    const int* __restrict__ ei, int E, const int* __restrict__ rowptr,
    int* __restrict__ cur, int* __restrict__ srcs)
{
  int e = blockIdx.x * 256 + threadIdx.x;
  if (e < E) {
    int dst = ei[E + e];
    int pos = atomicAdd(&cur[dst], 1);
    srcs[rowptr[dst] + pos] = ei[e];
  }
}

// ====== aggregate: agg[n] = sum_{i in CSR(n)} w[i,h] * v[srcs[i]] ==========
__global__ __launch_bounds__(256) void aggregate_kernel(
    const unsigned short* __restrict__ qkv, const float* __restrict__ wexp,
    const float* __restrict__ ginv, const int* __restrict__ srcs,
    const int* __restrict__ rowptr, int N, unsigned short* __restrict__ agg)
{
  int wid = threadIdx.x >> 6, lane = threadIdx.x & 63;
  int n = (blockIdx.x << 2) | wid;
  if (n >= N) return;
  int beg = rowptr[n], end = rowptr[n + 1];
  int h = lane >> 3;
  float inv = ginv[h];
  float acc[8] = {0.f,0.f,0.f,0.f,0.f,0.f,0.f,0.f};
  int i = beg;
  for (; i + 4 <= end; i += 4) {       // 4-edge ILP
    int s0 = srcs[i], s1 = srcs[i + 1], s2 = srcs[i + 2], s3 = srcs[i + 3];
    float w0 = wexp[(size_t)i * 8 + h] * inv;
    float w1 = wexp[(size_t)(i + 1) * 8 + h] * inv;
    float w2 = wexp[(size_t)(i + 2) * 8 + h] * inv;
    float w3 = wexp[(size_t)(i + 3) * 8 + h] * inv;
    ushort8v v0 = *(const ushort8v*)(qkv + (size_t)s0 * 1536 + 1024 + (lane << 3));
    ushort8v v1 = *(const ushort8v*)(qkv + (size_t)s1 * 1536 + 1024 + (lane << 3));
    ushort8v v2 = *(const ushort8v*)(qkv + (size_t)s2 * 1536 + 1024 + (lane << 3));
    ushort8v v3 = *(const ushort8v*)(qkv + (size_t)s3 * 1536 + 1024 + (lane << 3));
    #pragma unroll
    for (int j = 0; j < 8; ++j)
      acc[j] += (w0 * b2f(v0[j]) + w1 * b2f(v1[j]))
              + (w2 * b2f(v2[j]) + w3 * b2f(v3[j]));
  }
  for (; i < end; ++i) {
    int s0 = srcs[i];
    float w0 = wexp[(size_t)i * 8 + h] * inv;
    ushort8v v0 = *(const ushort8v*)(qkv + (size_t)s0 * 1536 + 1024 + (lane << 3));
    #pragma unroll
    for (int j = 0; j < 8; ++j) acc[j] += w0 * b2f(v0[j]);
  }
  ushort8v o;
  #pragma unroll
  for (int j = 0; j < 8; ++j) o[j] = f2b(acc[j]);
  *(ushort8v*)(agg + (size_t)n * 512 + (lane << 3)) = o;
}

// ============== LN(proj + resid)*g + bt, bf16 residual (wave/row) ==========
__global__ __launch_bounds__(256) void ln_kernel(
    const unsigned short* __restrict__ proj, const float* __restrict__ g,
    const float* __restrict__ bt, unsigned short* __restrict__ xb, int N)
{
  int wid = threadIdx.x >> 6, lane = threadIdx.x & 63;
  int n = (blockIdx.x << 2) | wid;
  if (n >= N) return;
  size_t base = (size_t)n * 512 + (lane << 3);
  ushort8v pv = *(const ushort8v*)(proj + base);
  ushort8v xv = *(const ushort8v*)(xb + base);
  float y[8];
  #pragma unroll
  for (int j = 0; j < 8; ++j) y[j] = b2f(pv[j]) + b2f(xv[j]);
  float s = 0.f;
  #pragma unroll
  for (int j = 0; j < 8; ++j) s += y[j];
  #pragma unroll
  for (int off = 1; off < 64; off <<= 1) s += __shfl_xor(s, off);
  float mean = s * (1.f / 512.f);
  float vs = 0.f;
  #pragma unroll
  for (int j = 0; j < 8; ++j) { float d = y[j] - mean; vs += d * d; }
  #pragma unroll
  for (int off = 1; off < 64; off <<= 1) vs += __shfl_xor(vs, off);
  float rstd = rsqrtf(vs * (1.f / 512.f) + 1e-5f);
  int gi = lane << 3;
  ushort8v ob;
  #pragma unroll
  for (int j = 0; j < 8; ++j)
    ob[j] = f2b((y[j] - mean) * rstd * g[gi + j] + bt[gi + j]);
  *(ushort8v*)(xb + base) = ob;
}

// ================================ driver ====================================
extern "C" void kernel_launch(void* const* d_in, const int* in_sizes, int n_in,
                              void* d_out, int out_size, void* d_ws, size_t ws_size,
                              hipStream_t stream)
{
  (void)n_in; (void)out_size;
  const float* feat[3] = {(const float*)d_in[0], (const float*)d_in[1], (const float*)d_in[2]};
  const float* emb[3]  = {(const float*)d_in[3], (const float*)d_in[4], (const float*)d_in[5]};
  const float* pos[3]  = {(const float*)d_in[6], (const float*)d_in[7], (const float*)d_in[8]};
  const float* W[3]  = {(const float*)d_in[9],  (const float*)d_in[13], (const float*)d_in[17]};
  const float* Bb[3] = {(const float*)d_in[10], (const float*)d_in[14], (const float*)d_in[18]};
  const float* G[3]  = {(const float*)d_in[11], (const float*)d_in[15], (const float*)d_in[19]};
  const float* Bt[3] = {(const float*)d_in[12], (const float*)d_in[16], (const float*)d_in[20]};
  const float* headW = (const float*)d_in[21];
  const float* headB = (const float*)d_in[22];
  const int* ei[3] = {(const int*)d_in[23], (const int*)d_in[24], (const int*)d_in[25]};

  int Ns[3], Es[3];
  for (int s = 0; s < 3; ++s) { Ns[s] = in_sizes[s] / 512; Es[s] = in_sizes[23 + s] / 2; }
  int NMAX = Ns[0], EMAX = Es[0];
  for (int s = 1; s < 3; ++s) { if (Ns[s] > NMAX) NMAX = Ns[s]; if (Es[s] > EMAX) EMAX = Es[s]; }

  char* base = (char*)d_ws;
  size_t off = 0;
  auto carve = [&](size_t bytes) -> char* {
    char* r = base + off;
    off += (bytes + 255) & ~(size_t)255;
    return r;
  };
  unsigned short* WT  = (unsigned short*)carve((size_t)27 * 262144 * 2);
  unsigned short* XB  = (unsigned short*)carve((size_t)NMAX * 512 * 2);
  unsigned short* QKV = (unsigned short*)carve((size_t)NMAX * 1536 * 2);
  float*          SC  = (float*)carve((size_t)EMAX * 8 * 4);
  unsigned short* AGG = (unsigned short*)carve((size_t)NMAX * 512 * 2);
  int*   ROWPTR = (int*)carve((size_t)(NMAX + 1) * 4);
  int*   DEG    = (int*)carve((size_t)NMAX * 4);
  int*   SRCS   = (int*)carve((size_t)EMAX * 4);
  int*   BSUMS  = (int*)carve(64 * 4);
  float* PARTM  = (float*)carve((size_t)(NMAX + 8) * 8 * 4);  // per-wave maxes
  float* PARTS  = (float*)carve(256 * 8 * 4);
  float* GMAX   = (float*)carve(256);
  float* GINV   = (float*)carve(256);
  unsigned short* PROJ = QKV;    // alias: q/k/v slots dead once aggregate done
  if (off > ws_size) return;     // insufficient workspace: fail loudly

  // weights -> bf16 transposed + column-permuted ("WTs" layout for the GEMM)
  transpose_w_kernel<<<dim3(16,16,8), dim3(32,8), 0, stream>>>(W[0], WT);
  transpose_w_kernel<<<dim3(16,16,8), dim3(32,8), 0, stream>>>(W[1], WT + (size_t)8 * 262144);
  transpose_w_kernel<<<dim3(16,16,8), dim3(32,8), 0, stream>>>(W[2], WT + (size_t)16 * 262144);
  transpose_w_kernel<<<dim3(16,16,3), dim3(32,8), 0, stream>>>(headW, WT + (size_t)24 * 262144);

  size_t out_off = 0;
  for (int s = 0; s < 3; ++s) {
    const int N = Ns[s], E = Es[s];
    const int mt = (N + 255) >> 8;           // 256-row tiles
    const int nb = (N + 1023) / 1024;
    const int nsb = (N + 3) / 4;             // score blocks (4 waves each)

    init_x_kernel<<<2048, 256, 0, stream>>>(
        (const float4*)feat[s], (const float4*)emb[s], (const float4*)pos[s],
        XB, (long long)N * 128);

    // CSR by dst (edge index is constant per stream; built once, used 2x)
    hipMemsetAsync(DEG, 0, (size_t)N * 4, stream);
    hist_kernel<<<(E + 255) / 256, 256, 0, stream>>>(ei[s], E, DEG);
    scan_part_kernel<<<nb, 1024, 0, stream>>>(DEG, N, ROWPTR, BSUMS);
    scan_bsums_kernel<<<1, 64, 0, stream>>>(BSUMS, nb);
    scan_add_kernel<<<nb, 1024, 0, stream>>>(ROWPTR, BSUMS, N);
    hipMemsetAsync(DEG, 0, (size_t)N * 4, stream);
    scatter_kernel<<<(E + 255) / 256, 256, 0, stream>>>(ei[s], E, ROWPTR, DEG, SRCS);

    for (int l = 0; l < 2; ++l) {
      const unsigned short* Wqkv = WT + (size_t)(s * 8 + l * 4) * 262144;
      const unsigned short* Wo   = WT + (size_t)(s * 8 + l * 4 + 3) * 262144;
      const float* bqkv = Bb[s] + (size_t)l * 4 * 512;       // q,k,v biases contiguous
      const float* bo   = Bb[s] + (size_t)(l * 4 + 3) * 512;

      gemm_bt_kernel<1><<<dim3(mt * 6), 512, 0, stream>>>(XB, Wqkv, bqkv, QKV, N, 1536);
      csr_scores_kernel<<<nsb, 256, 0, stream>>>(QKV, SRCS, ROWPTR, N, SC, PARTM);
      gmax_kernel<<<1, 256, 0, stream>>>(PARTM, nsb * 4, GMAX);
      sm_exp_partial_kernel<<<256, 256, 0, stream>>>(SC, E, GMAX, PARTS);
      sm_final_kernel<1><<<1, 256, 0, stream>>>(PARTS, GINV);
      aggregate_kernel<<<nsb, 256, 0, stream>>>(QKV, SC, GINV, SRCS, ROWPTR, N, AGG);
      gemm_bt_kernel<1><<<dim3(mt * 2), 512, 0, stream>>>(AGG, Wo, bo, PROJ, N, 512);
      ln_kernel<<<nsb, 256, 0, stream>>>(PROJ, G[s] + (size_t)l * 512,
                                         Bt[s] + (size_t)l * 512, XB, N);
    }

    gemm_bt_kernel<0><<<dim3(mt * 2), 512, 0, stream>>>(
        XB, WT + (size_t)(24 + s) * 262144, headB + (size_t)s * 512,
        (float*)d_out + out_off, N, 512);
    out_off += (size_t)N * 512;
  }
}

// Round 10
// 1541.537 us; speedup vs baseline: 1.0016x; 1.0016x over previous
//
#include <hip/hip_runtime.h>

// ---------------------------------------------------------------------------
// SimplicialAttentionTransformer: 3 streams x (embed-add, 2x[QKV gemm,
// CSR-ordered edge scores (+fused max partials), GLOBAL softmax over edges,
// CSR segment-sum, proj gemm, LN], head gemm). bf16 residual stream (no f32
// X buffer). bf16 MFMA GEMM: 256x256 tile, 8 waves (wave-tile 128x64),
// 4-phase-per-K-tile schedule (round-8 known-good), double-buffered
// global_load_lds staging (XOR-swizzled source), raw s_barrier phases,
// setprio around MFMA clusters, swapped-operand MFMA + permuted weights ->
// 16 consecutive cols/lane, fully coalesced 16B stores.
// ---------------------------------------------------------------------------

typedef __attribute__((ext_vector_type(8))) __bf16 bf16x8;
typedef __attribute__((ext_vector_type(4))) float f32x4;
typedef __attribute__((ext_vector_type(8))) unsigned short ushort8v;
typedef __attribute__((ext_vector_type(4))) unsigned short ushort4v;

__device__ __forceinline__ float b2f(unsigned short u) {
  union { unsigned u; float f; } x; x.u = (unsigned)u << 16; return x.f;
}
__device__ __forceinline__ unsigned short f2b(float f) {
  union { float f; unsigned u; } x; x.f = f;
  unsigned r = x.u + 0x7fffu + ((x.u >> 16) & 1u);   // RNE
  return (unsigned short)(r >> 16);
}

// ======================= xb = bf16(a + b + c) ==============================
__global__ __launch_bounds__(256) void init_x_kernel(
    const float4* __restrict__ a, const float4* __restrict__ b,
    const float4* __restrict__ c, unsigned short* __restrict__ xb,
    long long n4)
{
  long long stride = (long long)gridDim.x * 256;
  for (long long i = (long long)blockIdx.x * 256 + threadIdx.x; i < n4; i += stride) {
    float4 av = a[i], bv = b[i], cv = c[i];
    ushort4v o;
    o.x = f2b(av.x + bv.x + cv.x); o.y = f2b(av.y + bv.y + cv.y);
    o.z = f2b(av.z + bv.z + cv.z); o.w = f2b(av.w + bv.w + cv.w);
    *(ushort4v*)(xb + i * 4) = o;
  }
}

// ============== weight transpose fp32[512][512] -> bf16 WT[perm(c)][r] =====
// perm swaps bits [5:4] <-> [3:2] within each 64-col block (involution).
__global__ __launch_bounds__(256) void transpose_w_kernel(
    const float* __restrict__ W, unsigned short* __restrict__ WT)
{
  __shared__ float t[32][33];
  const float* src = W + (size_t)blockIdx.z * 262144;
  unsigned short* dst = WT + (size_t)blockIdx.z * 262144;
  int bx = blockIdx.x * 32, by = blockIdx.y * 32;
  int tx = threadIdx.x, ty = threadIdx.y;   // block 32x8
  #pragma unroll
  for (int i = 0; i < 32; i += 8)
    t[ty + i][tx] = src[(size_t)(by + ty + i) * 512 + bx + tx];
  __syncthreads();
  #pragma unroll
  for (int i = 0; i < 32; i += 8) {
    int c = bx + ty + i;
    int p = (c & ~0x3C) | ((c & 0x30) >> 2) | ((c & 0x0C) << 2);
    dst[(size_t)p * 512 + by + tx] = f2b(t[tx][ty + i]);
  }
}

// ========================== bf16 GEMM:  C = A @ WTs^T + bias ===============
__device__ __forceinline__ void stage16(const void* g, void* lds_uniform) {
  __builtin_amdgcn_global_load_lds(
      (const __attribute__((address_space(1))) void*)g,
      (__attribute__((address_space(3))) void*)lds_uniform, 16, 0, 0);
}

template<int OUT_BF16>
__global__ __launch_bounds__(512, 2) void gemm_bt_kernel(
    const unsigned short* __restrict__ A,
    const unsigned short* __restrict__ BT,
    const float* __restrict__ bias,
    void* __restrict__ Cv,
    int M, int Ncols)
{
  constexpr int K = 512;
  // 128KB: buf b at shorts [b*32768, +16384)=A(256x64), [+16384,+32768)=B
  __shared__ unsigned short smem[65536];

  // bijective XCD-chunked swizzle (m204)
  const int nwg = gridDim.x, orig = blockIdx.x;
  const int xcd = orig & 7, lin = orig >> 3;
  const int q = nwg >> 3, r8 = nwg & 7;
  const int wgid = (xcd < r8 ? xcd * (q + 1) : r8 * (q + 1) + (xcd - r8) * q) + lin;

  const int tiles_n = Ncols >> 8;
  const int tm = wgid / tiles_n;
  const int tn = wgid - tm * tiles_n;
  const int row0 = tm << 8, col0 = tn << 8;
  const int lane = threadIdx.x & 63, wid = threadIdx.x >> 6;
  const int wr = (wid >> 2) << 7;   // M-half: 0 / 128
  const int wc = (wid & 3) << 6;    // N-quarter: 0/64/128/192

  f32x4 acc[8][4];
  #pragma unroll
  for (int i = 0; i < 8; ++i)
    #pragma unroll
    for (int j = 0; j < 4; ++j) acc[i][j] = (f32x4)0.f;

  // staging plan: 32 segs of 1KB per operand; wave owns segs (i<<3)|wid.
  int srow[4], scsw[4], sseg[4];
  #pragma unroll
  for (int i = 0; i < 4; ++i) {
    int seg = (i << 3) | wid;
    int idx = (seg << 6) | lane;     // row = idx>>3 (0..255), chunk = idx&7
    int row = idx >> 3, ch = idx & 7;
    sseg[i] = seg; srow[i] = row; scsw[i] = ch ^ (row & 7);  // pre-swizzled src
  }

  #define STG_PAIR(buf, kb_, i)                                               \
    { int ra = row0 + srow[i]; ra = (ra < M) ? ra : (M - 1);                  \
      stage16(A + (size_t)ra * K + (kb_) + (scsw[i] << 3),                    \
              smem + (buf) * 32768 + (sseg[i] << 9));                         \
      int rb = col0 + srow[i];                                                \
      stage16(BT + (size_t)rb * K + (kb_) + (scsw[i] << 3),                   \
              smem + (buf) * 32768 + 16384 + (sseg[i] << 9)); }

  STG_PAIR(0, 0, 0) STG_PAIR(0, 0, 1) STG_PAIR(0, 0, 2) STG_PAIR(0, 0, 3)
  __syncthreads();

  const int lm = lane & 15;
  const int kbl = (lane >> 4) << 4;

  #pragma unroll
  for (int kt = 0; kt < 8; ++kt) {
    const int cur = kt & 1, nxt = cur ^ 1, kb1 = (kt + 1) << 6;
    const char* Asb = (const char*)(smem + cur * 32768);
    const char* Bsb = Asb + 32768;   // bytes

    auto rdA = [&](int mi, int kk) -> bf16x8 {
      int r = wr + (mi << 4) + lm;
      int kb = (kk << 6) + kbl;
      return *(const bf16x8*)(Asb + (r << 7) + (kb ^ ((r & 7) << 4)));
    };
    auto rdB = [&](int ni, int kk) -> bf16x8 {
      int r = wc + (ni << 4) + lm;
      int kb = (kk << 6) + kbl;
      return *(const bf16x8*)(Bsb + (r << 7) + (kb ^ ((r & 7) << 4)));
    };

    bf16x8 av[4], bv[4];

    // ---- phase 0: frags (mi 0-3, kk0) + B(kk0); stage pairs 0,1 of t+1
    #pragma unroll
    for (int i = 0; i < 4; ++i) { av[i] = rdA(i, 0); bv[i] = rdB(i, 0); }
    if (kt < 7) { STG_PAIR(nxt, kb1, 0) STG_PAIR(nxt, kb1, 1) }
    __builtin_amdgcn_s_barrier();
    __builtin_amdgcn_s_setprio(1);
    #pragma unroll
    for (int mi = 0; mi < 4; ++mi)
      #pragma unroll
      for (int ni = 0; ni < 4; ++ni)
        acc[mi][ni] = __builtin_amdgcn_mfma_f32_16x16x32_bf16(
            bv[ni], av[mi], acc[mi][ni], 0, 0, 0);
    __builtin_amdgcn_s_setprio(0);
    __builtin_amdgcn_s_barrier();

    // ---- phase 1: frags (mi 4-7, kk0); stage pairs 2,3 of t+1
    #pragma unroll
    for (int i = 0; i < 4; ++i) av[i] = rdA(4 + i, 0);
    if (kt < 7) { STG_PAIR(nxt, kb1, 2) STG_PAIR(nxt, kb1, 3) }
    __builtin_amdgcn_s_barrier();
    __builtin_amdgcn_s_setprio(1);
    #pragma unroll
    for (int mi = 0; mi < 4; ++mi)
      #pragma unroll
      for (int ni = 0; ni < 4; ++ni)
        acc[4 + mi][ni] = __builtin_amdgcn_mfma_f32_16x16x32_bf16(
            bv[ni], av[mi], acc[4 + mi][ni], 0, 0, 0);
    __builtin_amdgcn_s_setprio(0);
    __builtin_amdgcn_s_barrier();

    // ---- phase 2: frags (mi 0-3, kk1) + B(kk1)
    #pragma unroll
    for (int i = 0; i < 4; ++i) { av[i] = rdA(i, 1); bv[i] = rdB(i, 1); }
    __builtin_amdgcn_s_barrier();
    __builtin_amdgcn_s_setprio(1);
    #pragma unroll
    for (int mi = 0; mi < 4; ++mi)
      #pragma unroll
      for (int ni = 0; ni < 4; ++ni)
        acc[mi][ni] = __builtin_amdgcn_mfma_f32_16x16x32_bf16(
            bv[ni], av[mi], acc[mi][ni], 0, 0, 0);
    __builtin_amdgcn_s_setprio(0);
    __builtin_amdgcn_s_barrier();

    // ---- phase 3: frags (mi 4-7, kk1)
    #pragma unroll
    for (int i = 0; i < 4; ++i) av[i] = rdA(4 + i, 1);
    __builtin_amdgcn_s_barrier();
    __builtin_amdgcn_s_setprio(1);
    #pragma unroll
    for (int mi = 0; mi < 4; ++mi)
      #pragma unroll
      for (int ni = 0; ni < 4; ++ni)
        acc[4 + mi][ni] = __builtin_amdgcn_mfma_f32_16x16x32_bf16(
            bv[ni], av[mi], acc[4 + mi][ni], 0, 0, 0);
    __builtin_amdgcn_s_setprio(0);

    // K-tile boundary: drain (t+1 landed; everyone done reading cur)
    __syncthreads();
  }
  #undef STG_PAIR

  const int mrow = lane & 15;
  const int t4 = (lane >> 4) << 4;       // lane's orig-col base within 64
  float bsv[16];
  #pragma unroll
  for (int ni = 0; ni < 4; ++ni) {
    float4 bvv = *(const float4*)(bias + col0 + wc + t4 + (ni << 2));
    bsv[4*ni+0] = bvv.x; bsv[4*ni+1] = bvv.y; bsv[4*ni+2] = bvv.z; bsv[4*ni+3] = bvv.w;
  }

  if (OUT_BF16) {
    unsigned short* C = (unsigned short*)Cv;
    #pragma unroll
    for (int mi = 0; mi < 8; ++mi) {
      int rowg = row0 + wr + (mi << 4) + mrow;
      if (rowg < M) {
        ushort8v o0, o1;
        #pragma unroll
        for (int r = 0; r < 4; ++r) {
          o0[r]     = f2b(acc[mi][0][r] + bsv[r]);
          o0[4 + r] = f2b(acc[mi][1][r] + bsv[4 + r]);
          o1[r]     = f2b(acc[mi][2][r] + bsv[8 + r]);
          o1[4 + r] = f2b(acc[mi][3][r] + bsv[12 + r]);
        }
        unsigned short* cp = C + (size_t)rowg * Ncols + col0 + wc + t4;
        *(ushort8v*)cp = o0;
        *(ushort8v*)(cp + 8) = o1;
      }
    }
  } else {
    float* C = (float*)Cv;
    #pragma unroll
    for (int mi = 0; mi < 8; ++mi) {
      int rowg = row0 + wr + (mi << 4) + mrow;
      if (rowg < M) {
        float* cp = C + (size_t)rowg * Ncols + col0 + wc + t4;
        #pragma unroll
        for (int ni = 0; ni < 4; ++ni) {
          float4 v;
          v.x = acc[mi][ni][0] + bsv[4*ni+0];
          v.y = acc[mi][ni][1] + bsv[4*ni+1];
          v.z = acc[mi][ni][2] + bsv[4*ni+2];
          v.w = acc[mi][ni][3] + bsv[4*ni+3];
          *(float4*)(cp + (ni << 2)) = v;
        }
      }
    }
  }
}

// ====== CSR-ordered edge scores + fused per-wave max partials ==============
// One wave per dst node n: q[n] in regs, k gathered per in-edge; xor-reduce
// broadcasts each score to all 8 lanes of a head group, so a running max is
// tracked for free. Empty/out-of-range waves emit -1e30 (safe: the global
// softmax shift is invariant to the exact shift value).
__global__ __launch_bounds__(256) void csr_scores_kernel(
    const unsigned short* __restrict__ qkv, const int* __restrict__ srcs,
    const int* __restrict__ rowptr, int N, float* __restrict__ sc,
    float* __restrict__ partm)
{
  int wid = threadIdx.x >> 6, lane = threadIdx.x & 63;
  int n = (blockIdx.x << 2) | wid;
  float mx = -1e30f;
  if (n < N) {
    int beg = rowptr[n], end = rowptr[n + 1];
    if (beg < end) {
      ushort8v qv = *(const ushort8v*)(qkv + (size_t)n * 1536 + (lane << 3));
      float qf[8];
      #pragma unroll
      for (int j = 0; j < 8; ++j) qf[j] = b2f(qv[j]);
      int i = beg;
      for (; i + 2 <= end; i += 2) {       // 2-edge ILP
        int s0 = srcs[i], s1 = srcs[i + 1];
        ushort8v k0 = *(const ushort8v*)(qkv + (size_t)s0 * 1536 + 512 + (lane << 3));
        ushort8v k1 = *(const ushort8v*)(qkv + (size_t)s1 * 1536 + 512 + (lane << 3));
        float p0 = 0.f, p1 = 0.f;
        #pragma unroll
        for (int j = 0; j < 8; ++j) { p0 += qf[j] * b2f(k0[j]); p1 += qf[j] * b2f(k1[j]); }
        p0 += __shfl_xor(p0, 1); p1 += __shfl_xor(p1, 1);
        p0 += __shfl_xor(p0, 2); p1 += __shfl_xor(p1, 2);
        p0 += __shfl_xor(p0, 4); p1 += __shfl_xor(p1, 4);
        p0 *= 0.125f; p1 *= 0.125f;
        mx = fmaxf(mx, fmaxf(p0, p1));
        if (!(lane & 7)) {
          sc[(size_t)i * 8 + (lane >> 3)] = p0;
          sc[(size_t)(i + 1) * 8 + (lane >> 3)] = p1;
        }
      }
      if (i < end) {
        int s0 = srcs[i];
        ushort8v k0 = *(const ushort8v*)(qkv + (size_t)s0 * 1536 + 512 + (lane << 3));
        float p0 = 0.f;
        #pragma unroll
        for (int j = 0; j < 8; ++j) p0 += qf[j] * b2f(k0[j]);
        p0 += __shfl_xor(p0, 1);
        p0 += __shfl_xor(p0, 2);
        p0 += __shfl_xor(p0, 4);
        p0 *= 0.125f;
        mx = fmaxf(mx, p0);
        if (!(lane & 7)) sc[(size_t)i * 8 + (lane >> 3)] = p0;
      }
    }
  }
  if (!(lane & 7))
    partm[(((size_t)blockIdx.x << 2) | wid) * 8 + (lane >> 3)] = mx;
}

// ==================== global softmax over edge axis (per head) ==============
template<int OP>   // 0 = max, 1 = sum
__device__ __forceinline__ void reduce8_block(float (&v)[8], float* red) {
  int lane = threadIdx.x & 63, wid = threadIdx.x >> 6;
  #pragma unroll
  for (int h = 0; h < 8; ++h)
    #pragma unroll
    for (int off = 1; off < 64; off <<= 1) {
      float o = __shfl_xor(v[h], off);
      v[h] = OP ? (v[h] + o) : fmaxf(v[h], o);
    }
  if (lane == 0) {
    #pragma unroll
    for (int h = 0; h < 8; ++h) red[h * 4 + wid] = v[h];
  }
  __syncthreads();
  if (threadIdx.x == 0) {
    #pragma unroll
    for (int h = 0; h < 8; ++h) {
      float r = red[h * 4];
      #pragma unroll
      for (int w = 1; w < 4; ++w)
        r = OP ? (r + red[h * 4 + w]) : fmaxf(r, red[h * 4 + w]);
      v[h] = r;
    }
  }
}

// reduce per-wave max partials (nslots x 8) -> gmax[8]; single block
__global__ __launch_bounds__(256) void gmax_kernel(
    const float* __restrict__ partm, int nslots, float* __restrict__ gmax)
{
  __shared__ float red[32];
  float v[8];
  #pragma unroll
  for (int h = 0; h < 8; ++h) v[h] = -1e30f;
  for (int i = threadIdx.x; i < nslots; i += 256) {
    #pragma unroll
    for (int h = 0; h < 8; ++h) v[h] = fmaxf(v[h], partm[(size_t)i * 8 + h]);
  }
  reduce8_block<0>(v, red);
  if (threadIdx.x == 0) {
    #pragma unroll
    for (int h = 0; h < 8; ++h) gmax[h] = v[h];
  }
}

// exp pass: w = exp(sc - gmax) in place; per-block sums -> parts
__global__ __launch_bounds__(256) void sm_exp_partial_kernel(
    float* __restrict__ sc, int E, const float* __restrict__ gmax,
    float* __restrict__ parts)
{
  __shared__ float red[32];
  float gm[8], v[8];
  #pragma unroll
  for (int h = 0; h < 8; ++h) { gm[h] = gmax[h]; v[h] = 0.f; }
  int stride = gridDim.x * 256;
  for (int e = blockIdx.x * 256 + threadIdx.x; e < E; e += stride) {
    #pragma unroll
    for (int h = 0; h < 8; ++h) {
      float w = __expf(sc[(size_t)e * 8 + h] - gm[h]);
      sc[(size_t)e * 8 + h] = w;           // in-place exp
      v[h] += w;
    }
  }
  reduce8_block<1>(v, red);
  if (threadIdx.x == 0) {
    #pragma unroll
    for (int h = 0; h < 8; ++h) parts[blockIdx.x * 8 + h] = v[h];
  }
}

template<int OP>   // 1: out = 1/sum
__global__ __launch_bounds__(256) void sm_final_kernel(
    const float* __restrict__ part, float* __restrict__ out)
{
  __shared__ float red[32];
  float v[8];
  #pragma unroll
  for (int h = 0; h < 8; ++h) v[h] = part[threadIdx.x * 8 + h];
  reduce8_block<OP>(v, red);
  if (threadIdx.x == 0) {
    #pragma unroll
    for (int h = 0; h < 8; ++h) out[h] = OP ? (1.0f / v[h]) : v[h];
  }
}

// =============================== CSR build ==================================
__global__ __launch_bounds__(256) void hist_kernel(
    const int* __restrict__ ei, int E, int* __restrict__ deg)
{
  int e = blockIdx.x * 256 + threadIdx.x;
  if (e < E) atomicAdd(&deg[ei[E + e]], 1);
}

__global__ __launch_bounds__(1024) void scan_part_kernel(
    const int* __restrict__ deg, int N, int* __restrict__ rowptr,
    int* __restrict__ bsums)
{
  __shared__ int wsum[16];
  int i = blockIdx.x * 1024 + threadIdx.x;
  int lane = threadIdx.x & 63, wid = threadIdx.x >> 6;
  int sv = (i < N) ? deg[i] : 0;
  #pragma unroll
  for (int off = 1; off < 64; off <<= 1) {
    int t = __shfl_up(sv, off);
    if (lane >= off) sv += t;
  }
  if (lane == 63) wsum[wid] = sv;
  __syncthreads();
  if (threadIdx.x < 16) {
    int ws = wsum[threadIdx.x];
    #pragma unroll
    for (int off = 1; off < 16; off <<= 1) {
      int t = __shfl_up(ws, off);
      if (threadIdx.x >= off) ws += t;
    }
    wsum[threadIdx.x] = ws;
  }
  __syncthreads();
  if (wid > 0) sv += wsum[wid - 1];
  if (i < N) rowptr[i + 1] = sv;
  if (threadIdx.x == 1023) bsums[blockIdx.x] = sv;
}

__global__ __launch_bounds__(64) void scan_bsums_kernel(int* bsums, int nb)
{
  int lane = threadIdx.x;
  int v = (lane < nb) ? bsums[lane] : 0;
  #pragma unroll
  for (int off = 1; off < 64; off <<= 1) {
    int t = __shfl_up(v, off);
    if (lane >= off) v += t;
  }
  int ex = __shfl_up(v, 1);
  if (lane == 0) ex = 0;
  if (lane < nb) bsums[lane] = ex;     // exclusive offsets, in place
}

__global__ __launch_bounds__(1024) void scan_add_kernel(
    int* __restrict__ rowptr, const int* __restrict__ bsums, int N)
{
  int i = blockIdx.x * 1024 + threadIdx.x;
  if (i == 0) rowptr[0] = 0;
  if (i < N && blockIdx.x > 0) rowptr[i + 1] += bsums[blockIdx.x];
}

__global__ __launch_bounds__(256) void scatter_kernel(
    const int* __restrict__ ei, int E, const int* __restrict__ rowptr,
    int* __restrict__ cur, int* __restrict__ srcs)
{
  int e = blockIdx.x * 256 + threadIdx.x;
  if (e < E) {
    int dst = ei[E + e];
    int pos = atomicAdd(&cur[dst], 1);
    srcs[rowptr[dst] + pos] = ei[e];
  }
}

// ====== aggregate: agg[n] = sum_{i in CSR(n)} w[i,h] * v[srcs[i]] ==========
__global__ __launch_bounds__(256) void aggregate_kernel(
    const unsigned short* __restrict__ qkv, const float* __restrict__ wexp,
    const float* __restrict__ ginv, const int* __restrict__ srcs,
    const int* __restrict__ rowptr, int N, unsigned short* __restrict__ agg)
{
  int wid = threadIdx.x >> 6, lane = threadIdx.x & 63;
  int n = (blockIdx.x << 2) | wid;
  if (n >= N) return;
  int beg = rowptr[n], end = rowptr[n + 1];
  int h = lane >> 3;
  float inv = ginv[h];
  float acc[8] = {0.f,0.f,0.f,0.f,0.f,0.f,0.f,0.f};
  int i = beg;
  for (; i + 4 <= end; i += 4) {       // 4-edge ILP
    int s0 = srcs[i], s1 = srcs[i + 1], s2 = srcs[i + 2], s3 = srcs[i + 3];
    float w0 = wexp[(size_t)i * 8 + h] * inv;
    float w1 = wexp[(size_t)(i + 1) * 8 + h] * inv;
    float w2 = wexp[(size_t)(i + 2) * 8 + h] * inv;
    float w3 = wexp[(size_t)(i + 3) * 8 + h] * inv;
    ushort8v v0 = *(const ushort8v*)(qkv + (size_t)s0 * 1536 + 1024 + (lane << 3));
    ushort8v v1 = *(const ushort8v*)(qkv + (size_t)s1 * 1536 + 1024 + (lane << 3));
    ushort8v v2 = *(const ushort8v*)(qkv + (size_t)s2 * 1536 + 1024 + (lane << 3));
    ushort8v v3 = *(const ushort8v*)(qkv + (size_t)s3 * 1536 + 1024 + (lane << 3));
    #pragma unroll
    for (int j = 0; j < 8; ++j)
      acc[j] += (w0 * b2f(v0[j]) + w1 * b2f(v1[j]))
              + (w2 * b2f(v2[j]) + w3 * b2f(v3[j]));
  }
  for (; i < end; ++i) {
    int s0 = srcs[i];
    float w0 = wexp[(size_t)i * 8 + h] * inv;
    ushort8v v0 = *(const ushort8v*)(qkv + (size_t)s0 * 1536 + 1024 + (lane << 3));
    #pragma unroll
    for (int j = 0; j < 8; ++j) acc[j] += w0 * b2f(v0[j]);
  }
  ushort8v o;
  #pragma unroll
  for (int j = 0; j < 8; ++j) o[j] = f2b(acc[j]);
  *(ushort8v*)(agg + (size_t)n * 512 + (lane << 3)) = o;
}

// ============== LN(proj + resid)*g + bt, bf16 residual (wave/row) ==========
__global__ __launch_bounds__(256) void ln_kernel(
    const unsigned short* __restrict__ proj, const float* __restrict__ g,
    const float* __restrict__ bt, unsigned short* __restrict__ xb, int N)
{
  int wid = threadIdx.x >> 6, lane = threadIdx.x & 63;
  int n = (blockIdx.x << 2) | wid;
  if (n >= N) return;
  size_t base = (size_t)n * 512 + (lane << 3);
  ushort8v pv = *(const ushort8v*)(proj + base);
  ushort8v xv = *(const ushort8v*)(xb + base);
  float y[8];
  #pragma unroll
  for (int j = 0; j < 8; ++j) y[j] = b2f(pv[j]) + b2f(xv[j]);
  float s = 0.f;
  #pragma unroll
  for (int j = 0; j < 8; ++j) s += y[j];
  #pragma unroll
  for (int off = 1; off < 64; off <<= 1) s += __shfl_xor(s, off);
  float mean = s * (1.f / 512.f);
  float vs = 0.f;
  #pragma unroll
  for (int j = 0; j < 8; ++j) { float d = y[j] - mean; vs += d * d; }
  #pragma unroll
  for (int off = 1; off < 64; off <<= 1) vs += __shfl_xor(vs, off);
  float rstd = rsqrtf(vs * (1.f / 512.f) + 1e-5f);
  int gi = lane << 3;
  ushort8v ob;
  #pragma unroll
  for (int j = 0; j < 8; ++j)
    ob[j] = f2b((y[j] - mean) * rstd * g[gi + j] + bt[gi + j]);
  *(ushort8v*)(xb + base) = ob;
}

// ================================ driver ====================================
extern "C" void kernel_launch(void* const* d_in, const int* in_sizes, int n_in,
                              void* d_out, int out_size, void* d_ws, size_t ws_size,
                              hipStream_t stream)
{
  (void)n_in; (void)out_size;
  const float* feat[3] = {(const float*)d_in[0], (const float*)d_in[1], (const float*)d_in[2]};
  const float* emb[3]  = {(const float*)d_in[3], (const float*)d_in[4], (const float*)d_in[5]};
  const float* pos[3]  = {(const float*)d_in[6], (const float*)d_in[7], (const float*)d_in[8]};
  const float* W[3]  = {(const float*)d_in[9],  (const float*)d_in[13], (const float*)d_in[17]};
  const float* Bb[3] = {(const float*)d_in[10], (const float*)d_in[14], (const float*)d_in[18]};
  const float* G[3]  = {(const float*)d_in[11], (const float*)d_in[15], (const float*)d_in[19]};
  const float* Bt[3] = {(const float*)d_in[12], (const float*)d_in[16], (const float*)d_in[20]};
  const float* headW = (const float*)d_in[21];
  const float* headB = (const float*)d_in[22];
  const int* ei[3] = {(const int*)d_in[23], (const int*)d_in[24], (const int*)d_in[25]};

  int Ns[3], Es[3];
  for (int s = 0; s < 3; ++s) { Ns[s] = in_sizes[s] / 512; Es[s] = in_sizes[23 + s] / 2; }
  int NMAX = Ns[0], EMAX = Es[0];
  for (int s = 1; s < 3; ++s) { if (Ns[s] > NMAX) NMAX = Ns[s]; if (Es[s] > EMAX) EMAX = Es[s]; }

  char* base = (char*)d_ws;
  size_t off = 0;
  auto carve = [&](size_t bytes) -> char* {
    char* r = base + off;
    off += (bytes + 255) & ~(size_t)255;
    return r;
  };
  unsigned short* WT  = (unsigned short*)carve((size_t)27 * 262144 * 2);
  unsigned short* XB  = (unsigned short*)carve((size_t)NMAX * 512 * 2);
  unsigned short* QKV = (unsigned short*)carve((size_t)NMAX * 1536 * 2);
  float*          SC  = (float*)carve((size_t)EMAX * 8 * 4);
  unsigned short* AGG = (unsigned short*)carve((size_t)NMAX * 512 * 2);
  int*   ROWPTR = (int*)carve((size_t)(NMAX + 1) * 4);
  int*   DEG    = (int*)carve((size_t)NMAX * 4);
  int*   SRCS   = (int*)carve((size_t)EMAX * 4);
  int*   BSUMS  = (int*)carve(64 * 4);
  float* PARTM  = (float*)carve((size_t)(NMAX + 8) * 8 * 4);  // per-wave maxes
  float* PARTS  = (float*)carve(256 * 8 * 4);
  float* GMAX   = (float*)carve(256);
  float* GINV   = (float*)carve(256);
  unsigned short* PROJ = QKV;    // alias: q/k/v slots dead once aggregate done
  if (off > ws_size) return;     // insufficient workspace: fail loudly

  // weights -> bf16 transposed + column-permuted ("WTs" layout for the GEMM)
  transpose_w_kernel<<<dim3(16,16,8), dim3(32,8), 0, stream>>>(W[0], WT);
  transpose_w_kernel<<<dim3(16,16,8), dim3(32,8), 0, stream>>>(W[1], WT + (size_t)8 * 262144);
  transpose_w_kernel<<<dim3(16,16,8), dim3(32,8), 0, stream>>>(W[2], WT + (size_t)16 * 262144);
  transpose_w_kernel<<<dim3(16,16,3), dim3(32,8), 0, stream>>>(headW, WT + (size_t)24 * 262144);

  size_t out_off = 0;
  for (int s = 0; s < 3; ++s) {
    const int N = Ns[s], E = Es[s];
    const int mt = (N + 255) >> 8;           // 256-row tiles
    const int nb = (N + 1023) / 1024;
    const int nsb = (N + 3) / 4;             // score blocks (4 waves each)

    init_x_kernel<<<2048, 256, 0, stream>>>(
        (const float4*)feat[s], (const float4*)emb[s], (const float4*)pos[s],
        XB, (long long)N * 128);

    // CSR by dst (edge index is constant per stream; built once, used 2x)
    hipMemsetAsync(DEG, 0, (size_t)N * 4, stream);
    hist_kernel<<<(E + 255) / 256, 256, 0, stream>>>(ei[s], E, DEG);
    scan_part_kernel<<<nb, 1024, 0, stream>>>(DEG, N, ROWPTR, BSUMS);
    scan_bsums_kernel<<<1, 64, 0, stream>>>(BSUMS, nb);
    scan_add_kernel<<<nb, 1024, 0, stream>>>(ROWPTR, BSUMS, N);
    hipMemsetAsync(DEG, 0, (size_t)N * 4, stream);
    scatter_kernel<<<(E + 255) / 256, 256, 0, stream>>>(ei[s], E, ROWPTR, DEG, SRCS);

    for (int l = 0; l < 2; ++l) {
      const unsigned short* Wqkv = WT + (size_t)(s * 8 + l * 4) * 262144;
      const unsigned short* Wo   = WT + (size_t)(s * 8 + l * 4 + 3) * 262144;
      const float* bqkv = Bb[s] + (size_t)l * 4 * 512;       // q,k,v biases contiguous
      const float* bo   = Bb[s] + (size_t)(l * 4 + 3) * 512;

      gemm_bt_kernel<1><<<dim3(mt * 6), 512, 0, stream>>>(XB, Wqkv, bqkv, QKV, N, 1536);
      csr_scores_kernel<<<nsb, 256, 0, stream>>>(QKV, SRCS, ROWPTR, N, SC, PARTM);
      gmax_kernel<<<1, 256, 0, stream>>>(PARTM, nsb * 4, GMAX);
      sm_exp_partial_kernel<<<256, 256, 0, stream>>>(SC, E, GMAX, PARTS);
      sm_final_kernel<1><<<1, 256, 0, stream>>>(PARTS, GINV);
      aggregate_kernel<<<nsb, 256, 0, stream>>>(QKV, SC, GINV, SRCS, ROWPTR, N, AGG);
      gemm_bt_kernel<1><<<dim3(mt * 2), 512, 0, stream>>>(AGG, Wo, bo, PROJ, N, 512);
      ln_kernel<<<nsb, 256, 0, stream>>>(PROJ, G[s] + (size_t)l * 512,
                                         Bt[s] + (size_t)l * 512, XB, N);
    }

    gemm_bt_kernel<0><<<dim3(mt * 2), 512, 0, stream>>>(
        XB, WT + (size_t)(24 + s) * 262144, headB + (size_t)s * 512,
        (float*)d_out + out_off, N, 512);
    out_off += (size_t)N * 512;
  }
}

// Round 11
// 1352.781 us; speedup vs baseline: 1.1413x; 1.1395x over previous
//
#include <hip/hip_runtime.h>

// ---------------------------------------------------------------------------
// SimplicialAttentionTransformer: 3 streams x (embed-add, 2x[QKV gemm,
// CSR-ordered edge scores (+fused max partials), GLOBAL softmax over edges,
// CSR segment-sum, proj gemm, LN], head gemm). bf16 residual stream. bf16
// MFMA GEMM: 256x256 tile, 8 waves, 4-phase-per-K-tile schedule (measured-
// neutral vs alternatives; frozen), double-buffered global_load_lds staging
// (XOR-swizzled source), swapped-operand MFMA + permuted weights -> 16
// consecutive cols/lane. Softmax max: per-wave partials fused into scores,
// PARALLEL 256-block reduce, final 256-slot reduce fused into exp pass.
// ---------------------------------------------------------------------------

typedef __attribute__((ext_vector_type(8))) __bf16 bf16x8;
typedef __attribute__((ext_vector_type(4))) float f32x4;
typedef __attribute__((ext_vector_type(8))) unsigned short ushort8v;
typedef __attribute__((ext_vector_type(4))) unsigned short ushort4v;

__device__ __forceinline__ float b2f(unsigned short u) {
  union { unsigned u; float f; } x; x.u = (unsigned)u << 16; return x.f;
}
__device__ __forceinline__ unsigned short f2b(float f) {
  union { float f; unsigned u; } x; x.f = f;
  unsigned r = x.u + 0x7fffu + ((x.u >> 16) & 1u);   // RNE
  return (unsigned short)(r >> 16);
}

// ======================= xb = bf16(a + b + c) ==============================
__global__ __launch_bounds__(256) void init_x_kernel(
    const float4* __restrict__ a, const float4* __restrict__ b,
    const float4* __restrict__ c, unsigned short* __restrict__ xb,
    long long n4)
{
  long long stride = (long long)gridDim.x * 256;
  for (long long i = (long long)blockIdx.x * 256 + threadIdx.x; i < n4; i += stride) {
    float4 av = a[i], bv = b[i], cv = c[i];
    ushort4v o;
    o.x = f2b(av.x + bv.x + cv.x); o.y = f2b(av.y + bv.y + cv.y);
    o.z = f2b(av.z + bv.z + cv.z); o.w = f2b(av.w + bv.w + cv.w);
    *(ushort4v*)(xb + i * 4) = o;
  }
}

// ============== weight transpose fp32[512][512] -> bf16 WT[perm(c)][r] =====
// perm swaps bits [5:4] <-> [3:2] within each 64-col block (involution).
__global__ __launch_bounds__(256) void transpose_w_kernel(
    const float* __restrict__ W, unsigned short* __restrict__ WT)
{
  __shared__ float t[32][33];
  const float* src = W + (size_t)blockIdx.z * 262144;
  unsigned short* dst = WT + (size_t)blockIdx.z * 262144;
  int bx = blockIdx.x * 32, by = blockIdx.y * 32;
  int tx = threadIdx.x, ty = threadIdx.y;   // block 32x8
  #pragma unroll
  for (int i = 0; i < 32; i += 8)
    t[ty + i][tx] = src[(size_t)(by + ty + i) * 512 + bx + tx];
  __syncthreads();
  #pragma unroll
  for (int i = 0; i < 32; i += 8) {
    int c = bx + ty + i;
    int p = (c & ~0x3C) | ((c & 0x30) >> 2) | ((c & 0x0C) << 2);
    dst[(size_t)p * 512 + by + tx] = f2b(t[tx][ty + i]);
  }
}

// ========================== bf16 GEMM:  C = A @ WTs^T + bias ===============
__device__ __forceinline__ void stage16(const void* g, void* lds_uniform) {
  __builtin_amdgcn_global_load_lds(
      (const __attribute__((address_space(1))) void*)g,
      (__attribute__((address_space(3))) void*)lds_uniform, 16, 0, 0);
}

template<int OUT_BF16>
__global__ __launch_bounds__(512, 2) void gemm_bt_kernel(
    const unsigned short* __restrict__ A,
    const unsigned short* __restrict__ BT,
    const float* __restrict__ bias,
    void* __restrict__ Cv,
    int M, int Ncols)
{
  constexpr int K = 512;
  // 128KB: buf b at shorts [b*32768, +16384)=A(256x64), [+16384,+32768)=B
  __shared__ unsigned short smem[65536];

  // bijective XCD-chunked swizzle (m204)
  const int nwg = gridDim.x, orig = blockIdx.x;
  const int xcd = orig & 7, lin = orig >> 3;
  const int q = nwg >> 3, r8 = nwg & 7;
  const int wgid = (xcd < r8 ? xcd * (q + 1) : r8 * (q + 1) + (xcd - r8) * q) + lin;

  const int tiles_n = Ncols >> 8;
  const int tm = wgid / tiles_n;
  const int tn = wgid - tm * tiles_n;
  const int row0 = tm << 8, col0 = tn << 8;
  const int lane = threadIdx.x & 63, wid = threadIdx.x >> 6;
  const int wr = (wid >> 2) << 7;   // M-half: 0 / 128
  const int wc = (wid & 3) << 6;    // N-quarter: 0/64/128/192

  f32x4 acc[8][4];
  #pragma unroll
  for (int i = 0; i < 8; ++i)
    #pragma unroll
    for (int j = 0; j < 4; ++j) acc[i][j] = (f32x4)0.f;

  // staging plan: 32 segs of 1KB per operand; wave owns segs (i<<3)|wid.
  int srow[4], scsw[4], sseg[4];
  #pragma unroll
  for (int i = 0; i < 4; ++i) {
    int seg = (i << 3) | wid;
    int idx = (seg << 6) | lane;     // row = idx>>3 (0..255), chunk = idx&7
    int row = idx >> 3, ch = idx & 7;
    sseg[i] = seg; srow[i] = row; scsw[i] = ch ^ (row & 7);  // pre-swizzled src
  }

  #define STG_PAIR(buf, kb_, i)                                               \
    { int ra = row0 + srow[i]; ra = (ra < M) ? ra : (M - 1);                  \
      stage16(A + (size_t)ra * K + (kb_) + (scsw[i] << 3),                    \
              smem + (buf) * 32768 + (sseg[i] << 9));                         \
      int rb = col0 + srow[i];                                                \
      stage16(BT + (size_t)rb * K + (kb_) + (scsw[i] << 3),                   \
              smem + (buf) * 32768 + 16384 + (sseg[i] << 9)); }

  STG_PAIR(0, 0, 0) STG_PAIR(0, 0, 1) STG_PAIR(0, 0, 2) STG_PAIR(0, 0, 3)
  __syncthreads();

  const int lm = lane & 15;
  const int kbl = (lane >> 4) << 4;

  #pragma unroll
  for (int kt = 0; kt < 8; ++kt) {
    const int cur = kt & 1, nxt = cur ^ 1, kb1 = (kt + 1) << 6;
    const char* Asb = (const char*)(smem + cur * 32768);
    const char* Bsb = Asb + 32768;   // bytes

    auto rdA = [&](int mi, int kk) -> bf16x8 {
      int r = wr + (mi << 4) + lm;
      int kb = (kk << 6) + kbl;
      return *(const bf16x8*)(Asb + (r << 7) + (kb ^ ((r & 7) << 4)));
    };
    auto rdB = [&](int ni, int kk) -> bf16x8 {
      int r = wc + (ni << 4) + lm;
      int kb = (kk << 6) + kbl;
      return *(const bf16x8*)(Bsb + (r << 7) + (kb ^ ((r & 7) << 4)));
    };

    bf16x8 av[4], bv[4];

    // ---- phase 0: frags (mi 0-3, kk0) + B(kk0); stage pairs 0,1 of t+1
    #pragma unroll
    for (int i = 0; i < 4; ++i) { av[i] = rdA(i, 0); bv[i] = rdB(i, 0); }
    if (kt < 7) { STG_PAIR(nxt, kb1, 0) STG_PAIR(nxt, kb1, 1) }
    __builtin_amdgcn_s_barrier();
    __builtin_amdgcn_s_setprio(1);
    #pragma unroll
    for (int mi = 0; mi < 4; ++mi)
      #pragma unroll
      for (int ni = 0; ni < 4; ++ni)
        acc[mi][ni] = __builtin_amdgcn_mfma_f32_16x16x32_bf16(
            bv[ni], av[mi], acc[mi][ni], 0, 0, 0);
    __builtin_amdgcn_s_setprio(0);
    __builtin_amdgcn_s_barrier();

    // ---- phase 1: frags (mi 4-7, kk0); stage pairs 2,3 of t+1
    #pragma unroll
    for (int i = 0; i < 4; ++i) av[i] = rdA(4 + i, 0);
    if (kt < 7) { STG_PAIR(nxt, kb1, 2) STG_PAIR(nxt, kb1, 3) }
    __builtin_amdgcn_s_barrier();
    __builtin_amdgcn_s_setprio(1);
    #pragma unroll
    for (int mi = 0; mi < 4; ++mi)
      #pragma unroll
      for (int ni = 0; ni < 4; ++ni)
        acc[4 + mi][ni] = __builtin_amdgcn_mfma_f32_16x16x32_bf16(
            bv[ni], av[mi], acc[4 + mi][ni], 0, 0, 0);
    __builtin_amdgcn_s_setprio(0);
    __builtin_amdgcn_s_barrier();

    // ---- phase 2: frags (mi 0-3, kk1) + B(kk1)
    #pragma unroll
    for (int i = 0; i < 4; ++i) { av[i] = rdA(i, 1); bv[i] = rdB(i, 1); }
    __builtin_amdgcn_s_barrier();
    __builtin_amdgcn_s_setprio(1);
    #pragma unroll
    for (int mi = 0; mi < 4; ++mi)
      #pragma unroll
      for (int ni = 0; ni < 4; ++ni)
        acc[mi][ni] = __builtin_amdgcn_mfma_f32_16x16x32_bf16(
            bv[ni], av[mi], acc[mi][ni], 0, 0, 0);
    __builtin_amdgcn_s_setprio(0);
    __builtin_amdgcn_s_barrier();

    // ---- phase 3: frags (mi 4-7, kk1)
    #pragma unroll
    for (int i = 0; i < 4; ++i) av[i] = rdA(4 + i, 1);
    __builtin_amdgcn_s_barrier();
    __builtin_amdgcn_s_setprio(1);
    #pragma unroll
    for (int mi = 0; mi < 4; ++mi)
      #pragma unroll
      for (int ni = 0; ni < 4; ++ni)
        acc[4 + mi][ni] = __builtin_amdgcn_mfma_f32_16x16x32_bf16(
            bv[ni], av[mi], acc[4 + mi][ni], 0, 0, 0);
    __builtin_amdgcn_s_setprio(0);

    // K-tile boundary: drain (t+1 landed; everyone done reading cur)
    __syncthreads();
  }
  #undef STG_PAIR

  const int mrow = lane & 15;
  const int t4 = (lane >> 4) << 4;       // lane's orig-col base within 64
  float bsv[16];
  #pragma unroll
  for (int ni = 0; ni < 4; ++ni) {
    float4 bvv = *(const float4*)(bias + col0 + wc + t4 + (ni << 2));
    bsv[4*ni+0] = bvv.x; bsv[4*ni+1] = bvv.y; bsv[4*ni+2] = bvv.z; bsv[4*ni+3] = bvv.w;
  }

  if (OUT_BF16) {
    unsigned short* C = (unsigned short*)Cv;
    #pragma unroll
    for (int mi = 0; mi < 8; ++mi) {
      int rowg = row0 + wr + (mi << 4) + mrow;
      if (rowg < M) {
        ushort8v o0, o1;
        #pragma unroll
        for (int r = 0; r < 4; ++r) {
          o0[r]     = f2b(acc[mi][0][r] + bsv[r]);
          o0[4 + r] = f2b(acc[mi][1][r] + bsv[4 + r]);
          o1[r]     = f2b(acc[mi][2][r] + bsv[8 + r]);
          o1[4 + r] = f2b(acc[mi][3][r] + bsv[12 + r]);
        }
        unsigned short* cp = C + (size_t)rowg * Ncols + col0 + wc + t4;
        *(ushort8v*)cp = o0;
        *(ushort8v*)(cp + 8) = o1;
      }
    }
  } else {
    float* C = (float*)Cv;
    #pragma unroll
    for (int mi = 0; mi < 8; ++mi) {
      int rowg = row0 + wr + (mi << 4) + mrow;
      if (rowg < M) {
        float* cp = C + (size_t)rowg * Ncols + col0 + wc + t4;
        #pragma unroll
        for (int ni = 0; ni < 4; ++ni) {
          float4 v;
          v.x = acc[mi][ni][0] + bsv[4*ni+0];
          v.y = acc[mi][ni][1] + bsv[4*ni+1];
          v.z = acc[mi][ni][2] + bsv[4*ni+2];
          v.w = acc[mi][ni][3] + bsv[4*ni+3];
          *(float4*)(cp + (ni << 2)) = v;
        }
      }
    }
  }
}

// ====== CSR-ordered edge scores + fused per-wave max partials ==============
// One wave per dst node n: q[n] in regs, k gathered per in-edge; xor-reduce
// broadcasts each score to all 8 lanes of a head group, so a running max is
// tracked for free. Empty/out-of-range waves emit -1e30 (safe: the global
// softmax shift is invariant to the exact shift value).
__global__ __launch_bounds__(256) void csr_scores_kernel(
    const unsigned short* __restrict__ qkv, const int* __restrict__ srcs,
    const int* __restrict__ rowptr, int N, float* __restrict__ sc,
    float* __restrict__ partm)
{
  int wid = threadIdx.x >> 6, lane = threadIdx.x & 63;
  int n = (blockIdx.x << 2) | wid;
  float mx = -1e30f;
  if (n < N) {
    int beg = rowptr[n], end = rowptr[n + 1];
    if (beg < end) {
      ushort8v qv = *(const ushort8v*)(qkv + (size_t)n * 1536 + (lane << 3));
      float qf[8];
      #pragma unroll
      for (int j = 0; j < 8; ++j) qf[j] = b2f(qv[j]);
      int i = beg;
      for (; i + 2 <= end; i += 2) {       // 2-edge ILP
        int s0 = srcs[i], s1 = srcs[i + 1];
        ushort8v k0 = *(const ushort8v*)(qkv + (size_t)s0 * 1536 + 512 + (lane << 3));
        ushort8v k1 = *(const ushort8v*)(qkv + (size_t)s1 * 1536 + 512 + (lane << 3));
        float p0 = 0.f, p1 = 0.f;
        #pragma unroll
        for (int j = 0; j < 8; ++j) { p0 += qf[j] * b2f(k0[j]); p1 += qf[j] * b2f(k1[j]); }
        p0 += __shfl_xor(p0, 1); p1 += __shfl_xor(p1, 1);
        p0 += __shfl_xor(p0, 2); p1 += __shfl_xor(p1, 2);
        p0 += __shfl_xor(p0, 4); p1 += __shfl_xor(p1, 4);
        p0 *= 0.125f; p1 *= 0.125f;
        mx = fmaxf(mx, fmaxf(p0, p1));
        if (!(lane & 7)) {
          sc[(size_t)i * 8 + (lane >> 3)] = p0;
          sc[(size_t)(i + 1) * 8 + (lane >> 3)] = p1;
        }
      }
      if (i < end) {
        int s0 = srcs[i];
        ushort8v k0 = *(const ushort8v*)(qkv + (size_t)s0 * 1536 + 512 + (lane << 3));
        float p0 = 0.f;
        #pragma unroll
        for (int j = 0; j < 8; ++j) p0 += qf[j] * b2f(k0[j]);
        p0 += __shfl_xor(p0, 1);
        p0 += __shfl_xor(p0, 2);
        p0 += __shfl_xor(p0, 4);
        p0 *= 0.125f;
        mx = fmaxf(mx, p0);
        if (!(lane & 7)) sc[(size_t)i * 8 + (lane >> 3)] = p0;
      }
    }
  }
  if (!(lane & 7))
    partm[(((size_t)blockIdx.x << 2) | wid) * 8 + (lane >> 3)] = mx;
}

// ==================== global softmax over edge axis (per head) ==============
template<int OP>   // 0 = max, 1 = sum
__device__ __forceinline__ void reduce8_block(float (&v)[8], float* red) {
  int lane = threadIdx.x & 63, wid = threadIdx.x >> 6;
  #pragma unroll
  for (int h = 0; h < 8; ++h)
    #pragma unroll
    for (int off = 1; off < 64; off <<= 1) {
      float o = __shfl_xor(v[h], off);
      v[h] = OP ? (v[h] + o) : fmaxf(v[h], o);
    }
  if (lane == 0) {
    #pragma unroll
    for (int h = 0; h < 8; ++h) red[h * 4 + wid] = v[h];
  }
  __syncthreads();
  if (threadIdx.x == 0) {
    #pragma unroll
    for (int h = 0; h < 8; ++h) {
      float r = red[h * 4];
      #pragma unroll
      for (int w = 1; w < 4; ++w)
        r = OP ? (r + red[h * 4 + w]) : fmaxf(r, red[h * 4 + w]);
      v[h] = r;
    }
  }
}

// PARALLEL stage-1 max reduce: 256 blocks cover all per-wave partial slots
// (nslots <= 65536: one read per thread), each block writes its max.
__global__ __launch_bounds__(256) void gmax_part_kernel(
    const float* __restrict__ partm, int nslots, float* __restrict__ partm2)
{
  __shared__ float red[32];
  float v[8];
  #pragma unroll
  for (int h = 0; h < 8; ++h) v[h] = -1e30f;
  int stride = gridDim.x * 256;
  for (int i = blockIdx.x * 256 + threadIdx.x; i < nslots; i += stride) {
    #pragma unroll
    for (int h = 0; h < 8; ++h) v[h] = fmaxf(v[h], partm[(size_t)i * 8 + h]);
  }
  reduce8_block<0>(v, red);
  if (threadIdx.x == 0) {
    #pragma unroll
    for (int h = 0; h < 8; ++h) partm2[blockIdx.x * 8 + h] = v[h];
  }
}

// exp pass with stage-2 max reduction fused in (reads 256-block partials)
__global__ __launch_bounds__(256) void sm_exp_partial_kernel(
    float* __restrict__ sc, int E, const float* __restrict__ partm2,
    float* __restrict__ parts)
{
  __shared__ float red[32];
  __shared__ float gmx[8];
  float v[8];
  #pragma unroll
  for (int h = 0; h < 8; ++h) v[h] = partm2[threadIdx.x * 8 + h];
  reduce8_block<0>(v, red);
  if (threadIdx.x == 0) {
    #pragma unroll
    for (int h = 0; h < 8; ++h) gmx[h] = v[h];
  }
  __syncthreads();
  float gm[8];
  #pragma unroll
  for (int h = 0; h < 8; ++h) { gm[h] = gmx[h]; v[h] = 0.f; }
  int stride = gridDim.x * 256;
  for (int e = blockIdx.x * 256 + threadIdx.x; e < E; e += stride) {
    #pragma unroll
    for (int h = 0; h < 8; ++h) {
      float w = __expf(sc[(size_t)e * 8 + h] - gm[h]);
      sc[(size_t)e * 8 + h] = w;           // in-place exp
      v[h] += w;
    }
  }
  reduce8_block<1>(v, red);
  if (threadIdx.x == 0) {
    #pragma unroll
    for (int h = 0; h < 8; ++h) parts[blockIdx.x * 8 + h] = v[h];
  }
}

template<int OP>   // 1: out = 1/sum
__global__ __launch_bounds__(256) void sm_final_kernel(
    const float* __restrict__ part, float* __restrict__ out)
{
  __shared__ float red[32];
  float v[8];
  #pragma unroll
  for (int h = 0; h < 8; ++h) v[h] = part[threadIdx.x * 8 + h];
  reduce8_block<OP>(v, red);
  if (threadIdx.x == 0) {
    #pragma unroll
    for (int h = 0; h < 8; ++h) out[h] = OP ? (1.0f / v[h]) : v[h];
  }
}

// =============================== CSR build ==================================
__global__ __launch_bounds__(256) void hist_kernel(
    const int* __restrict__ ei, int E, int* __restrict__ deg)
{
  int e = blockIdx.x * 256 + threadIdx.x;
  if (e < E) atomicAdd(&deg[ei[E + e]], 1);
}

__global__ __launch_bounds__(1024) void scan_part_kernel(
    const int* __restrict__ deg, int N, int* __restrict__ rowptr,
    int* __restrict__ bsums)
{
  __shared__ int wsum[16];
  int i = blockIdx.x * 1024 + threadIdx.x;
  int lane = threadIdx.x & 63, wid = threadIdx.x >> 6;
  int sv = (i < N) ? deg[i] : 0;
  #pragma unroll
  for (int off = 1; off < 64; off <<= 1) {
    int t = __shfl_up(sv, off);
    if (lane >= off) sv += t;
  }
  if (lane == 63) wsum[wid] = sv;
  __syncthreads();
  if (threadIdx.x < 16) {
    int ws = wsum[threadIdx.x];
    #pragma unroll
    for (int off = 1; off < 16; off <<= 1) {
      int t = __shfl_up(ws, off);
      if (threadIdx.x >= off) ws += t;
    }
    wsum[threadIdx.x] = ws;
  }
  __syncthreads();
  if (wid > 0) sv += wsum[wid - 1];
  if (i < N) rowptr[i + 1] = sv;
  if (threadIdx.x == 1023) bsums[blockIdx.x] = sv;
}

__global__ __launch_bounds__(64) void scan_bsums_kernel(int* bsums, int nb)
{
  int lane = threadIdx.x;
  int v = (lane < nb) ? bsums[lane] : 0;
  #pragma unroll
  for (int off = 1; off < 64; off <<= 1) {
    int t = __shfl_up(v, off);
    if (lane >= off) v += t;
  }
  int ex = __shfl_up(v, 1);
  if (lane == 0) ex = 0;
  if (lane < nb) bsums[lane] = ex;     // exclusive offsets, in place
}

__global__ __launch_bounds__(1024) void scan_add_kernel(
    int* __restrict__ rowptr, const int* __restrict__ bsums, int N)
{
  int i = blockIdx.x * 1024 + threadIdx.x;
  if (i == 0) rowptr[0] = 0;
  if (i < N && blockIdx.x > 0) rowptr[i + 1] += bsums[blockIdx.x];
}

__global__ __launch_bounds__(256) void scatter_kernel(
    const int* __restrict__ ei, int E, const int* __restrict__ rowptr,
    int* __restrict__ cur, int* __restrict__ srcs)
{
  int e = blockIdx.x * 256 + threadIdx.x;
  if (e < E) {
    int dst = ei[E + e];
    int pos = atomicAdd(&cur[dst], 1);
    srcs[rowptr[dst] + pos] = ei[e];
  }
}

// ====== aggregate: agg[n] = sum_{i in CSR(n)} w[i,h] * v[srcs[i]] ==========
__global__ __launch_bounds__(256) void aggregate_kernel(
    const unsigned short* __restrict__ qkv, const float* __restrict__ wexp,
    const float* __restrict__ ginv, const int* __restrict__ srcs,
    const int* __restrict__ rowptr, int N, unsigned short* __restrict__ agg)
{
  int wid = threadIdx.x >> 6, lane = threadIdx.x & 63;
  int n = (blockIdx.x << 2) | wid;
  if (n >= N) return;
  int beg = rowptr[n], end = rowptr[n + 1];
  int h = lane >> 3;
  float inv = ginv[h];
  float acc[8] = {0.f,0.f,0.f,0.f,0.f,0.f,0.f,0.f};
  int i = beg;
  for (; i + 4 <= end; i += 4) {       // 4-edge ILP
    int s0 = srcs[i], s1 = srcs[i + 1], s2 = srcs[i + 2], s3 = srcs[i + 3];
    float w0 = wexp[(size_t)i * 8 + h] * inv;
    float w1 = wexp[(size_t)(i + 1) * 8 + h] * inv;
    float w2 = wexp[(size_t)(i + 2) * 8 + h] * inv;
    float w3 = wexp[(size_t)(i + 3) * 8 + h] * inv;
    ushort8v v0 = *(const ushort8v*)(qkv + (size_t)s0 * 1536 + 1024 + (lane << 3));
    ushort8v v1 = *(const ushort8v*)(qkv + (size_t)s1 * 1536 + 1024 + (lane << 3));
    ushort8v v2 = *(const ushort8v*)(qkv + (size_t)s2 * 1536 + 1024 + (lane << 3));
    ushort8v v3 = *(const ushort8v*)(qkv + (size_t)s3 * 1536 + 1024 + (lane << 3));
    #pragma unroll
    for (int j = 0; j < 8; ++j)
      acc[j] += (w0 * b2f(v0[j]) + w1 * b2f(v1[j]))
              + (w2 * b2f(v2[j]) + w3 * b2f(v3[j]));
  }
  for (; i < end; ++i) {
    int s0 = srcs[i];
    float w0 = wexp[(size_t)i * 8 + h] * inv;
    ushort8v v0 = *(const ushort8v*)(qkv + (size_t)s0 * 1536 + 1024 + (lane << 3));
    #pragma unroll
    for (int j = 0; j < 8; ++j) acc[j] += w0 * b2f(v0[j]);
  }
  ushort8v o;
  #pragma unroll
  for (int j = 0; j < 8; ++j) o[j] = f2b(acc[j]);
  *(ushort8v*)(agg + (size_t)n * 512 + (lane << 3)) = o;
}

// ============== LN(proj + resid)*g + bt, bf16 residual (wave/row) ==========
__global__ __launch_bounds__(256) void ln_kernel(
    const unsigned short* __restrict__ proj, const float* __restrict__ g,
    const float* __restrict__ bt, unsigned short* __restrict__ xb, int N)
{
  int wid = threadIdx.x >> 6, lane = threadIdx.x & 63;
  int n = (blockIdx.x << 2) | wid;
  if (n >= N) return;
  size_t base = (size_t)n * 512 + (lane << 3);
  ushort8v pv = *(const ushort8v*)(proj + base);
  ushort8v xv = *(const ushort8v*)(xb + base);
  float y[8];
  #pragma unroll
  for (int j = 0; j < 8; ++j) y[j] = b2f(pv[j]) + b2f(xv[j]);
  float s = 0.f;
  #pragma unroll
  for (int j = 0; j < 8; ++j) s += y[j];
  #pragma unroll
  for (int off = 1; off < 64; off <<= 1) s += __shfl_xor(s, off);
  float mean = s * (1.f / 512.f);
  float vs = 0.f;
  #pragma unroll
  for (int j = 0; j < 8; ++j) { float d = y[j] - mean; vs += d * d; }
  #pragma unroll
  for (int off = 1; off < 64; off <<= 1) vs += __shfl_xor(vs, off);
  float rstd = rsqrtf(vs * (1.f / 512.f) + 1e-5f);
  int gi = lane << 3;
  ushort8v ob;
  #pragma unroll
  for (int j = 0; j < 8; ++j)
    ob[j] = f2b((y[j] - mean) * rstd * g[gi + j] + bt[gi + j]);
  *(ushort8v*)(xb + base) = ob;
}

// ================================ driver ====================================
extern "C" void kernel_launch(void* const* d_in, const int* in_sizes, int n_in,
                              void* d_out, int out_size, void* d_ws, size_t ws_size,
                              hipStream_t stream)
{
  (void)n_in; (void)out_size;
  const float* feat[3] = {(const float*)d_in[0], (const float*)d_in[1], (const float*)d_in[2]};
  const float* emb[3]  = {(const float*)d_in[3], (const float*)d_in[4], (const float*)d_in[5]};
  const float* pos[3]  = {(const float*)d_in[6], (const float*)d_in[7], (const float*)d_in[8]};
  const float* W[3]  = {(const float*)d_in[9],  (const float*)d_in[13], (const float*)d_in[17]};
  const float* Bb[3] = {(const float*)d_in[10], (const float*)d_in[14], (const float*)d_in[18]};
  const float* G[3]  = {(const float*)d_in[11], (const float*)d_in[15], (const float*)d_in[19]};
  const float* Bt[3] = {(const float*)d_in[12], (const float*)d_in[16], (const float*)d_in[20]};
  const float* headW = (const float*)d_in[21];
  const float* headB = (const float*)d_in[22];
  const int* ei[3] = {(const int*)d_in[23], (const int*)d_in[24], (const int*)d_in[25]};

  int Ns[3], Es[3];
  for (int s = 0; s < 3; ++s) { Ns[s] = in_sizes[s] / 512; Es[s] = in_sizes[23 + s] / 2; }
  int NMAX = Ns[0], EMAX = Es[0];
  for (int s = 1; s < 3; ++s) { if (Ns[s] > NMAX) NMAX = Ns[s]; if (Es[s] > EMAX) EMAX = Es[s]; }

  char* base = (char*)d_ws;
  size_t off = 0;
  auto carve = [&](size_t bytes) -> char* {
    char* r = base + off;
    off += (bytes + 255) & ~(size_t)255;
    return r;
  };
  unsigned short* WT  = (unsigned short*)carve((size_t)27 * 262144 * 2);
  unsigned short* XB  = (unsigned short*)carve((size_t)NMAX * 512 * 2);
  unsigned short* QKV = (unsigned short*)carve((size_t)NMAX * 1536 * 2);
  float*          SC  = (float*)carve((size_t)EMAX * 8 * 4);
  unsigned short* AGG = (unsigned short*)carve((size_t)NMAX * 512 * 2);
  int*   ROWPTR = (int*)carve((size_t)(NMAX + 1) * 4);
  int*   DEG    = (int*)carve((size_t)NMAX * 4);
  int*   SRCS   = (int*)carve((size_t)EMAX * 4);
  int*   BSUMS  = (int*)carve(64 * 4);
  float* PARTM  = (float*)carve((size_t)(NMAX + 8) * 8 * 4);  // per-wave maxes
  float* PARTM2 = (float*)carve(256 * 8 * 4);                 // stage-2 maxes
  float* PARTS  = (float*)carve(256 * 8 * 4);
  float* GINV   = (float*)carve(256);
  unsigned short* PROJ = QKV;    // alias: q/k/v slots dead once aggregate done
  if (off > ws_size) return;     // insufficient workspace: fail loudly

  // weights -> bf16 transposed + column-permuted ("WTs" layout for the GEMM)
  transpose_w_kernel<<<dim3(16,16,8), dim3(32,8), 0, stream>>>(W[0], WT);
  transpose_w_kernel<<<dim3(16,16,8), dim3(32,8), 0, stream>>>(W[1], WT + (size_t)8 * 262144);
  transpose_w_kernel<<<dim3(16,16,8), dim3(32,8), 0, stream>>>(W[2], WT + (size_t)16 * 262144);
  transpose_w_kernel<<<dim3(16,16,3), dim3(32,8), 0, stream>>>(headW, WT + (size_t)24 * 262144);

  size_t out_off = 0;
  for (int s = 0; s < 3; ++s) {
    const int N = Ns[s], E = Es[s];
    const int mt = (N + 255) >> 8;           // 256-row tiles
    const int nb = (N + 1023) / 1024;
    const int nsb = (N + 3) / 4;             // score blocks (4 waves each)

    init_x_kernel<<<2048, 256, 0, stream>>>(
        (const float4*)feat[s], (const float4*)emb[s], (const float4*)pos[s],
        XB, (long long)N * 128);

    // CSR by dst (edge index is constant per stream; built once, used 2x)
    hipMemsetAsync(DEG, 0, (size_t)N * 4, stream);
    hist_kernel<<<(E + 255) / 256, 256, 0, stream>>>(ei[s], E, DEG);
    scan_part_kernel<<<nb, 1024, 0, stream>>>(DEG, N, ROWPTR, BSUMS);
    scan_bsums_kernel<<<1, 64, 0, stream>>>(BSUMS, nb);
    scan_add_kernel<<<nb, 1024, 0, stream>>>(ROWPTR, BSUMS, N);
    hipMemsetAsync(DEG, 0, (size_t)N * 4, stream);
    scatter_kernel<<<(E + 255) / 256, 256, 0, stream>>>(ei[s], E, ROWPTR, DEG, SRCS);

    for (int l = 0; l < 2; ++l) {
      const unsigned short* Wqkv = WT + (size_t)(s * 8 + l * 4) * 262144;
      const unsigned short* Wo   = WT + (size_t)(s * 8 + l * 4 + 3) * 262144;
      const float* bqkv = Bb[s] + (size_t)l * 4 * 512;       // q,k,v biases contiguous
      const float* bo   = Bb[s] + (size_t)(l * 4 + 3) * 512;

      gemm_bt_kernel<1><<<dim3(mt * 6), 512, 0, stream>>>(XB, Wqkv, bqkv, QKV, N, 1536);
      csr_scores_kernel<<<nsb, 256, 0, stream>>>(QKV, SRCS, ROWPTR, N, SC, PARTM);
      gmax_part_kernel<<<256, 256, 0, stream>>>(PARTM, nsb * 4, PARTM2);
      sm_exp_partial_kernel<<<256, 256, 0, stream>>>(SC, E, PARTM2, PARTS);
      sm_final_kernel<1><<<1, 256, 0, stream>>>(PARTS, GINV);
      aggregate_kernel<<<nsb, 256, 0, stream>>>(QKV, SC, GINV, SRCS, ROWPTR, N, AGG);
      gemm_bt_kernel<1><<<dim3(mt * 2), 512, 0, stream>>>(AGG, Wo, bo, PROJ, N, 512);
      ln_kernel<<<nsb, 256, 0, stream>>>(PROJ, G[s] + (size_t)l * 512,
                                         Bt[s] + (size_t)l * 512, XB, N);
    }

    gemm_bt_kernel<0><<<dim3(mt * 2), 512, 0, stream>>>(
        XB, WT + (size_t)(24 + s) * 262144, headB + (size_t)s * 512,
        (float*)d_out + out_off, N, 512);
    out_off += (size_t)N * 512;
  }
}

// Round 12
// 1314.424 us; speedup vs baseline: 1.1746x; 1.0292x over previous
//
#include <hip/hip_runtime.h>

// ---------------------------------------------------------------------------
// SimplicialAttentionTransformer: 3 streams x (embed-add, 2x[QKV gemm,
// CSR-ordered edge scores (+fused online (max,sumexp) partials), 2-stage
// pair-combine, aggregate with on-the-fly softmax weights, proj gemm, LN],
// head gemm). bf16 residual stream. Big GEMM (Ncols>=1536): 256x256 tile,
// 8 waves, 4-phase dbuf schedule (frozen). Small GEMM (Ncols=512): 128x128
// tile, 4 waves, single-buffer (occupancy-driven). Both: global_load_lds
// staging w/ XOR-swizzled source, swapped-operand MFMA + permuted weights
// -> 16 consecutive cols/lane, fully coalesced stores.
// ---------------------------------------------------------------------------

typedef __attribute__((ext_vector_type(8))) __bf16 bf16x8;
typedef __attribute__((ext_vector_type(4))) float f32x4;
typedef __attribute__((ext_vector_type(8))) unsigned short ushort8v;
typedef __attribute__((ext_vector_type(4))) unsigned short ushort4v;

__device__ __forceinline__ float b2f(unsigned short u) {
  union { unsigned u; float f; } x; x.u = (unsigned)u << 16; return x.f;
}
__device__ __forceinline__ unsigned short f2b(float f) {
  union { float f; unsigned u; } x; x.f = f;
  unsigned r = x.u + 0x7fffu + ((x.u >> 16) & 1u);   // RNE
  return (unsigned short)(r >> 16);
}

// ======================= xb = bf16(a + b + c) ==============================
__global__ __launch_bounds__(256) void init_x_kernel(
    const float4* __restrict__ a, const float4* __restrict__ b,
    const float4* __restrict__ c, unsigned short* __restrict__ xb,
    long long n4)
{
  long long stride = (long long)gridDim.x * 256;
  for (long long i = (long long)blockIdx.x * 256 + threadIdx.x; i < n4; i += stride) {
    float4 av = a[i], bv = b[i], cv = c[i];
    ushort4v o;
    o.x = f2b(av.x + bv.x + cv.x); o.y = f2b(av.y + bv.y + cv.y);
    o.z = f2b(av.z + bv.z + cv.z); o.w = f2b(av.w + bv.w + cv.w);
    *(ushort4v*)(xb + i * 4) = o;
  }
}

// ============== weight transpose fp32[512][512] -> bf16 WT[perm(c)][r] =====
// perm swaps bits [5:4] <-> [3:2] within each 64-col block (involution).
__global__ __launch_bounds__(256) void transpose_w_kernel(
    const float* __restrict__ W, unsigned short* __restrict__ WT)
{
  __shared__ float t[32][33];
  const float* src = W + (size_t)blockIdx.z * 262144;
  unsigned short* dst = WT + (size_t)blockIdx.z * 262144;
  int bx = blockIdx.x * 32, by = blockIdx.y * 32;
  int tx = threadIdx.x, ty = threadIdx.y;   // block 32x8
  #pragma unroll
  for (int i = 0; i < 32; i += 8)
    t[ty + i][tx] = src[(size_t)(by + ty + i) * 512 + bx + tx];
  __syncthreads();
  #pragma unroll
  for (int i = 0; i < 32; i += 8) {
    int c = bx + ty + i;
    int p = (c & ~0x3C) | ((c & 0x30) >> 2) | ((c & 0x0C) << 2);
    dst[(size_t)p * 512 + by + tx] = f2b(t[tx][ty + i]);
  }
}

// ========================== shared GEMM helpers ============================
__device__ __forceinline__ void stage16(const void* g, void* lds_uniform) {
  __builtin_amdgcn_global_load_lds(
      (const __attribute__((address_space(1))) void*)g,
      (__attribute__((address_space(3))) void*)lds_uniform, 16, 0, 0);
}
__device__ __forceinline__ int xcd_swizzle(int orig, int nwg) {
  const int xcd = orig & 7, lin = orig >> 3;
  const int q = nwg >> 3, r8 = nwg & 7;
  return (xcd < r8 ? xcd * (q + 1) : r8 * (q + 1) + (xcd - r8) * q) + lin;
}

// =================== big bf16 GEMM (256x256, 8 waves) ======================
template<int OUT_BF16>
__global__ __launch_bounds__(512, 2) void gemm_bt_kernel(
    const unsigned short* __restrict__ A,
    const unsigned short* __restrict__ BT,
    const float* __restrict__ bias,
    void* __restrict__ Cv,
    int M, int Ncols)
{
  constexpr int K = 512;
  __shared__ unsigned short smem[65536];

  const int wgid = xcd_swizzle(blockIdx.x, gridDim.x);
  const int tiles_n = Ncols >> 8;
  const int tm = wgid / tiles_n;
  const int tn = wgid - tm * tiles_n;
  const int row0 = tm << 8, col0 = tn << 8;
  const int lane = threadIdx.x & 63, wid = threadIdx.x >> 6;
  const int wr = (wid >> 2) << 7;   // M-half: 0 / 128
  const int wc = (wid & 3) << 6;    // N-quarter: 0/64/128/192

  f32x4 acc[8][4];
  #pragma unroll
  for (int i = 0; i < 8; ++i)
    #pragma unroll
    for (int j = 0; j < 4; ++j) acc[i][j] = (f32x4)0.f;

  int srow[4], scsw[4], sseg[4];
  #pragma unroll
  for (int i = 0; i < 4; ++i) {
    int seg = (i << 3) | wid;
    int idx = (seg << 6) | lane;
    int row = idx >> 3, ch = idx & 7;
    sseg[i] = seg; srow[i] = row; scsw[i] = ch ^ (row & 7);
  }

  #define STG_PAIR(buf, kb_, i)                                               \
    { int ra = row0 + srow[i]; ra = (ra < M) ? ra : (M - 1);                  \
      stage16(A + (size_t)ra * K + (kb_) + (scsw[i] << 3),                    \
              smem + (buf) * 32768 + (sseg[i] << 9));                         \
      int rb = col0 + srow[i];                                                \
      stage16(BT + (size_t)rb * K + (kb_) + (scsw[i] << 3),                   \
              smem + (buf) * 32768 + 16384 + (sseg[i] << 9)); }

  STG_PAIR(0, 0, 0) STG_PAIR(0, 0, 1) STG_PAIR(0, 0, 2) STG_PAIR(0, 0, 3)
  __syncthreads();

  const int lm = lane & 15;
  const int kbl = (lane >> 4) << 4;

  #pragma unroll
  for (int kt = 0; kt < 8; ++kt) {
    const int cur = kt & 1, nxt = cur ^ 1, kb1 = (kt + 1) << 6;
    const char* Asb = (const char*)(smem + cur * 32768);
    const char* Bsb = Asb + 32768;

    auto rdA = [&](int mi, int kk) -> bf16x8 {
      int r = wr + (mi << 4) + lm;
      int kb = (kk << 6) + kbl;
      return *(const bf16x8*)(Asb + (r << 7) + (kb ^ ((r & 7) << 4)));
    };
    auto rdB = [&](int ni, int kk) -> bf16x8 {
      int r = wc + (ni << 4) + lm;
      int kb = (kk << 6) + kbl;
      return *(const bf16x8*)(Bsb + (r << 7) + (kb ^ ((r & 7) << 4)));
    };

    bf16x8 av[4], bv[4];

    #pragma unroll
    for (int i = 0; i < 4; ++i) { av[i] = rdA(i, 0); bv[i] = rdB(i, 0); }
    if (kt < 7) { STG_PAIR(nxt, kb1, 0) STG_PAIR(nxt, kb1, 1) }
    __builtin_amdgcn_s_barrier();
    __builtin_amdgcn_s_setprio(1);
    #pragma unroll
    for (int mi = 0; mi < 4; ++mi)
      #pragma unroll
      for (int ni = 0; ni < 4; ++ni)
        acc[mi][ni] = __builtin_amdgcn_mfma_f32_16x16x32_bf16(
            bv[ni], av[mi], acc[mi][ni], 0, 0, 0);
    __builtin_amdgcn_s_setprio(0);
    __builtin_amdgcn_s_barrier();

    #pragma unroll
    for (int i = 0; i < 4; ++i) av[i] = rdA(4 + i, 0);
    if (kt < 7) { STG_PAIR(nxt, kb1, 2) STG_PAIR(nxt, kb1, 3) }
    __builtin_amdgcn_s_barrier();
    __builtin_amdgcn_s_setprio(1);
    #pragma unroll
    for (int mi = 0; mi < 4; ++mi)
      #pragma unroll
      for (int ni = 0; ni < 4; ++ni)
        acc[4 + mi][ni] = __builtin_amdgcn_mfma_f32_16x16x32_bf16(
            bv[ni], av[mi], acc[4 + mi][ni], 0, 0, 0);
    __builtin_amdgcn_s_setprio(0);
    __builtin_amdgcn_s_barrier();

    #pragma unroll
    for (int i = 0; i < 4; ++i) { av[i] = rdA(i, 1); bv[i] = rdB(i, 1); }
    __builtin_amdgcn_s_barrier();
    __builtin_amdgcn_s_setprio(1);
    #pragma unroll
    for (int mi = 0; mi < 4; ++mi)
      #pragma unroll
      for (int ni = 0; ni < 4; ++ni)
        acc[mi][ni] = __builtin_amdgcn_mfma_f32_16x16x32_bf16(
            bv[ni], av[mi], acc[mi][ni], 0, 0, 0);
    __builtin_amdgcn_s_setprio(0);
    __builtin_amdgcn_s_barrier();

    #pragma unroll
    for (int i = 0; i < 4; ++i) av[i] = rdA(4 + i, 1);
    __builtin_amdgcn_s_barrier();
    __builtin_amdgcn_s_setprio(1);
    #pragma unroll
    for (int mi = 0; mi < 4; ++mi)
      #pragma unroll
      for (int ni = 0; ni < 4; ++ni)
        acc[4 + mi][ni] = __builtin_amdgcn_mfma_f32_16x16x32_bf16(
            bv[ni], av[mi], acc[4 + mi][ni], 0, 0, 0);
    __builtin_amdgcn_s_setprio(0);

    __syncthreads();
  }
  #undef STG_PAIR

  const int mrow = lane & 15;
  const int t4 = (lane >> 4) << 4;
  float bsv[16];
  #pragma unroll
  for (int ni = 0; ni < 4; ++ni) {
    float4 bvv = *(const float4*)(bias + col0 + wc + t4 + (ni << 2));
    bsv[4*ni+0] = bvv.x; bsv[4*ni+1] = bvv.y; bsv[4*ni+2] = bvv.z; bsv[4*ni+3] = bvv.w;
  }

  if (OUT_BF16) {
    unsigned short* C = (unsigned short*)Cv;
    #pragma unroll
    for (int mi = 0; mi < 8; ++mi) {
      int rowg = row0 + wr + (mi << 4) + mrow;
      if (rowg < M) {
        ushort8v o0, o1;
        #pragma unroll
        for (int r = 0; r < 4; ++r) {
          o0[r]     = f2b(acc[mi][0][r] + bsv[r]);
          o0[4 + r] = f2b(acc[mi][1][r] + bsv[4 + r]);
          o1[r]     = f2b(acc[mi][2][r] + bsv[8 + r]);
          o1[4 + r] = f2b(acc[mi][3][r] + bsv[12 + r]);
        }
        unsigned short* cp = C + (size_t)rowg * Ncols + col0 + wc + t4;
        *(ushort8v*)cp = o0;
        *(ushort8v*)(cp + 8) = o1;
      }
    }
  } else {
    float* C = (float*)Cv;
    #pragma unroll
    for (int mi = 0; mi < 8; ++mi) {
      int rowg = row0 + wr + (mi << 4) + mrow;
      if (rowg < M) {
        float* cp = C + (size_t)rowg * Ncols + col0 + wc + t4;
        #pragma unroll
        for (int ni = 0; ni < 4; ++ni) {
          float4 v;
          v.x = acc[mi][ni][0] + bsv[4*ni+0];
          v.y = acc[mi][ni][1] + bsv[4*ni+1];
          v.z = acc[mi][ni][2] + bsv[4*ni+2];
          v.w = acc[mi][ni][3] + bsv[4*ni+3];
          *(float4*)(cp + (ni << 2)) = v;
        }
      }
    }
  }
}

// ========= small bf16 GEMM (128x128, 4 waves, high occupancy) ==============
// For Ncols=512 (proj/head): 4x the block count of the 256^2 kernel ->
// avoids CU under-subscription; single-buffer staging (cross-block overlap
// at ~5 blocks/CU hides stage latency). Same permuted-weight epilogue.
template<int OUT_BF16>
__global__ __launch_bounds__(256) void gemm_sm_kernel(
    const unsigned short* __restrict__ A,
    const unsigned short* __restrict__ BT,
    const float* __restrict__ bias,
    void* __restrict__ Cv,
    int M, int Ncols)
{
  constexpr int K = 512;
  __shared__ unsigned short As[8192];   // 128 x 64 bf16 (128B rows)
  __shared__ unsigned short Bs[8192];

  const int wgid = xcd_swizzle(blockIdx.x, gridDim.x);
  const int tiles_n = Ncols >> 7;
  const int tm = wgid / tiles_n;
  const int tn = wgid - tm * tiles_n;
  const int row0 = tm << 7, col0 = tn << 7;
  const int lane = threadIdx.x & 63, wid = threadIdx.x >> 6;
  const int wm = (wid >> 1) << 6, wn = (wid & 1) << 6;

  f32x4 acc[4][4];
  #pragma unroll
  for (int i = 0; i < 4; ++i)
    #pragma unroll
    for (int j = 0; j < 4; ++j) acc[i][j] = (f32x4)0.f;

  int srow[4], scsw[4], sseg[4];
  #pragma unroll
  for (int i = 0; i < 4; ++i) {
    int seg = (i << 2) | wid;
    int idx = (seg << 6) | lane;
    int row = idx >> 3, ch = idx & 7;
    sseg[i] = seg; srow[i] = row; scsw[i] = ch ^ (row & 7);
  }

  #pragma unroll
  for (int kt = 0; kt < 8; ++kt) {
    const int kbase = kt << 6;
    #pragma unroll
    for (int i = 0; i < 4; ++i) {
      int ra = row0 + srow[i]; ra = (ra < M) ? ra : (M - 1);
      stage16(A + (size_t)ra * K + kbase + (scsw[i] << 3), As + (sseg[i] << 9));
      int rb = col0 + srow[i];
      stage16(BT + (size_t)rb * K + kbase + (scsw[i] << 3), Bs + (sseg[i] << 9));
    }
    asm volatile("s_waitcnt vmcnt(0)" ::: "memory");
    __syncthreads();

    #pragma unroll
    for (int kk = 0; kk < 2; ++kk) {
      const int kb = (kk << 6) + ((lane >> 4) << 4);
      bf16x8 af[4], bfr[4];
      #pragma unroll
      for (int mi = 0; mi < 4; ++mi) {
        int r = wm + (mi << 4) + (lane & 15);
        af[mi] = *(const bf16x8*)((const char*)As + (r << 7) + (kb ^ ((r & 7) << 4)));
      }
      #pragma unroll
      for (int ni = 0; ni < 4; ++ni) {
        int r = wn + (ni << 4) + (lane & 15);
        bfr[ni] = *(const bf16x8*)((const char*)Bs + (r << 7) + (kb ^ ((r & 7) << 4)));
      }
      #pragma unroll
      for (int mi = 0; mi < 4; ++mi)
        #pragma unroll
        for (int ni = 0; ni < 4; ++ni)
          acc[mi][ni] = __builtin_amdgcn_mfma_f32_16x16x32_bf16(
              bfr[ni], af[mi], acc[mi][ni], 0, 0, 0);
    }
    __syncthreads();
  }

  const int mrow = lane & 15;
  const int t4 = (lane >> 4) << 4;
  float bsv[16];
  #pragma unroll
  for (int ni = 0; ni < 4; ++ni) {
    float4 bvv = *(const float4*)(bias + col0 + wn + t4 + (ni << 2));
    bsv[4*ni+0] = bvv.x; bsv[4*ni+1] = bvv.y; bsv[4*ni+2] = bvv.z; bsv[4*ni+3] = bvv.w;
  }

  if (OUT_BF16) {
    unsigned short* C = (unsigned short*)Cv;
    #pragma unroll
    for (int mi = 0; mi < 4; ++mi) {
      int rowg = row0 + wm + (mi << 4) + mrow;
      if (rowg < M) {
        ushort8v o0, o1;
        #pragma unroll
        for (int r = 0; r < 4; ++r) {
          o0[r]     = f2b(acc[mi][0][r] + bsv[r]);
          o0[4 + r] = f2b(acc[mi][1][r] + bsv[4 + r]);
          o1[r]     = f2b(acc[mi][2][r] + bsv[8 + r]);
          o1[4 + r] = f2b(acc[mi][3][r] + bsv[12 + r]);
        }
        unsigned short* cp = C + (size_t)rowg * Ncols + col0 + wn + t4;
        *(ushort8v*)cp = o0;
        *(ushort8v*)(cp + 8) = o1;
      }
    }
  } else {
    float* C = (float*)Cv;
    #pragma unroll
    for (int mi = 0; mi < 4; ++mi) {
      int rowg = row0 + wm + (mi << 4) + mrow;
      if (rowg < M) {
        float* cp = C + (size_t)rowg * Ncols + col0 + wn + t4;
        #pragma unroll
        for (int ni = 0; ni < 4; ++ni) {
          float4 v;
          v.x = acc[mi][ni][0] + bsv[4*ni+0];
          v.y = acc[mi][ni][1] + bsv[4*ni+1];
          v.z = acc[mi][ni][2] + bsv[4*ni+2];
          v.w = acc[mi][ni][3] + bsv[4*ni+3];
          *(float4*)(cp + (ni << 2)) = v;
        }
      }
    }
  }
}

// ====== CSR-ordered edge scores + fused ONLINE (max, sumexp) partials ======
// One wave per dst node n; xor-reduce broadcasts each head-score to all 8
// lanes of its head group, so each lane tracks a running (max, sum_exp)
// online-softmax pair for free. Empty waves emit (-1e30, 0).
__global__ __launch_bounds__(256) void csr_scores_kernel(
    const unsigned short* __restrict__ qkv, const int* __restrict__ srcs,
    const int* __restrict__ rowptr, int N, float* __restrict__ sc,
    float* __restrict__ partm, float* __restrict__ parts)
{
  int wid = threadIdx.x >> 6, lane = threadIdx.x & 63;
  int n = (blockIdx.x << 2) | wid;
  float mx = -1e30f, sm = 0.f;
  if (n < N) {
    int beg = rowptr[n], end = rowptr[n + 1];
    if (beg < end) {
      ushort8v qv = *(const ushort8v*)(qkv + (size_t)n * 1536 + (lane << 3));
      float qf[8];
      #pragma unroll
      for (int j = 0; j < 8; ++j) qf[j] = b2f(qv[j]);
      int i = beg;
      for (; i + 2 <= end; i += 2) {       // 2-edge ILP
        int s0 = srcs[i], s1 = srcs[i + 1];
        ushort8v k0 = *(const ushort8v*)(qkv + (size_t)s0 * 1536 + 512 + (lane << 3));
        ushort8v k1 = *(const ushort8v*)(qkv + (size_t)s1 * 1536 + 512 + (lane << 3));
        float p0 = 0.f, p1 = 0.f;
        #pragma unroll
        for (int j = 0; j < 8; ++j) { p0 += qf[j] * b2f(k0[j]); p1 += qf[j] * b2f(k1[j]); }
        p0 += __shfl_xor(p0, 1); p1 += __shfl_xor(p1, 1);
        p0 += __shfl_xor(p0, 2); p1 += __shfl_xor(p1, 2);
        p0 += __shfl_xor(p0, 4); p1 += __shfl_xor(p1, 4);
        p0 *= 0.125f; p1 *= 0.125f;
        float nm = fmaxf(mx, fmaxf(p0, p1));
        sm = sm * __expf(mx - nm) + __expf(p0 - nm) + __expf(p1 - nm);
        mx = nm;
        if (!(lane & 7)) {
          sc[(size_t)i * 8 + (lane >> 3)] = p0;
          sc[(size_t)(i + 1) * 8 + (lane >> 3)] = p1;
        }
      }
      if (i < end) {
        int s0 = srcs[i];
        ushort8v k0 = *(const ushort8v*)(qkv + (size_t)s0 * 1536 + 512 + (lane << 3));
        float p0 = 0.f;
        #pragma unroll
        for (int j = 0; j < 8; ++j) p0 += qf[j] * b2f(k0[j]);
        p0 += __shfl_xor(p0, 1);
        p0 += __shfl_xor(p0, 2);
        p0 += __shfl_xor(p0, 4);
        p0 *= 0.125f;
        float nm = fmaxf(mx, p0);
        sm = sm * __expf(mx - nm) + __expf(p0 - nm);
        mx = nm;
        if (!(lane & 7)) sc[(size_t)i * 8 + (lane >> 3)] = p0;
      }
    }
  }
  if (!(lane & 7)) {
    size_t slot = ((size_t)blockIdx.x << 2) | wid;
    partm[slot * 8 + (lane >> 3)] = mx;
    parts[slot * 8 + (lane >> 3)] = sm;
  }
}

// ============ (max,sum) pair block reduce: (m1,s1)+(m2,s2) -> (M, ...) =====
__device__ __forceinline__ void pair_reduce_block(
    float (&m)[8], float (&s)[8], float* redm, float* reds)
{
  int lane = threadIdx.x & 63, wid = threadIdx.x >> 6;
  #pragma unroll
  for (int h = 0; h < 8; ++h)
    #pragma unroll
    for (int off = 1; off < 64; off <<= 1) {
      float om = __shfl_xor(m[h], off);
      float os = __shfl_xor(s[h], off);
      float M = fmaxf(m[h], om);
      s[h] = s[h] * __expf(m[h] - M) + os * __expf(om - M);
      m[h] = M;
    }
  if (lane == 0) {
    #pragma unroll
    for (int h = 0; h < 8; ++h) { redm[h * 4 + wid] = m[h]; reds[h * 4 + wid] = s[h]; }
  }
  __syncthreads();
  if (threadIdx.x == 0) {
    #pragma unroll
    for (int h = 0; h < 8; ++h) {
      float M = redm[h * 4], S = reds[h * 4];
      #pragma unroll
      for (int w = 1; w < 4; ++w) {
        float om = redm[h * 4 + w], os = reds[h * 4 + w];
        float nM = fmaxf(M, om);
        S = S * __expf(M - nM) + os * __expf(om - nM);
        M = nM;
      }
      m[h] = M; s[h] = S;
    }
  }
}

// stage-1 parallel combine: 256 blocks over all per-wave (max,sum) slots
__global__ __launch_bounds__(256) void gms_part_kernel(
    const float* __restrict__ pm, const float* __restrict__ ps, int nslots,
    float* __restrict__ pm2, float* __restrict__ ps2)
{
  __shared__ float redm[32], reds[32];
  float m[8], s[8];
  #pragma unroll
  for (int h = 0; h < 8; ++h) { m[h] = -1e30f; s[h] = 0.f; }
  int stride = gridDim.x * 256;
  for (int i = blockIdx.x * 256 + threadIdx.x; i < nslots; i += stride) {
    #pragma unroll
    for (int h = 0; h < 8; ++h) {
      float mi = pm[(size_t)i * 8 + h], si = ps[(size_t)i * 8 + h];
      float M = fmaxf(m[h], mi);
      s[h] = s[h] * __expf(m[h] - M) + si * __expf(mi - M);
      m[h] = M;
    }
  }
  pair_reduce_block(m, s, redm, reds);
  if (threadIdx.x == 0) {
    #pragma unroll
    for (int h = 0; h < 8; ++h) { pm2[blockIdx.x * 8 + h] = m[h]; ps2[blockIdx.x * 8 + h] = s[h]; }
  }
}

// stage-2 final combine (1 block, 256 slots) -> gmax[8], ginv[8]
__global__ __launch_bounds__(256) void gms_final_kernel(
    const float* __restrict__ pm2, const float* __restrict__ ps2,
    float* __restrict__ gmax, float* __restrict__ ginv)
{
  __shared__ float redm[32], reds[32];
  float m[8], s[8];
  #pragma unroll
  for (int h = 0; h < 8; ++h) {
    m[h] = pm2[threadIdx.x * 8 + h];
    s[h] = ps2[threadIdx.x * 8 + h];
  }
  pair_reduce_block(m, s, redm, reds);
  if (threadIdx.x == 0) {
    #pragma unroll
    for (int h = 0; h < 8; ++h) { gmax[h] = m[h]; ginv[h] = 1.0f / s[h]; }
  }
}

// =============================== CSR build ==================================
__global__ __launch_bounds__(256) void hist_kernel(
    const int* __restrict__ ei, int E, int* __restrict__ deg)
{
  int e = blockIdx.x * 256 + threadIdx.x;
  if (e < E) atomicAdd(&deg[ei[E + e]], 1);
}

__global__ __launch_bounds__(1024) void scan_part_kernel(
    const int* __restrict__ deg, int N, int* __restrict__ rowptr,
    int* __restrict__ bsums)
{
  __shared__ int wsum[16];
  int i = blockIdx.x * 1024 + threadIdx.x;
  int lane = threadIdx.x & 63, wid = threadIdx.x >> 6;
  int sv = (i < N) ? deg[i] : 0;
  #pragma unroll
  for (int off = 1; off < 64; off <<= 1) {
    int t = __shfl_up(sv, off);
    if (lane >= off) sv += t;
  }
  if (lane == 63) wsum[wid] = sv;
  __syncthreads();
  if (threadIdx.x < 16) {
    int ws = wsum[threadIdx.x];
    #pragma unroll
    for (int off = 1; off < 16; off <<= 1) {
      int t = __shfl_up(ws, off);
      if (threadIdx.x >= off) ws += t;
    }
    wsum[threadIdx.x] = ws;
  }
  __syncthreads();
  if (wid > 0) sv += wsum[wid - 1];
  if (i < N) rowptr[i + 1] = sv;
  if (threadIdx.x == 1023) bsums[blockIdx.x] = sv;
}

__global__ __launch_bounds__(64) void scan_bsums_kernel(int* bsums, int nb)
{
  int lane = threadIdx.x;
  int v = (lane < nb) ? bsums[lane] : 0;
  #pragma unroll
  for (int off = 1; off < 64; off <<= 1) {
    int t = __shfl_up(v, off);
    if (lane >= off) v += t;
  }
  int ex = __shfl_up(v, 1);
  if (lane == 0) ex = 0;
  if (lane < nb) bsums[lane] = ex;
}

__global__ __launch_bounds__(1024) void scan_add_kernel(
    int* __restrict__ rowptr, const int* __restrict__ bsums, int N)
{
  int i = blockIdx.x * 1024 + threadIdx.x;
  if (i == 0) rowptr[0] = 0;
  if (i < N && blockIdx.x > 0) rowptr[i + 1] += bsums[blockIdx.x];
}

__global__ __launch_bounds__(256) void scatter_kernel(
    const int* __restrict__ ei, int E, const int* __restrict__ rowptr,
    int* __restrict__ cur, int* __restrict__ srcs)
{
  int e = blockIdx.x * 256 + threadIdx.x;
  if (e < E) {
    int dst = ei[E + e];
    int pos = atomicAdd(&cur[dst], 1);
    srcs[rowptr[dst] + pos] = ei[e];
  }
}

// == aggregate: agg[n] = sum_i exp(sc_i - gmax)*ginv * v[srcs[i]] (on the fly)
__global__ __launch_bounds__(256) void aggregate_kernel(
    const unsigned short* __restrict__ qkv, const float* __restrict__ sc,
    const float* __restrict__ gmax, const float* __restrict__ ginv,
    const int* __restrict__ srcs, const int* __restrict__ rowptr,
    int N, unsigned short* __restrict__ agg)
{
  int wid = threadIdx.x >> 6, lane = threadIdx.x & 63;
  int n = (blockIdx.x << 2) | wid;
  if (n >= N) return;
  int beg = rowptr[n], end = rowptr[n + 1];
  int h = lane >> 3;
  float gm = gmax[h];
  float inv = ginv[h];
  float acc[8] = {0.f,0.f,0.f,0.f,0.f,0.f,0.f,0.f};
  int i = beg;
  for (; i + 4 <= end; i += 4) {       // 4-edge ILP
    int s0 = srcs[i], s1 = srcs[i + 1], s2 = srcs[i + 2], s3 = srcs[i + 3];
    float w0 = __expf(sc[(size_t)i * 8 + h] - gm) * inv;
    float w1 = __expf(sc[(size_t)(i + 1) * 8 + h] - gm) * inv;
    float w2 = __expf(sc[(size_t)(i + 2) * 8 + h] - gm) * inv;
    float w3 = __expf(sc[(size_t)(i + 3) * 8 + h] - gm) * inv;
    ushort8v v0 = *(const ushort8v*)(qkv + (size_t)s0 * 1536 + 1024 + (lane << 3));
    ushort8v v1 = *(const ushort8v*)(qkv + (size_t)s1 * 1536 + 1024 + (lane << 3));
    ushort8v v2 = *(const ushort8v*)(qkv + (size_t)s2 * 1536 + 1024 + (lane << 3));
    ushort8v v3 = *(const ushort8v*)(qkv + (size_t)s3 * 1536 + 1024 + (lane << 3));
    #pragma unroll
    for (int j = 0; j < 8; ++j)
      acc[j] += (w0 * b2f(v0[j]) + w1 * b2f(v1[j]))
              + (w2 * b2f(v2[j]) + w3 * b2f(v3[j]));
  }
  for (; i < end; ++i) {
    int s0 = srcs[i];
    float w0 = __expf(sc[(size_t)i * 8 + h] - gm) * inv;
    ushort8v v0 = *(const ushort8v*)(qkv + (size_t)s0 * 1536 + 1024 + (lane << 3));
    #pragma unroll
    for (int j = 0; j < 8; ++j) acc[j] += w0 * b2f(v0[j]);
  }
  ushort8v o;
  #pragma unroll
  for (int j = 0; j < 8; ++j) o[j] = f2b(acc[j]);
  *(ushort8v*)(agg + (size_t)n * 512 + (lane << 3)) = o;
}

// ============== LN(proj + resid)*g + bt, bf16 residual (wave/row) ==========
__global__ __launch_bounds__(256) void ln_kernel(
    const unsigned short* __restrict__ proj, const float* __restrict__ g,
    const float* __restrict__ bt, unsigned short* __restrict__ xb, int N)
{
  int wid = threadIdx.x >> 6, lane = threadIdx.x & 63;
  int n = (blockIdx.x << 2) | wid;
  if (n >= N) return;
  size_t base = (size_t)n * 512 + (lane << 3);
  ushort8v pv = *(const ushort8v*)(proj + base);
  ushort8v xv = *(const ushort8v*)(xb + base);
  float y[8];
  #pragma unroll
  for (int j = 0; j < 8; ++j) y[j] = b2f(pv[j]) + b2f(xv[j]);
  float s = 0.f;
  #pragma unroll
  for (int j = 0; j < 8; ++j) s += y[j];
  #pragma unroll
  for (int off = 1; off < 64; off <<= 1) s += __shfl_xor(s, off);
  float mean = s * (1.f / 512.f);
  float vs = 0.f;
  #pragma unroll
  for (int j = 0; j < 8; ++j) { float d = y[j] - mean; vs += d * d; }
  #pragma unroll
  for (int off = 1; off < 64; off <<= 1) vs += __shfl_xor(vs, off);
  float rstd = rsqrtf(vs * (1.f / 512.f) + 1e-5f);
  int gi = lane << 3;
  ushort8v ob;
  #pragma unroll
  for (int j = 0; j < 8; ++j)
    ob[j] = f2b((y[j] - mean) * rstd * g[gi + j] + bt[gi + j]);
  *(ushort8v*)(xb + base) = ob;
}

// ================================ driver ====================================
extern "C" void kernel_launch(void* const* d_in, const int* in_sizes, int n_in,
                              void* d_out, int out_size, void* d_ws, size_t ws_size,
                              hipStream_t stream)
{
  (void)n_in; (void)out_size;
  const float* feat[3] = {(const float*)d_in[0], (const float*)d_in[1], (const float*)d_in[2]};
  const float* emb[3]  = {(const float*)d_in[3], (const float*)d_in[4], (const float*)d_in[5]};
  const float* pos[3]  = {(const float*)d_in[6], (const float*)d_in[7], (const float*)d_in[8]};
  const float* W[3]  = {(const float*)d_in[9],  (const float*)d_in[13], (const float*)d_in[17]};
  const float* Bb[3] = {(const float*)d_in[10], (const float*)d_in[14], (const float*)d_in[18]};
  const float* G[3]  = {(const float*)d_in[11], (const float*)d_in[15], (const float*)d_in[19]};
  const float* Bt[3] = {(const float*)d_in[12], (const float*)d_in[16], (const float*)d_in[20]};
  const float* headW = (const float*)d_in[21];
  const float* headB = (const float*)d_in[22];
  const int* ei[3] = {(const int*)d_in[23], (const int*)d_in[24], (const int*)d_in[25]};

  int Ns[3], Es[3];
  for (int s = 0; s < 3; ++s) { Ns[s] = in_sizes[s] / 512; Es[s] = in_sizes[23 + s] / 2; }
  int NMAX = Ns[0], EMAX = Es[0];
  for (int s = 1; s < 3; ++s) { if (Ns[s] > NMAX) NMAX = Ns[s]; if (Es[s] > EMAX) EMAX = Es[s]; }

  char* base = (char*)d_ws;
  size_t off = 0;
  auto carve = [&](size_t bytes) -> char* {
    char* r = base + off;
    off += (bytes + 255) & ~(size_t)255;
    return r;
  };
  unsigned short* WT  = (unsigned short*)carve((size_t)27 * 262144 * 2);
  unsigned short* XB  = (unsigned short*)carve((size_t)NMAX * 512 * 2);
  unsigned short* QKV = (unsigned short*)carve((size_t)NMAX * 1536 * 2);
  float*          SC  = (float*)carve((size_t)EMAX * 8 * 4);
  unsigned short* AGG = (unsigned short*)carve((size_t)NMAX * 512 * 2);
  int*   ROWPTR = (int*)carve((size_t)(NMAX + 1) * 4);
  int*   DEG    = (int*)carve((size_t)NMAX * 4);
  int*   SRCS   = (int*)carve((size_t)EMAX * 4);
  int*   BSUMS  = (int*)carve(64 * 4);
  float* PARTM  = (float*)carve((size_t)(NMAX + 8) * 8 * 4);  // per-wave maxes
  float* PARTS1 = (float*)carve((size_t)(NMAX + 8) * 8 * 4);  // per-wave sums
  float* PARTM2 = (float*)carve(256 * 8 * 4);
  float* PARTS2 = (float*)carve(256 * 8 * 4);
  float* GMAX   = (float*)carve(256);
  float* GINV   = (float*)carve(256);
  unsigned short* PROJ = QKV;    // alias: q/k/v slots dead once aggregate done
  if (off > ws_size) return;     // insufficient workspace: fail loudly

  // weights -> bf16 transposed + column-permuted ("WTs" layout for the GEMM)
  transpose_w_kernel<<<dim3(16,16,8), dim3(32,8), 0, stream>>>(W[0], WT);
  transpose_w_kernel<<<dim3(16,16,8), dim3(32,8), 0, stream>>>(W[1], WT + (size_t)8 * 262144);
  transpose_w_kernel<<<dim3(16,16,8), dim3(32,8), 0, stream>>>(W[2], WT + (size_t)16 * 262144);
  transpose_w_kernel<<<dim3(16,16,3), dim3(32,8), 0, stream>>>(headW, WT + (size_t)24 * 262144);

  size_t out_off = 0;
  for (int s = 0; s < 3; ++s) {
    const int N = Ns[s], E = Es[s];
    const int mt = (N + 255) >> 8;           // 256-row tiles (big GEMM)
    const int mts = (N + 127) >> 7;          // 128-row tiles (small GEMM)
    const int nb = (N + 1023) / 1024;
    const int nsb = (N + 3) / 4;             // score blocks (4 waves each)

    init_x_kernel<<<2048, 256, 0, stream>>>(
        (const float4*)feat[s], (const float4*)emb[s], (const float4*)pos[s],
        XB, (long long)N * 128);

    // CSR by dst (edge index is constant per stream; built once, used 2x)
    hipMemsetAsync(DEG, 0, (size_t)N * 4, stream);
    hist_kernel<<<(E + 255) / 256, 256, 0, stream>>>(ei[s], E, DEG);
    scan_part_kernel<<<nb, 1024, 0, stream>>>(DEG, N, ROWPTR, BSUMS);
    scan_bsums_kernel<<<1, 64, 0, stream>>>(BSUMS, nb);
    scan_add_kernel<<<nb, 1024, 0, stream>>>(ROWPTR, BSUMS, N);
    hipMemsetAsync(DEG, 0, (size_t)N * 4, stream);
    scatter_kernel<<<(E + 255) / 256, 256, 0, stream>>>(ei[s], E, ROWPTR, DEG, SRCS);

    for (int l = 0; l < 2; ++l) {
      const unsigned short* Wqkv = WT + (size_t)(s * 8 + l * 4) * 262144;
      const unsigned short* Wo   = WT + (size_t)(s * 8 + l * 4 + 3) * 262144;
      const float* bqkv = Bb[s] + (size_t)l * 4 * 512;       // q,k,v biases contiguous
      const float* bo   = Bb[s] + (size_t)(l * 4 + 3) * 512;

      gemm_bt_kernel<1><<<dim3(mt * 6), 512, 0, stream>>>(XB, Wqkv, bqkv, QKV, N, 1536);
      csr_scores_kernel<<<nsb, 256, 0, stream>>>(QKV, SRCS, ROWPTR, N, SC, PARTM, PARTS1);
      gms_part_kernel<<<256, 256, 0, stream>>>(PARTM, PARTS1, nsb * 4, PARTM2, PARTS2);
      gms_final_kernel<<<1, 256, 0, stream>>>(PARTM2, PARTS2, GMAX, GINV);
      aggregate_kernel<<<nsb, 256, 0, stream>>>(QKV, SC, GMAX, GINV, SRCS, ROWPTR, N, AGG);
      gemm_sm_kernel<1><<<dim3(mts * 4), 256, 0, stream>>>(AGG, Wo, bo, PROJ, N, 512);
      ln_kernel<<<nsb, 256, 0, stream>>>(PROJ, G[s] + (size_t)l * 512,
                                         Bt[s] + (size_t)l * 512, XB, N);
    }

    gemm_sm_kernel<0><<<dim3(mts * 4), 256, 0, stream>>>(
        XB, WT + (size_t)(24 + s) * 262144, headB + (size_t)s * 512,
        (float*)d_out + out_off, N, 512);
    out_off += (size_t)N * 512;
  }
}

// Round 13
// 1219.902 us; speedup vs baseline: 1.2656x; 1.0775x over previous
//
#include <hip/hip_runtime.h>

// ---------------------------------------------------------------------------
// SimplicialAttentionTransformer — LAYER-MAJOR, CROSS-STREAM-BATCHED.
// The 3 streams (v,e,t) are independent; every kernel is launched ONCE per
// stage covering all 3 via batch structs (per-stream pointers + cumulative
// block offsets). 73 launches -> 24 (saves ~2.5us dispatch+drain each).
// Kernel bodies identical to round-12 (same math -> same absmax).
// GEMMs: big 256x256/8-wave 4-phase dbuf (frozen); small 128x128/4-wave.
// Softmax: online (max,sumexp) partials fused into scores, 2-stage combine.
// ---------------------------------------------------------------------------

typedef __attribute__((ext_vector_type(8))) __bf16 bf16x8;
typedef __attribute__((ext_vector_type(4))) float f32x4;
typedef __attribute__((ext_vector_type(8))) unsigned short ushort8v;
typedef __attribute__((ext_vector_type(4))) unsigned short ushort4v;

__device__ __forceinline__ float b2f(unsigned short u) {
  union { unsigned u; float f; } x; x.u = (unsigned)u << 16; return x.f;
}
__device__ __forceinline__ unsigned short f2b(float f) {
  union { float f; unsigned u; } x; x.f = f;
  unsigned r = x.u + 0x7fffu + ((x.u >> 16) & 1u);   // RNE
  return (unsigned short)(r >> 16);
}
__device__ __forceinline__ int xcd_swizzle(int orig, int nwg) {
  const int xcd = orig & 7, lin = orig >> 3;
  const int q = nwg >> 3, r8 = nwg & 7;
  return (xcd < r8 ? xcd * (q + 1) : r8 * (q + 1) + (xcd - r8) * q) + lin;
}
__device__ __forceinline__ void stage16(const void* g, void* lds_uniform) {
  __builtin_amdgcn_global_load_lds(
      (const __attribute__((address_space(1))) void*)g,
      (__attribute__((address_space(3))) void*)lds_uniform, 16, 0, 0);
}

// ============================ batch structs ================================
struct IB {  // init
  const float4* a[3]; const float4* b[3]; const float4* c[3];
  unsigned short* xb[3];
  long long cum[4];          // cumulative float4 counts
};
struct HB {  // hist / scatter
  const int* ei[3]; int E[3]; int cum[4];   // cum of ceil(E/256) blocks
  int* deg[3]; const int* rowptr[3]; int* srcs[3];
};
struct PB {  // scan part / add
  const int* deg[3]; int* rowptr[3]; int N[3]; int nbcum[4];
};
struct GB {  // gemm batch (big or small)
  const unsigned short* A[3]; const unsigned short* BT[3];
  const float* bias[3]; void* C[3];
  int M[3]; int cum[4];      // cum of block counts
};
struct SB {  // scores
  const unsigned short* qkv[3]; const int* srcs[3]; const int* rowptr[3];
  float* sc[3]; float* pm[3]; float* ps[3];
  int N[3]; int cum[4];      // cum of nsb blocks
};
struct MB {  // gms stage-1
  const float* pm[3]; const float* ps[3]; int nslots[3];
};
struct AB {  // aggregate
  const unsigned short* qkv[3]; const float* sc[3]; const int* srcs[3];
  const int* rowptr[3]; unsigned short* agg[3];
  int N[3]; int cum[4];
};
struct LB {  // layernorm
  const unsigned short* proj[3]; const float* g[3]; const float* bt[3];
  unsigned short* xb[3]; int N[3]; int cum[4];
};
__device__ __forceinline__ int find3(int b, const int* cum) {
  return (b >= cum[1]) + (b >= cum[2]);
}

// ======================= xb = bf16(a + b + c), batched =====================
__global__ __launch_bounds__(256) void init_b_kernel(IB ib)
{
  long long total = ib.cum[3];
  long long stride = (long long)gridDim.x * 256;
  for (long long i = (long long)blockIdx.x * 256 + threadIdx.x; i < total; i += stride) {
    int s = (i >= ib.cum[1]) + (i >= ib.cum[2]);
    long long j = i - ib.cum[s];
    float4 av = ib.a[s][j], bv = ib.b[s][j], cv = ib.c[s][j];
    ushort4v o;
    o.x = f2b(av.x + bv.x + cv.x); o.y = f2b(av.y + bv.y + cv.y);
    o.z = f2b(av.z + bv.z + cv.z); o.w = f2b(av.w + bv.w + cv.w);
    *(ushort4v*)(ib.xb[s] + j * 4) = o;
  }
}

// ===== weight transpose fp32[512][512] -> bf16 WT[perm(c)][r], all 27 ======
// perm swaps bits [5:4] <-> [3:2] within each 64-col block (involution).
__global__ __launch_bounds__(256) void transpose_all_kernel(
    const float* W0, const float* W1, const float* W2, const float* Wh,
    unsigned short* WT)
{
  __shared__ float t[32][33];
  int z = blockIdx.z;
  const float* src = (z < 8)  ? W0 + (size_t)z * 262144
                   : (z < 16) ? W1 + (size_t)(z - 8) * 262144
                   : (z < 24) ? W2 + (size_t)(z - 16) * 262144
                              : Wh + (size_t)(z - 24) * 262144;
  unsigned short* dst = WT + (size_t)z * 262144;
  int bx = blockIdx.x * 32, by = blockIdx.y * 32;
  int tx = threadIdx.x, ty = threadIdx.y;   // block 32x8
  #pragma unroll
  for (int i = 0; i < 32; i += 8)
    t[ty + i][tx] = src[(size_t)(by + ty + i) * 512 + bx + tx];
  __syncthreads();
  #pragma unroll
  for (int i = 0; i < 32; i += 8) {
    int c = bx + ty + i;
    int p = (c & ~0x3C) | ((c & 0x30) >> 2) | ((c & 0x0C) << 2);
    dst[(size_t)p * 512 + by + tx] = f2b(t[tx][ty + i]);
  }
}

// =================== big bf16 GEMM (256x256, 8 waves), batched =============
template<int OUT_BF16>
__global__ __launch_bounds__(512, 2) void gemm_big_kernel(GB gb, int Ncols)
{
  constexpr int K = 512;
  __shared__ unsigned short smem[65536];

  const int b = blockIdx.x;
  const int s = find3(b, gb.cum);
  const int wgid = xcd_swizzle(b - gb.cum[s], gb.cum[s + 1] - gb.cum[s]);
  const unsigned short* A  = gb.A[s];
  const unsigned short* BT = gb.BT[s];
  const float* bias = gb.bias[s];
  const int M = gb.M[s];

  const int tiles_n = Ncols >> 8;
  const int tm = wgid / tiles_n;
  const int tn = wgid - tm * tiles_n;
  const int row0 = tm << 8, col0 = tn << 8;
  const int lane = threadIdx.x & 63, wid = threadIdx.x >> 6;
  const int wr = (wid >> 2) << 7;
  const int wc = (wid & 3) << 6;

  f32x4 acc[8][4];
  #pragma unroll
  for (int i = 0; i < 8; ++i)
    #pragma unroll
    for (int j = 0; j < 4; ++j) acc[i][j] = (f32x4)0.f;

  int srow[4], scsw[4], sseg[4];
  #pragma unroll
  for (int i = 0; i < 4; ++i) {
    int seg = (i << 3) | wid;
    int idx = (seg << 6) | lane;
    int row = idx >> 3, ch = idx & 7;
    sseg[i] = seg; srow[i] = row; scsw[i] = ch ^ (row & 7);
  }

  #define STG_PAIR(buf, kb_, i)                                               \
    { int ra = row0 + srow[i]; ra = (ra < M) ? ra : (M - 1);                  \
      stage16(A + (size_t)ra * K + (kb_) + (scsw[i] << 3),                    \
              smem + (buf) * 32768 + (sseg[i] << 9));                         \
      int rb = col0 + srow[i];                                                \
      stage16(BT + (size_t)rb * K + (kb_) + (scsw[i] << 3),                   \
              smem + (buf) * 32768 + 16384 + (sseg[i] << 9)); }

  STG_PAIR(0, 0, 0) STG_PAIR(0, 0, 1) STG_PAIR(0, 0, 2) STG_PAIR(0, 0, 3)
  __syncthreads();

  const int lm = lane & 15;
  const int kbl = (lane >> 4) << 4;

  #pragma unroll
  for (int kt = 0; kt < 8; ++kt) {
    const int cur = kt & 1, nxt = cur ^ 1, kb1 = (kt + 1) << 6;
    const char* Asb = (const char*)(smem + cur * 32768);
    const char* Bsb = Asb + 32768;

    auto rdA = [&](int mi, int kk) -> bf16x8 {
      int r = wr + (mi << 4) + lm;
      int kb = (kk << 6) + kbl;
      return *(const bf16x8*)(Asb + (r << 7) + (kb ^ ((r & 7) << 4)));
    };
    auto rdB = [&](int ni, int kk) -> bf16x8 {
      int r = wc + (ni << 4) + lm;
      int kb = (kk << 6) + kbl;
      return *(const bf16x8*)(Bsb + (r << 7) + (kb ^ ((r & 7) << 4)));
    };

    bf16x8 av[4], bv[4];

    #pragma unroll
    for (int i = 0; i < 4; ++i) { av[i] = rdA(i, 0); bv[i] = rdB(i, 0); }
    if (kt < 7) { STG_PAIR(nxt, kb1, 0) STG_PAIR(nxt, kb1, 1) }
    __builtin_amdgcn_s_barrier();
    __builtin_amdgcn_s_setprio(1);
    #pragma unroll
    for (int mi = 0; mi < 4; ++mi)
      #pragma unroll
      for (int ni = 0; ni < 4; ++ni)
        acc[mi][ni] = __builtin_amdgcn_mfma_f32_16x16x32_bf16(
            bv[ni], av[mi], acc[mi][ni], 0, 0, 0);
    __builtin_amdgcn_s_setprio(0);
    __builtin_amdgcn_s_barrier();

    #pragma unroll
    for (int i = 0; i < 4; ++i) av[i] = rdA(4 + i, 0);
    if (kt < 7) { STG_PAIR(nxt, kb1, 2) STG_PAIR(nxt, kb1, 3) }
    __builtin_amdgcn_s_barrier();
    __builtin_amdgcn_s_setprio(1);
    #pragma unroll
    for (int mi = 0; mi < 4; ++mi)
      #pragma unroll
      for (int ni = 0; ni < 4; ++ni)
        acc[4 + mi][ni] = __builtin_amdgcn_mfma_f32_16x16x32_bf16(
            bv[ni], av[mi], acc[4 + mi][ni], 0, 0, 0);
    __builtin_amdgcn_s_setprio(0);
    __builtin_amdgcn_s_barrier();

    #pragma unroll
    for (int i = 0; i < 4; ++i) { av[i] = rdA(i, 1); bv[i] = rdB(i, 1); }
    __builtin_amdgcn_s_barrier();
    __builtin_amdgcn_s_setprio(1);
    #pragma unroll
    for (int mi = 0; mi < 4; ++mi)
      #pragma unroll
      for (int ni = 0; ni < 4; ++ni)
        acc[mi][ni] = __builtin_amdgcn_mfma_f32_16x16x32_bf16(
            bv[ni], av[mi], acc[mi][ni], 0, 0, 0);
    __builtin_amdgcn_s_setprio(0);
    __builtin_amdgcn_s_barrier();

    #pragma unroll
    for (int i = 0; i < 4; ++i) av[i] = rdA(4 + i, 1);
    __builtin_amdgcn_s_barrier();
    __builtin_amdgcn_s_setprio(1);
    #pragma unroll
    for (int mi = 0; mi < 4; ++mi)
      #pragma unroll
      for (int ni = 0; ni < 4; ++ni)
        acc[4 + mi][ni] = __builtin_amdgcn_mfma_f32_16x16x32_bf16(
            bv[ni], av[mi], acc[4 + mi][ni], 0, 0, 0);
    __builtin_amdgcn_s_setprio(0);

    __syncthreads();
  }
  #undef STG_PAIR

  const int mrow = lane & 15;
  const int t4 = (lane >> 4) << 4;
  float bsv[16];
  #pragma unroll
  for (int ni = 0; ni < 4; ++ni) {
    float4 bvv = *(const float4*)(bias + col0 + wc + t4 + (ni << 2));
    bsv[4*ni+0] = bvv.x; bsv[4*ni+1] = bvv.y; bsv[4*ni+2] = bvv.z; bsv[4*ni+3] = bvv.w;
  }

  if (OUT_BF16) {
    unsigned short* C = (unsigned short*)gb.C[s];
    #pragma unroll
    for (int mi = 0; mi < 8; ++mi) {
      int rowg = row0 + wr + (mi << 4) + mrow;
      if (rowg < M) {
        ushort8v o0, o1;
        #pragma unroll
        for (int r = 0; r < 4; ++r) {
          o0[r]     = f2b(acc[mi][0][r] + bsv[r]);
          o0[4 + r] = f2b(acc[mi][1][r] + bsv[4 + r]);
          o1[r]     = f2b(acc[mi][2][r] + bsv[8 + r]);
          o1[4 + r] = f2b(acc[mi][3][r] + bsv[12 + r]);
        }
        unsigned short* cp = C + (size_t)rowg * Ncols + col0 + wc + t4;
        *(ushort8v*)cp = o0;
        *(ushort8v*)(cp + 8) = o1;
      }
    }
  } else {
    float* C = (float*)gb.C[s];
    #pragma unroll
    for (int mi = 0; mi < 8; ++mi) {
      int rowg = row0 + wr + (mi << 4) + mrow;
      if (rowg < M) {
        float* cp = C + (size_t)rowg * Ncols + col0 + wc + t4;
        #pragma unroll
        for (int ni = 0; ni < 4; ++ni) {
          float4 v;
          v.x = acc[mi][ni][0] + bsv[4*ni+0];
          v.y = acc[mi][ni][1] + bsv[4*ni+1];
          v.z = acc[mi][ni][2] + bsv[4*ni+2];
          v.w = acc[mi][ni][3] + bsv[4*ni+3];
          *(float4*)(cp + (ni << 2)) = v;
        }
      }
    }
  }
}

// ======= small bf16 GEMM (128x128, 4 waves, high occupancy), batched =======
template<int OUT_BF16>
__global__ __launch_bounds__(256) void gemm_sm_kernel(GB gb, int Ncols)
{
  constexpr int K = 512;
  __shared__ unsigned short As[8192];
  __shared__ unsigned short Bs[8192];

  const int b = blockIdx.x;
  const int s = find3(b, gb.cum);
  const int wgid = xcd_swizzle(b - gb.cum[s], gb.cum[s + 1] - gb.cum[s]);
  const unsigned short* A  = gb.A[s];
  const unsigned short* BT = gb.BT[s];
  const float* bias = gb.bias[s];
  const int M = gb.M[s];

  const int tiles_n = Ncols >> 7;
  const int tm = wgid / tiles_n;
  const int tn = wgid - tm * tiles_n;
  const int row0 = tm << 7, col0 = tn << 7;
  const int lane = threadIdx.x & 63, wid = threadIdx.x >> 6;
  const int wm = (wid >> 1) << 6, wn = (wid & 1) << 6;

  f32x4 acc[4][4];
  #pragma unroll
  for (int i = 0; i < 4; ++i)
    #pragma unroll
    for (int j = 0; j < 4; ++j) acc[i][j] = (f32x4)0.f;

  int srow[4], scsw[4], sseg[4];
  #pragma unroll
  for (int i = 0; i < 4; ++i) {
    int seg = (i << 2) | wid;
    int idx = (seg << 6) | lane;
    int row = idx >> 3, ch = idx & 7;
    sseg[i] = seg; srow[i] = row; scsw[i] = ch ^ (row & 7);
  }

  #pragma unroll
  for (int kt = 0; kt < 8; ++kt) {
    const int kbase = kt << 6;
    #pragma unroll
    for (int i = 0; i < 4; ++i) {
      int ra = row0 + srow[i]; ra = (ra < M) ? ra : (M - 1);
      stage16(A + (size_t)ra * K + kbase + (scsw[i] << 3), As + (sseg[i] << 9));
      int rb = col0 + srow[i];
      stage16(BT + (size_t)rb * K + kbase + (scsw[i] << 3), Bs + (sseg[i] << 9));
    }
    asm volatile("s_waitcnt vmcnt(0)" ::: "memory");
    __syncthreads();

    #pragma unroll
    for (int kk = 0; kk < 2; ++kk) {
      const int kb = (kk << 6) + ((lane >> 4) << 4);
      bf16x8 af[4], bfr[4];
      #pragma unroll
      for (int mi = 0; mi < 4; ++mi) {
        int r = wm + (mi << 4) + (lane & 15);
        af[mi] = *(const bf16x8*)((const char*)As + (r << 7) + (kb ^ ((r & 7) << 4)));
      }
      #pragma unroll
      for (int ni = 0; ni < 4; ++ni) {
        int r = wn + (ni << 4) + (lane & 15);
        bfr[ni] = *(const bf16x8*)((const char*)Bs + (r << 7) + (kb ^ ((r & 7) << 4)));
      }
      #pragma unroll
      for (int mi = 0; mi < 4; ++mi)
        #pragma unroll
        for (int ni = 0; ni < 4; ++ni)
          acc[mi][ni] = __builtin_amdgcn_mfma_f32_16x16x32_bf16(
              bfr[ni], af[mi], acc[mi][ni], 0, 0, 0);
    }
    __syncthreads();
  }

  const int mrow = lane & 15;
  const int t4 = (lane >> 4) << 4;
  float bsv[16];
  #pragma unroll
  for (int ni = 0; ni < 4; ++ni) {
    float4 bvv = *(const float4*)(bias + col0 + wn + t4 + (ni << 2));
    bsv[4*ni+0] = bvv.x; bsv[4*ni+1] = bvv.y; bsv[4*ni+2] = bvv.z; bsv[4*ni+3] = bvv.w;
  }

  if (OUT_BF16) {
    unsigned short* C = (unsigned short*)gb.C[s];
    #pragma unroll
    for (int mi = 0; mi < 4; ++mi) {
      int rowg = row0 + wm + (mi << 4) + mrow;
      if (rowg < M) {
        ushort8v o0, o1;
        #pragma unroll
        for (int r = 0; r < 4; ++r) {
          o0[r]     = f2b(acc[mi][0][r] + bsv[r]);
          o0[4 + r] = f2b(acc[mi][1][r] + bsv[4 + r]);
          o1[r]     = f2b(acc[mi][2][r] + bsv[8 + r]);
          o1[4 + r] = f2b(acc[mi][3][r] + bsv[12 + r]);
        }
        unsigned short* cp = C + (size_t)rowg * Ncols + col0 + wn + t4;
        *(ushort8v*)cp = o0;
        *(ushort8v*)(cp + 8) = o1;
      }
    }
  } else {
    float* C = (float*)gb.C[s];
    #pragma unroll
    for (int mi = 0; mi < 4; ++mi) {
      int rowg = row0 + wm + (mi << 4) + mrow;
      if (rowg < M) {
        float* cp = C + (size_t)rowg * Ncols + col0 + wn + t4;
        #pragma unroll
        for (int ni = 0; ni < 4; ++ni) {
          float4 v;
          v.x = acc[mi][ni][0] + bsv[4*ni+0];
          v.y = acc[mi][ni][1] + bsv[4*ni+1];
          v.z = acc[mi][ni][2] + bsv[4*ni+2];
          v.w = acc[mi][ni][3] + bsv[4*ni+3];
          *(float4*)(cp + (ni << 2)) = v;
        }
      }
    }
  }
}

// ====== CSR-ordered edge scores + fused ONLINE (max,sumexp), batched =======
__global__ __launch_bounds__(256) void scores_b_kernel(SB sb)
{
  int b = blockIdx.x;
  int s = find3(b, sb.cum);
  int lb = b - sb.cum[s];
  const unsigned short* qkv = sb.qkv[s];
  const int* srcs = sb.srcs[s];
  float* sc = sb.sc[s];
  int wid = threadIdx.x >> 6, lane = threadIdx.x & 63;
  int n = (lb << 2) | wid;
  float mx = -1e30f, sm = 0.f;
  if (n < sb.N[s]) {
    int beg = sb.rowptr[s][n], end = sb.rowptr[s][n + 1];
    if (beg < end) {
      ushort8v qv = *(const ushort8v*)(qkv + (size_t)n * 1536 + (lane << 3));
      float qf[8];
      #pragma unroll
      for (int j = 0; j < 8; ++j) qf[j] = b2f(qv[j]);
      int i = beg;
      for (; i + 2 <= end; i += 2) {       // 2-edge ILP
        int s0 = srcs[i], s1 = srcs[i + 1];
        ushort8v k0 = *(const ushort8v*)(qkv + (size_t)s0 * 1536 + 512 + (lane << 3));
        ushort8v k1 = *(const ushort8v*)(qkv + (size_t)s1 * 1536 + 512 + (lane << 3));
        float p0 = 0.f, p1 = 0.f;
        #pragma unroll
        for (int j = 0; j < 8; ++j) { p0 += qf[j] * b2f(k0[j]); p1 += qf[j] * b2f(k1[j]); }
        p0 += __shfl_xor(p0, 1); p1 += __shfl_xor(p1, 1);
        p0 += __shfl_xor(p0, 2); p1 += __shfl_xor(p1, 2);
        p0 += __shfl_xor(p0, 4); p1 += __shfl_xor(p1, 4);
        p0 *= 0.125f; p1 *= 0.125f;
        float nm = fmaxf(mx, fmaxf(p0, p1));
        sm = sm * __expf(mx - nm) + __expf(p0 - nm) + __expf(p1 - nm);
        mx = nm;
        if (!(lane & 7)) {
          sc[(size_t)i * 8 + (lane >> 3)] = p0;
          sc[(size_t)(i + 1) * 8 + (lane >> 3)] = p1;
        }
      }
      if (i < end) {
        int s0 = srcs[i];
        ushort8v k0 = *(const ushort8v*)(qkv + (size_t)s0 * 1536 + 512 + (lane << 3));
        float p0 = 0.f;
        #pragma unroll
        for (int j = 0; j < 8; ++j) p0 += qf[j] * b2f(k0[j]);
        p0 += __shfl_xor(p0, 1);
        p0 += __shfl_xor(p0, 2);
        p0 += __shfl_xor(p0, 4);
        p0 *= 0.125f;
        float nm = fmaxf(mx, p0);
        sm = sm * __expf(mx - nm) + __expf(p0 - nm);
        mx = nm;
        if (!(lane & 7)) sc[(size_t)i * 8 + (lane >> 3)] = p0;
      }
    }
  }
  if (!(lane & 7)) {
    size_t slot = ((size_t)lb << 2) | wid;
    sb.pm[s][slot * 8 + (lane >> 3)] = mx;
    sb.ps[s][slot * 8 + (lane >> 3)] = sm;
  }
}

// ============ (max,sum) pair block reduce ==================================
__device__ __forceinline__ void pair_reduce_block(
    float (&m)[8], float (&s)[8], float* redm, float* reds)
{
  int lane = threadIdx.x & 63, wid = threadIdx.x >> 6;
  #pragma unroll
  for (int h = 0; h < 8; ++h)
    #pragma unroll
    for (int off = 1; off < 64; off <<= 1) {
      float om = __shfl_xor(m[h], off);
      float os = __shfl_xor(s[h], off);
      float M = fmaxf(m[h], om);
      s[h] = s[h] * __expf(m[h] - M) + os * __expf(om - M);
      m[h] = M;
    }
  if (lane == 0) {
    #pragma unroll
    for (int h = 0; h < 8; ++h) { redm[h * 4 + wid] = m[h]; reds[h * 4 + wid] = s[h]; }
  }
  __syncthreads();
  if (threadIdx.x == 0) {
    #pragma unroll
    for (int h = 0; h < 8; ++h) {
      float M = redm[h * 4], S = reds[h * 4];
      #pragma unroll
      for (int w = 1; w < 4; ++w) {
        float om = redm[h * 4 + w], os = reds[h * 4 + w];
        float nM = fmaxf(M, om);
        S = S * __expf(M - nM) + os * __expf(om - nM);
        M = nM;
      }
      m[h] = M; s[h] = S;
    }
  }
}

// stage-1 parallel combine, batched: 256 blocks per stream (grid = 768)
__global__ __launch_bounds__(256) void gms_part_b_kernel(
    MB mb, float* pm2, float* ps2)
{
  __shared__ float redm[32], reds[32];
  int s = blockIdx.x >> 8, j = blockIdx.x & 255;
  const float* pm = mb.pm[s];
  const float* ps = mb.ps[s];
  float m[8], sv[8];
  #pragma unroll
  for (int h = 0; h < 8; ++h) { m[h] = -1e30f; sv[h] = 0.f; }
  for (int i = j * 256 + threadIdx.x; i < mb.nslots[s]; i += 65536) {
    #pragma unroll
    for (int h = 0; h < 8; ++h) {
      float mi = pm[(size_t)i * 8 + h], si = ps[(size_t)i * 8 + h];
      float M = fmaxf(m[h], mi);
      sv[h] = sv[h] * __expf(m[h] - M) + si * __expf(mi - M);
      m[h] = M;
    }
  }
  pair_reduce_block(m, sv, redm, reds);
  if (threadIdx.x == 0) {
    #pragma unroll
    for (int h = 0; h < 8; ++h) {
      pm2[(s * 256 + j) * 8 + h] = m[h];
      ps2[(s * 256 + j) * 8 + h] = sv[h];
    }
  }
}

// stage-2 final combine, batched: 3 blocks (one per stream)
__global__ __launch_bounds__(256) void gms_final_b_kernel(
    const float* pm2, const float* ps2, float* gmax, float* ginv)
{
  __shared__ float redm[32], reds[32];
  int s = blockIdx.x;
  float m[8], sv[8];
  #pragma unroll
  for (int h = 0; h < 8; ++h) {
    m[h]  = pm2[(s * 256 + threadIdx.x) * 8 + h];
    sv[h] = ps2[(s * 256 + threadIdx.x) * 8 + h];
  }
  pair_reduce_block(m, sv, redm, reds);
  if (threadIdx.x == 0) {
    #pragma unroll
    for (int h = 0; h < 8; ++h) { gmax[s * 8 + h] = m[h]; ginv[s * 8 + h] = 1.0f / sv[h]; }
  }
}

// =============================== CSR build, batched ========================
__global__ __launch_bounds__(256) void hist_b_kernel(HB hb)
{
  int b = blockIdx.x;
  int s = find3(b, hb.cum);
  int e = (b - hb.cum[s]) * 256 + threadIdx.x;
  if (e < hb.E[s]) atomicAdd(&hb.deg[s][hb.ei[s][hb.E[s] + e]], 1);
}

__global__ __launch_bounds__(1024) void scan_part_b_kernel(PB pb, int* bsums)
{
  __shared__ int wsum[16];
  int b = blockIdx.x;
  int s = (b >= pb.nbcum[1]) + (b >= pb.nbcum[2]);
  int lb = b - pb.nbcum[s];
  int i = lb * 1024 + threadIdx.x;
  int lane = threadIdx.x & 63, wid = threadIdx.x >> 6;
  int sv = (i < pb.N[s]) ? pb.deg[s][i] : 0;
  #pragma unroll
  for (int off = 1; off < 64; off <<= 1) {
    int t = __shfl_up(sv, off);
    if (lane >= off) sv += t;
  }
  if (lane == 63) wsum[wid] = sv;
  __syncthreads();
  if (threadIdx.x < 16) {
    int ws = wsum[threadIdx.x];
    #pragma unroll
    for (int off = 1; off < 16; off <<= 1) {
      int t = __shfl_up(ws, off);
      if (threadIdx.x >= off) ws += t;
    }
    wsum[threadIdx.x] = ws;
  }
  __syncthreads();
  if (wid > 0) sv += wsum[wid - 1];
  if (i < pb.N[s]) pb.rowptr[s][i + 1] = sv;
  if (threadIdx.x == 1023) bsums[s * 64 + lb] = sv;
}

__global__ __launch_bounds__(64) void scan_bsums_b_kernel(
    int* bsums, int nb0, int nb1, int nb2)
{
  int s = blockIdx.x;
  int nb = (s == 0) ? nb0 : (s == 1) ? nb1 : nb2;
  int* bs = bsums + s * 64;
  int lane = threadIdx.x;
  int v = (lane < nb) ? bs[lane] : 0;
  #pragma unroll
  for (int off = 1; off < 64; off <<= 1) {
    int t = __shfl_up(v, off);
    if (lane >= off) v += t;
  }
  int ex = __shfl_up(v, 1);
  if (lane == 0) ex = 0;
  if (lane < nb) bs[lane] = ex;     // exclusive offsets, in place
}

__global__ __launch_bounds__(1024) void scan_add_b_kernel(
    PB pb, const int* bsums)
{
  int b = blockIdx.x;
  int s = (b >= pb.nbcum[1]) + (b >= pb.nbcum[2]);
  int lb = b - pb.nbcum[s];
  int i = lb * 1024 + threadIdx.x;
  if (lb == 0 && threadIdx.x == 0) pb.rowptr[s][0] = 0;
  if (i < pb.N[s] && lb > 0) pb.rowptr[s][i + 1] += bsums[s * 64 + lb];
}

__global__ __launch_bounds__(256) void scatter_b_kernel(HB hb)
{
  int b = blockIdx.x;
  int s = find3(b, hb.cum);
  int e = (b - hb.cum[s]) * 256 + threadIdx.x;
  if (e < hb.E[s]) {
    const int* ei = hb.ei[s];
    int dst = ei[hb.E[s] + e];
    int pos = atomicAdd(&hb.deg[s][dst], 1);
    hb.srcs[s][hb.rowptr[s][dst] + pos] = ei[e];
  }
}

// == aggregate: agg[n] = sum_i exp(sc_i - gmax)*ginv * v[srcs[i]], batched ==
__global__ __launch_bounds__(256) void aggregate_b_kernel(
    AB ab, const float* gmaxg, const float* ginvg)
{
  int b = blockIdx.x;
  int s = find3(b, ab.cum);
  int lb = b - ab.cum[s];
  int wid = threadIdx.x >> 6, lane = threadIdx.x & 63;
  int n = (lb << 2) | wid;
  if (n >= ab.N[s]) return;
  const unsigned short* qkv = ab.qkv[s];
  const float* sc = ab.sc[s];
  const int* srcs = ab.srcs[s];
  int beg = ab.rowptr[s][n], end = ab.rowptr[s][n + 1];
  int h = lane >> 3;
  float gm  = gmaxg[s * 8 + h];
  float inv = ginvg[s * 8 + h];
  float acc[8] = {0.f,0.f,0.f,0.f,0.f,0.f,0.f,0.f};
  int i = beg;
  for (; i + 4 <= end; i += 4) {       // 4-edge ILP
    int s0 = srcs[i], s1 = srcs[i + 1], s2 = srcs[i + 2], s3 = srcs[i + 3];
    float w0 = __expf(sc[(size_t)i * 8 + h] - gm) * inv;
    float w1 = __expf(sc[(size_t)(i + 1) * 8 + h] - gm) * inv;
    float w2 = __expf(sc[(size_t)(i + 2) * 8 + h] - gm) * inv;
    float w3 = __expf(sc[(size_t)(i + 3) * 8 + h] - gm) * inv;
    ushort8v v0 = *(const ushort8v*)(qkv + (size_t)s0 * 1536 + 1024 + (lane << 3));
    ushort8v v1 = *(const ushort8v*)(qkv + (size_t)s1 * 1536 + 1024 + (lane << 3));
    ushort8v v2 = *(const ushort8v*)(qkv + (size_t)s2 * 1536 + 1024 + (lane << 3));
    ushort8v v3 = *(const ushort8v*)(qkv + (size_t)s3 * 1536 + 1024 + (lane << 3));
    #pragma unroll
    for (int j = 0; j < 8; ++j)
      acc[j] += (w0 * b2f(v0[j]) + w1 * b2f(v1[j]))
              + (w2 * b2f(v2[j]) + w3 * b2f(v3[j]));
  }
  for (; i < end; ++i) {
    int s0 = srcs[i];
    float w0 = __expf(sc[(size_t)i * 8 + h] - gm) * inv;
    ushort8v v0 = *(const ushort8v*)(qkv + (size_t)s0 * 1536 + 1024 + (lane << 3));
    #pragma unroll
    for (int j = 0; j < 8; ++j) acc[j] += w0 * b2f(v0[j]);
  }
  ushort8v o;
  #pragma unroll
  for (int j = 0; j < 8; ++j) o[j] = f2b(acc[j]);
  *(ushort8v*)(ab.agg[s] + (size_t)n * 512 + (lane << 3)) = o;
}

// ============== LN(proj + resid)*g + bt, bf16 residual, batched ============
__global__ __launch_bounds__(256) void ln_b_kernel(LB lb_)
{
  int b = blockIdx.x;
  int s = find3(b, lb_.cum);
  int lb = b - lb_.cum[s];
  int wid = threadIdx.x >> 6, lane = threadIdx.x & 63;
  int n = (lb << 2) | wid;
  if (n >= lb_.N[s]) return;
  size_t base = (size_t)n * 512 + (lane << 3);
  ushort8v pv = *(const ushort8v*)(lb_.proj[s] + base);
  ushort8v xv = *(const ushort8v*)(lb_.xb[s] + base);
  float y[8];
  #pragma unroll
  for (int j = 0; j < 8; ++j) y[j] = b2f(pv[j]) + b2f(xv[j]);
  float sum = 0.f;
  #pragma unroll
  for (int j = 0; j < 8; ++j) sum += y[j];
  #pragma unroll
  for (int off = 1; off < 64; off <<= 1) sum += __shfl_xor(sum, off);
  float mean = sum * (1.f / 512.f);
  float vs = 0.f;
  #pragma unroll
  for (int j = 0; j < 8; ++j) { float d = y[j] - mean; vs += d * d; }
  #pragma unroll
  for (int off = 1; off < 64; off <<= 1) vs += __shfl_xor(vs, off);
  float rstd = rsqrtf(vs * (1.f / 512.f) + 1e-5f);
  int gi = lane << 3;
  ushort8v ob;
  #pragma unroll
  for (int j = 0; j < 8; ++j)
    ob[j] = f2b((y[j] - mean) * rstd * lb_.g[s][gi + j] + lb_.bt[s][gi + j]);
  *(ushort8v*)(lb_.xb[s] + base) = ob;
}

// ================================ driver ====================================
extern "C" void kernel_launch(void* const* d_in, const int* in_sizes, int n_in,
                              void* d_out, int out_size, void* d_ws, size_t ws_size,
                              hipStream_t stream)
{
  (void)n_in; (void)out_size;
  const float* feat[3] = {(const float*)d_in[0], (const float*)d_in[1], (const float*)d_in[2]};
  const float* emb[3]  = {(const float*)d_in[3], (const float*)d_in[4], (const float*)d_in[5]};
  const float* pos[3]  = {(const float*)d_in[6], (const float*)d_in[7], (const float*)d_in[8]};
  const float* W[3]  = {(const float*)d_in[9],  (const float*)d_in[13], (const float*)d_in[17]};
  const float* Bb[3] = {(const float*)d_in[10], (const float*)d_in[14], (const float*)d_in[18]};
  const float* G[3]  = {(const float*)d_in[11], (const float*)d_in[15], (const float*)d_in[19]};
  const float* Bt[3] = {(const float*)d_in[12], (const float*)d_in[16], (const float*)d_in[20]};
  const float* headW = (const float*)d_in[21];
  const float* headB = (const float*)d_in[22];
  const int* ei[3] = {(const int*)d_in[23], (const int*)d_in[24], (const int*)d_in[25]};

  int Ns[3], Es[3];
  for (int s = 0; s < 3; ++s) { Ns[s] = in_sizes[s] / 512; Es[s] = in_sizes[23 + s] / 2; }

  // per-stream offsets
  long long Noff[4] = {0}, Eoff[4] = {0}, Roff[4] = {0}, Poff[4] = {0};
  for (int s = 0; s < 3; ++s) {
    Noff[s + 1] = Noff[s] + Ns[s];
    Eoff[s + 1] = Eoff[s] + Es[s];
    Roff[s + 1] = Roff[s] + Ns[s] + 1;
    Poff[s + 1] = Poff[s] + ((Ns[s] + 3) / 4) * 4;
  }

  char* base = (char*)d_ws;
  size_t off = 0;
  auto carve = [&](size_t bytes) -> char* {
    char* r = base + off;
    off += (bytes + 255) & ~(size_t)255;
    return r;
  };
  unsigned short* WT   = (unsigned short*)carve((size_t)27 * 262144 * 2);
  unsigned short* XB   = (unsigned short*)carve((size_t)Noff[3] * 512 * 2);
  unsigned short* QKV  = (unsigned short*)carve((size_t)Noff[3] * 1536 * 2);
  float*          SC   = (float*)carve((size_t)Eoff[3] * 8 * 4);
  unsigned short* AGG  = (unsigned short*)carve((size_t)Noff[3] * 512 * 2);
  int*   ROWPTR = (int*)carve((size_t)Roff[3] * 4);
  int*   DEG    = (int*)carve((size_t)Noff[3] * 4);
  int*   SRCS   = (int*)carve((size_t)Eoff[3] * 4);
  int*   BSUMS  = (int*)carve(3 * 64 * 4);
  float* PARTM  = (float*)carve((size_t)Poff[3] * 8 * 4);
  float* PARTS1 = (float*)carve((size_t)Poff[3] * 8 * 4);
  float* PARTM2 = (float*)carve(3 * 256 * 8 * 4);
  float* PARTS2 = (float*)carve(3 * 256 * 8 * 4);
  float* GMAX   = (float*)carve(256);
  float* GINV   = (float*)carve(256);
  if (off > ws_size) return;     // insufficient workspace: fail loudly

  unsigned short* XBs[3];  unsigned short* QKVs[3]; float* SCs[3];
  unsigned short* AGGs[3]; int* ROWPTRs[3]; int* DEGs[3]; int* SRCSs[3];
  float* PMs[3]; float* PSs[3];
  for (int s = 0; s < 3; ++s) {
    XBs[s]  = XB  + Noff[s] * 512;
    QKVs[s] = QKV + Noff[s] * 1536;
    SCs[s]  = SC  + Eoff[s] * 8;
    AGGs[s] = AGG + Noff[s] * 512;
    ROWPTRs[s] = ROWPTR + Roff[s];
    DEGs[s] = DEG + Noff[s];
    SRCSs[s] = SRCS + Eoff[s];
    PMs[s] = PARTM + Poff[s] * 8;
    PSs[s] = PARTS1 + Poff[s] * 8;
  }

  // 1) weights -> bf16 transposed + column-permuted (27 matrices, 1 launch)
  transpose_all_kernel<<<dim3(16, 16, 27), dim3(32, 8), 0, stream>>>(
      W[0], W[1], W[2], headW, WT);

  // 2) init (batched)
  IB ib;
  for (int s = 0; s < 3; ++s) {
    ib.a[s] = (const float4*)feat[s]; ib.b[s] = (const float4*)emb[s];
    ib.c[s] = (const float4*)pos[s];  ib.xb[s] = XBs[s];
  }
  ib.cum[0] = 0;
  for (int s = 0; s < 3; ++s) ib.cum[s + 1] = ib.cum[s] + (long long)Ns[s] * 128;
  init_b_kernel<<<2048, 256, 0, stream>>>(ib);

  // 3) CSR build (batched; one memset covers all streams)
  HB hb;
  hb.cum[0] = 0;
  for (int s = 0; s < 3; ++s) {
    hb.ei[s] = ei[s]; hb.E[s] = Es[s];
    hb.cum[s + 1] = hb.cum[s] + (Es[s] + 255) / 256;
    hb.deg[s] = DEGs[s]; hb.rowptr[s] = ROWPTRs[s]; hb.srcs[s] = SRCSs[s];
  }
  PB pb;
  pb.nbcum[0] = 0;
  for (int s = 0; s < 3; ++s) {
    pb.deg[s] = DEGs[s]; pb.rowptr[s] = ROWPTRs[s]; pb.N[s] = Ns[s];
    pb.nbcum[s + 1] = pb.nbcum[s] + (Ns[s] + 1023) / 1024;
  }
  hipMemsetAsync(DEG, 0, (size_t)Noff[3] * 4, stream);
  hist_b_kernel<<<hb.cum[3], 256, 0, stream>>>(hb);
  scan_part_b_kernel<<<pb.nbcum[3], 1024, 0, stream>>>(pb, BSUMS);
  scan_bsums_b_kernel<<<3, 64, 0, stream>>>(
      BSUMS, (Ns[0] + 1023) / 1024, (Ns[1] + 1023) / 1024, (Ns[2] + 1023) / 1024);
  scan_add_b_kernel<<<pb.nbcum[3], 1024, 0, stream>>>(pb, BSUMS);
  hipMemsetAsync(DEG, 0, (size_t)Noff[3] * 4, stream);
  scatter_b_kernel<<<hb.cum[3], 256, 0, stream>>>(hb);

  // shared batch geometry
  int nsbcum[4] = {0}, mtcum[4] = {0}, mtscum[4] = {0};
  for (int s = 0; s < 3; ++s) {
    nsbcum[s + 1] = nsbcum[s] + (Ns[s] + 3) / 4;
    mtcum[s + 1]  = mtcum[s]  + ((Ns[s] + 255) >> 8) * 6;    // big QKV (1536)
    mtscum[s + 1] = mtscum[s] + ((Ns[s] + 127) >> 7) * 4;    // small (512)
  }

  MB mb;
  for (int s = 0; s < 3; ++s) {
    mb.pm[s] = PMs[s]; mb.ps[s] = PSs[s];
    mb.nslots[s] = ((Ns[s] + 3) / 4) * 4;
  }

  // 4) layers (layer-major across streams)
  for (int l = 0; l < 2; ++l) {
    GB qg;
    for (int s = 0; s < 3; ++s) {
      qg.A[s] = XBs[s];
      qg.BT[s] = WT + (size_t)(s * 8 + l * 4) * 262144;
      qg.bias[s] = Bb[s] + (size_t)l * 2048;
      qg.C[s] = QKVs[s];
      qg.M[s] = Ns[s];
      qg.cum[s] = mtcum[s];
    }
    qg.cum[3] = mtcum[3];
    gemm_big_kernel<1><<<mtcum[3], 512, 0, stream>>>(qg, 1536);

    SB sb;
    for (int s = 0; s < 3; ++s) {
      sb.qkv[s] = QKVs[s]; sb.srcs[s] = SRCSs[s]; sb.rowptr[s] = ROWPTRs[s];
      sb.sc[s] = SCs[s]; sb.pm[s] = PMs[s]; sb.ps[s] = PSs[s];
      sb.N[s] = Ns[s]; sb.cum[s] = nsbcum[s];
    }
    sb.cum[3] = nsbcum[3];
    scores_b_kernel<<<nsbcum[3], 256, 0, stream>>>(sb);

    gms_part_b_kernel<<<768, 256, 0, stream>>>(mb, PARTM2, PARTS2);
    gms_final_b_kernel<<<3, 256, 0, stream>>>(PARTM2, PARTS2, GMAX, GINV);

    AB ab;
    for (int s = 0; s < 3; ++s) {
      ab.qkv[s] = QKVs[s]; ab.sc[s] = SCs[s]; ab.srcs[s] = SRCSs[s];
      ab.rowptr[s] = ROWPTRs[s]; ab.agg[s] = AGGs[s];
      ab.N[s] = Ns[s]; ab.cum[s] = nsbcum[s];
    }
    ab.cum[3] = nsbcum[3];
    aggregate_b_kernel<<<nsbcum[3], 256, 0, stream>>>(ab, GMAX, GINV);

    GB pg;
    for (int s = 0; s < 3; ++s) {
      pg.A[s] = AGGs[s];
      pg.BT[s] = WT + (size_t)(s * 8 + l * 4 + 3) * 262144;
      pg.bias[s] = Bb[s] + (size_t)(l * 2048 + 1536);
      pg.C[s] = QKVs[s];                      // PROJ aliases QKV (q/k/v dead)
      pg.M[s] = Ns[s];
      pg.cum[s] = mtscum[s];
    }
    pg.cum[3] = mtscum[3];
    gemm_sm_kernel<1><<<mtscum[3], 256, 0, stream>>>(pg, 512);

    LB lb;
    for (int s = 0; s < 3; ++s) {
      lb.proj[s] = QKVs[s]; lb.g[s] = G[s] + (size_t)l * 512;
      lb.bt[s] = Bt[s] + (size_t)l * 512; lb.xb[s] = XBs[s];
      lb.N[s] = Ns[s]; lb.cum[s] = nsbcum[s];
    }
    lb.cum[3] = nsbcum[3];
    ln_b_kernel<<<nsbcum[3], 256, 0, stream>>>(lb);
  }

  // 5) head (batched small GEMM, f32 out)
  GB hg;
  size_t out_off = 0;
  for (int s = 0; s < 3; ++s) {
    hg.A[s] = XBs[s];
    hg.BT[s] = WT + (size_t)(24 + s) * 262144;
    hg.bias[s] = headB + (size_t)s * 512;
    hg.C[s] = (float*)d_out + out_off;
    hg.M[s] = Ns[s];
    hg.cum[s] = mtscum[s];
    out_off += (size_t)Ns[s] * 512;
  }
  hg.cum[3] = mtscum[3];
  gemm_sm_kernel<0><<<mtscum[3], 256, 0, stream>>>(hg, 512);
}

// Round 14
// 1206.100 us; speedup vs baseline: 1.2801x; 1.0114x over previous
//
#include <hip/hip_runtime.h>

// ---------------------------------------------------------------------------
// SimplicialAttentionTransformer — LAYER-MAJOR, CROSS-STREAM-BATCHED.
// Big GEMM (256x256, 8 waves): T4 counted-vmcnt pipeline — A triple-buffered,
// B double-buffered (160KB LDS), boundary waits s_waitcnt vmcnt(4) (never 0
// in steady state) + raw s_barrier, so the newest A-stage stays in flight
// across the barrier. Small GEMM 128x128/4-wave (occupancy-overlapped).
// Softmax: online (max,sumexp) fused into scores, 2-stage combine.
// bf16 residual stream; swapped-operand MFMA + permuted weights -> 16
// consecutive cols/lane, coalesced stores; XOR-swizzled LDS staging.
// ---------------------------------------------------------------------------

typedef __attribute__((ext_vector_type(8))) __bf16 bf16x8;
typedef __attribute__((ext_vector_type(4))) float f32x4;
typedef __attribute__((ext_vector_type(8))) unsigned short ushort8v;
typedef __attribute__((ext_vector_type(4))) unsigned short ushort4v;

__device__ __forceinline__ float b2f(unsigned short u) {
  union { unsigned u; float f; } x; x.u = (unsigned)u << 16; return x.f;
}
__device__ __forceinline__ unsigned short f2b(float f) {
  union { float f; unsigned u; } x; x.f = f;
  unsigned r = x.u + 0x7fffu + ((x.u >> 16) & 1u);   // RNE
  return (unsigned short)(r >> 16);
}
__device__ __forceinline__ int xcd_swizzle(int orig, int nwg) {
  const int xcd = orig & 7, lin = orig >> 3;
  const int q = nwg >> 3, r8 = nwg & 7;
  return (xcd < r8 ? xcd * (q + 1) : r8 * (q + 1) + (xcd - r8) * q) + lin;
}
__device__ __forceinline__ void stage16(const void* g, void* lds_uniform) {
  __builtin_amdgcn_global_load_lds(
      (const __attribute__((address_space(1))) void*)g,
      (__attribute__((address_space(3))) void*)lds_uniform, 16, 0, 0);
}

// ============================ batch structs ================================
struct IB {
  const float4* a[3]; const float4* b[3]; const float4* c[3];
  unsigned short* xb[3];
  long long cum[4];
};
struct HB {
  const int* ei[3]; int E[3]; int cum[4];
  int* deg[3]; const int* rowptr[3]; int* srcs[3];
};
struct PB {
  const int* deg[3]; int* rowptr[3]; int N[3]; int nbcum[4];
};
struct GB {
  const unsigned short* A[3]; const unsigned short* BT[3];
  const float* bias[3]; void* C[3];
  int M[3]; int cum[4];
};
struct SB {
  const unsigned short* qkv[3]; const int* srcs[3]; const int* rowptr[3];
  float* sc[3]; float* pm[3]; float* ps[3];
  int N[3]; int cum[4];
};
struct MB {
  const float* pm[3]; const float* ps[3]; int nslots[3];
};
struct AB {
  const unsigned short* qkv[3]; const float* sc[3]; const int* srcs[3];
  const int* rowptr[3]; unsigned short* agg[3];
  int N[3]; int cum[4];
};
struct LB {
  const unsigned short* proj[3]; const float* g[3]; const float* bt[3];
  unsigned short* xb[3]; int N[3]; int cum[4];
};
__device__ __forceinline__ int find3(int b, const int* cum) {
  return (b >= cum[1]) + (b >= cum[2]);
}

// ======================= xb = bf16(a + b + c), batched =====================
__global__ __launch_bounds__(256) void init_b_kernel(IB ib)
{
  long long total = ib.cum[3];
  long long stride = (long long)gridDim.x * 256;
  for (long long i = (long long)blockIdx.x * 256 + threadIdx.x; i < total; i += stride) {
    int s = (i >= ib.cum[1]) + (i >= ib.cum[2]);
    long long j = i - ib.cum[s];
    float4 av = ib.a[s][j], bv = ib.b[s][j], cv = ib.c[s][j];
    ushort4v o;
    o.x = f2b(av.x + bv.x + cv.x); o.y = f2b(av.y + bv.y + cv.y);
    o.z = f2b(av.z + bv.z + cv.z); o.w = f2b(av.w + bv.w + cv.w);
    *(ushort4v*)(ib.xb[s] + j * 4) = o;
  }
}

// ===== weight transpose fp32[512][512] -> bf16 WT[perm(c)][r], all 27 ======
__global__ __launch_bounds__(256) void transpose_all_kernel(
    const float* W0, const float* W1, const float* W2, const float* Wh,
    unsigned short* WT)
{
  __shared__ float t[32][33];
  int z = blockIdx.z;
  const float* src = (z < 8)  ? W0 + (size_t)z * 262144
                   : (z < 16) ? W1 + (size_t)(z - 8) * 262144
                   : (z < 24) ? W2 + (size_t)(z - 16) * 262144
                              : Wh + (size_t)(z - 24) * 262144;
  unsigned short* dst = WT + (size_t)z * 262144;
  int bx = blockIdx.x * 32, by = blockIdx.y * 32;
  int tx = threadIdx.x, ty = threadIdx.y;   // block 32x8
  #pragma unroll
  for (int i = 0; i < 32; i += 8)
    t[ty + i][tx] = src[(size_t)(by + ty + i) * 512 + bx + tx];
  __syncthreads();
  #pragma unroll
  for (int i = 0; i < 32; i += 8) {
    int c = bx + ty + i;
    int p = (c & ~0x3C) | ((c & 0x30) >> 2) | ((c & 0x0C) << 2);
    dst[(size_t)p * 512 + by + tx] = f2b(t[tx][ty + i]);
  }
}

// ====== big bf16 GEMM (256x256, 8 waves, counted-vmcnt pipeline) ===========
// LDS 160KB: Abuf[3] @ {0,32,64}KB (A 256x64), Bbuf[2] @ {96,128}KB.
// Tile t: phase0 issues B(t+1)->Bbuf[(t+1)&1]; phase1 issues A(t+2)->
// Abuf[(t+2)%3]. Boundary: s_waitcnt vmcnt(4) lgkmcnt(0) + s_barrier — the
// newest 4 loads (A(t+2)) stay in flight ACROSS the barrier (T4).
template<int OUT_BF16>
__global__ __launch_bounds__(512, 2) void gemm_big_kernel(GB gb, int Ncols)
{
  constexpr int K = 512;
  __shared__ unsigned short smem[81920];   // 160 KB

  const int b = blockIdx.x;
  const int s = find3(b, gb.cum);
  const int wgid = xcd_swizzle(b - gb.cum[s], gb.cum[s + 1] - gb.cum[s]);
  const unsigned short* A  = gb.A[s];
  const unsigned short* BT = gb.BT[s];
  const float* bias = gb.bias[s];
  const int M = gb.M[s];

  const int tiles_n = Ncols >> 8;
  const int tm = wgid / tiles_n;
  const int tn = wgid - tm * tiles_n;
  const int row0 = tm << 8, col0 = tn << 8;
  const int lane = threadIdx.x & 63, wid = threadIdx.x >> 6;
  const int wr = (wid >> 2) << 7;
  const int wc = (wid & 3) << 6;

  f32x4 acc[8][4];
  #pragma unroll
  for (int i = 0; i < 8; ++i)
    #pragma unroll
    for (int j = 0; j < 4; ++j) acc[i][j] = (f32x4)0.f;

  // staging plan: 32 segs of 1KB per operand; wave owns segs (i<<3)|wid.
  int srow[4], scsw[4], sseg[4];
  #pragma unroll
  for (int i = 0; i < 4; ++i) {
    int seg = (i << 3) | wid;
    int idx = (seg << 6) | lane;
    int row = idx >> 3, ch = idx & 7;
    sseg[i] = seg; srow[i] = row; scsw[i] = ch ^ (row & 7);
  }

  #define STG_A(buf3, kb_, i)                                                 \
    { int ra = row0 + srow[i]; ra = (ra < M) ? ra : (M - 1);                  \
      stage16(A + (size_t)ra * K + (kb_) + (scsw[i] << 3),                    \
              smem + (buf3) * 16384 + (sseg[i] << 9)); }
  #define STG_B(buf2, kb_, i)                                                 \
    { int rb = col0 + srow[i];                                                \
      stage16(BT + (size_t)rb * K + (kb_) + (scsw[i] << 3),                   \
              smem + 49152 + (buf2) * 16384 + (sseg[i] << 9)); }

  // prologue: B(0), A(0), A(1) in flight; wait for B(0)+A(0) (oldest 8)
  STG_B(0, 0, 0) STG_B(0, 0, 1) STG_B(0, 0, 2) STG_B(0, 0, 3)
  STG_A(0, 0, 0) STG_A(0, 0, 1) STG_A(0, 0, 2) STG_A(0, 0, 3)
  STG_A(1, 64, 0) STG_A(1, 64, 1) STG_A(1, 64, 2) STG_A(1, 64, 3)
  asm volatile("s_waitcnt vmcnt(4)" ::: "memory");
  __builtin_amdgcn_s_barrier();

  const int lm = lane & 15;
  const int kbl = (lane >> 4) << 4;

  #pragma unroll
  for (int kt = 0; kt < 8; ++kt) {
    const char* Asb = (const char*)(smem + (kt % 3) * 16384);
    const char* Bsb = (const char*)(smem + 49152 + (kt & 1) * 16384);
    const int kb1 = (kt + 1) << 6, kb2 = (kt + 2) << 6;

    auto rdA = [&](int mi, int kk) -> bf16x8 {
      int r = wr + (mi << 4) + lm;
      int kb = (kk << 6) + kbl;
      return *(const bf16x8*)(Asb + (r << 7) + (kb ^ ((r & 7) << 4)));
    };
    auto rdB = [&](int ni, int kk) -> bf16x8 {
      int r = wc + (ni << 4) + lm;
      int kb = (kk << 6) + kbl;
      return *(const bf16x8*)(Bsb + (r << 7) + (kb ^ ((r & 7) << 4)));
    };

    bf16x8 av[4], bv[4];

    // ---- phase 0: frags (mi 0-3, kk0) + B(kk0); issue B(t+1) stage
    #pragma unroll
    for (int i = 0; i < 4; ++i) { av[i] = rdA(i, 0); bv[i] = rdB(i, 0); }
    if (kt < 7) {
      STG_B((kt + 1) & 1, kb1, 0) STG_B((kt + 1) & 1, kb1, 1)
      STG_B((kt + 1) & 1, kb1, 2) STG_B((kt + 1) & 1, kb1, 3)
    }
    __builtin_amdgcn_s_barrier();
    __builtin_amdgcn_s_setprio(1);
    #pragma unroll
    for (int mi = 0; mi < 4; ++mi)
      #pragma unroll
      for (int ni = 0; ni < 4; ++ni)
        acc[mi][ni] = __builtin_amdgcn_mfma_f32_16x16x32_bf16(
            bv[ni], av[mi], acc[mi][ni], 0, 0, 0);
    __builtin_amdgcn_s_setprio(0);
    __builtin_amdgcn_s_barrier();

    // ---- phase 1: frags (mi 4-7, kk0); issue A(t+2) stage
    #pragma unroll
    for (int i = 0; i < 4; ++i) av[i] = rdA(4 + i, 0);
    if (kt < 6) {
      STG_A((kt + 2) % 3, kb2, 0) STG_A((kt + 2) % 3, kb2, 1)
      STG_A((kt + 2) % 3, kb2, 2) STG_A((kt + 2) % 3, kb2, 3)
    }
    __builtin_amdgcn_s_barrier();
    __builtin_amdgcn_s_setprio(1);
    #pragma unroll
    for (int mi = 0; mi < 4; ++mi)
      #pragma unroll
      for (int ni = 0; ni < 4; ++ni)
        acc[4 + mi][ni] = __builtin_amdgcn_mfma_f32_16x16x32_bf16(
            bv[ni], av[mi], acc[4 + mi][ni], 0, 0, 0);
    __builtin_amdgcn_s_setprio(0);
    __builtin_amdgcn_s_barrier();

    // ---- phase 2: frags (mi 0-3, kk1) + B(kk1)
    #pragma unroll
    for (int i = 0; i < 4; ++i) { av[i] = rdA(i, 1); bv[i] = rdB(i, 1); }
    __builtin_amdgcn_s_barrier();
    __builtin_amdgcn_s_setprio(1);
    #pragma unroll
    for (int mi = 0; mi < 4; ++mi)
      #pragma unroll
      for (int ni = 0; ni < 4; ++ni)
        acc[mi][ni] = __builtin_amdgcn_mfma_f32_16x16x32_bf16(
            bv[ni], av[mi], acc[mi][ni], 0, 0, 0);
    __builtin_amdgcn_s_setprio(0);
    __builtin_amdgcn_s_barrier();

    // ---- phase 3: frags (mi 4-7, kk1)
    #pragma unroll
    for (int i = 0; i < 4; ++i) av[i] = rdA(4 + i, 1);
    __builtin_amdgcn_s_barrier();
    __builtin_amdgcn_s_setprio(1);
    #pragma unroll
    for (int mi = 0; mi < 4; ++mi)
      #pragma unroll
      for (int ni = 0; ni < 4; ++ni)
        acc[4 + mi][ni] = __builtin_amdgcn_mfma_f32_16x16x32_bf16(
            bv[ni], av[mi], acc[4 + mi][ni], 0, 0, 0);
    __builtin_amdgcn_s_setprio(0);

    // ---- K-tile boundary: COUNTED wait — A(t+2)'s 4 loads stay in flight.
    if (kt < 6) {
      asm volatile("s_waitcnt vmcnt(4) lgkmcnt(0)" ::: "memory");
      __builtin_amdgcn_s_barrier();
    } else if (kt == 6) {
      asm volatile("s_waitcnt vmcnt(0) lgkmcnt(0)" ::: "memory");
      __builtin_amdgcn_s_barrier();
    }
    // kt == 7: epilogue follows; no LDS reuse, no wait needed.
  }
  #undef STG_A
  #undef STG_B

  const int mrow = lane & 15;
  const int t4 = (lane >> 4) << 4;
  float bsv[16];
  #pragma unroll
  for (int ni = 0; ni < 4; ++ni) {
    float4 bvv = *(const float4*)(bias + col0 + wc + t4 + (ni << 2));
    bsv[4*ni+0] = bvv.x; bsv[4*ni+1] = bvv.y; bsv[4*ni+2] = bvv.z; bsv[4*ni+3] = bvv.w;
  }

  if (OUT_BF16) {
    unsigned short* C = (unsigned short*)gb.C[s];
    #pragma unroll
    for (int mi = 0; mi < 8; ++mi) {
      int rowg = row0 + wr + (mi << 4) + mrow;
      if (rowg < M) {
        ushort8v o0, o1;
        #pragma unroll
        for (int r = 0; r < 4; ++r) {
          o0[r]     = f2b(acc[mi][0][r] + bsv[r]);
          o0[4 + r] = f2b(acc[mi][1][r] + bsv[4 + r]);
          o1[r]     = f2b(acc[mi][2][r] + bsv[8 + r]);
          o1[4 + r] = f2b(acc[mi][3][r] + bsv[12 + r]);
        }
        unsigned short* cp = C + (size_t)rowg * Ncols + col0 + wc + t4;
        *(ushort8v*)cp = o0;
        *(ushort8v*)(cp + 8) = o1;
      }
    }
  } else {
    float* C = (float*)gb.C[s];
    #pragma unroll
    for (int mi = 0; mi < 8; ++mi) {
      int rowg = row0 + wr + (mi << 4) + mrow;
      if (rowg < M) {
        float* cp = C + (size_t)rowg * Ncols + col0 + wc + t4;
        #pragma unroll
        for (int ni = 0; ni < 4; ++ni) {
          float4 v;
          v.x = acc[mi][ni][0] + bsv[4*ni+0];
          v.y = acc[mi][ni][1] + bsv[4*ni+1];
          v.z = acc[mi][ni][2] + bsv[4*ni+2];
          v.w = acc[mi][ni][3] + bsv[4*ni+3];
          *(float4*)(cp + (ni << 2)) = v;
        }
      }
    }
  }
}

// ======= small bf16 GEMM (128x128, 4 waves, high occupancy), batched =======
template<int OUT_BF16>
__global__ __launch_bounds__(256) void gemm_sm_kernel(GB gb, int Ncols)
{
  constexpr int K = 512;
  __shared__ unsigned short As[8192];
  __shared__ unsigned short Bs[8192];

  const int b = blockIdx.x;
  const int s = find3(b, gb.cum);
  const int wgid = xcd_swizzle(b - gb.cum[s], gb.cum[s + 1] - gb.cum[s]);
  const unsigned short* A  = gb.A[s];
  const unsigned short* BT = gb.BT[s];
  const float* bias = gb.bias[s];
  const int M = gb.M[s];

  const int tiles_n = Ncols >> 7;
  const int tm = wgid / tiles_n;
  const int tn = wgid - tm * tiles_n;
  const int row0 = tm << 7, col0 = tn << 7;
  const int lane = threadIdx.x & 63, wid = threadIdx.x >> 6;
  const int wm = (wid >> 1) << 6, wn = (wid & 1) << 6;

  f32x4 acc[4][4];
  #pragma unroll
  for (int i = 0; i < 4; ++i)
    #pragma unroll
    for (int j = 0; j < 4; ++j) acc[i][j] = (f32x4)0.f;

  int srow[4], scsw[4], sseg[4];
  #pragma unroll
  for (int i = 0; i < 4; ++i) {
    int seg = (i << 2) | wid;
    int idx = (seg << 6) | lane;
    int row = idx >> 3, ch = idx & 7;
    sseg[i] = seg; srow[i] = row; scsw[i] = ch ^ (row & 7);
  }

  #pragma unroll
  for (int kt = 0; kt < 8; ++kt) {
    const int kbase = kt << 6;
    #pragma unroll
    for (int i = 0; i < 4; ++i) {
      int ra = row0 + srow[i]; ra = (ra < M) ? ra : (M - 1);
      stage16(A + (size_t)ra * K + kbase + (scsw[i] << 3), As + (sseg[i] << 9));
      int rb = col0 + srow[i];
      stage16(BT + (size_t)rb * K + kbase + (scsw[i] << 3), Bs + (sseg[i] << 9));
    }
    asm volatile("s_waitcnt vmcnt(0)" ::: "memory");
    __syncthreads();

    #pragma unroll
    for (int kk = 0; kk < 2; ++kk) {
      const int kb = (kk << 6) + ((lane >> 4) << 4);
      bf16x8 af[4], bfr[4];
      #pragma unroll
      for (int mi = 0; mi < 4; ++mi) {
        int r = wm + (mi << 4) + (lane & 15);
        af[mi] = *(const bf16x8*)((const char*)As + (r << 7) + (kb ^ ((r & 7) << 4)));
      }
      #pragma unroll
      for (int ni = 0; ni < 4; ++ni) {
        int r = wn + (ni << 4) + (lane & 15);
        bfr[ni] = *(const bf16x8*)((const char*)Bs + (r << 7) + (kb ^ ((r & 7) << 4)));
      }
      #pragma unroll
      for (int mi = 0; mi < 4; ++mi)
        #pragma unroll
        for (int ni = 0; ni < 4; ++ni)
          acc[mi][ni] = __builtin_amdgcn_mfma_f32_16x16x32_bf16(
              bfr[ni], af[mi], acc[mi][ni], 0, 0, 0);
    }
    __syncthreads();
  }

  const int mrow = lane & 15;
  const int t4 = (lane >> 4) << 4;
  float bsv[16];
  #pragma unroll
  for (int ni = 0; ni < 4; ++ni) {
    float4 bvv = *(const float4*)(bias + col0 + wn + t4 + (ni << 2));
    bsv[4*ni+0] = bvv.x; bsv[4*ni+1] = bvv.y; bsv[4*ni+2] = bvv.z; bsv[4*ni+3] = bvv.w;
  }

  if (OUT_BF16) {
    unsigned short* C = (unsigned short*)gb.C[s];
    #pragma unroll
    for (int mi = 0; mi < 4; ++mi) {
      int rowg = row0 + wm + (mi << 4) + mrow;
      if (rowg < M) {
        ushort8v o0, o1;
        #pragma unroll
        for (int r = 0; r < 4; ++r) {
          o0[r]     = f2b(acc[mi][0][r] + bsv[r]);
          o0[4 + r] = f2b(acc[mi][1][r] + bsv[4 + r]);
          o1[r]     = f2b(acc[mi][2][r] + bsv[8 + r]);
          o1[4 + r] = f2b(acc[mi][3][r] + bsv[12 + r]);
        }
        unsigned short* cp = C + (size_t)rowg * Ncols + col0 + wn + t4;
        *(ushort8v*)cp = o0;
        *(ushort8v*)(cp + 8) = o1;
      }
    }
  } else {
    float* C = (float*)gb.C[s];
    #pragma unroll
    for (int mi = 0; mi < 4; ++mi) {
      int rowg = row0 + wm + (mi << 4) + mrow;
      if (rowg < M) {
        float* cp = C + (size_t)rowg * Ncols + col0 + wn + t4;
        #pragma unroll
        for (int ni = 0; ni < 4; ++ni) {
          float4 v;
          v.x = acc[mi][ni][0] + bsv[4*ni+0];
          v.y = acc[mi][ni][1] + bsv[4*ni+1];
          v.z = acc[mi][ni][2] + bsv[4*ni+2];
          v.w = acc[mi][ni][3] + bsv[4*ni+3];
          *(float4*)(cp + (ni << 2)) = v;
        }
      }
    }
  }
}

// ====== CSR-ordered edge scores + fused ONLINE (max,sumexp), batched =======
__global__ __launch_bounds__(256) void scores_b_kernel(SB sb)
{
  int b = blockIdx.x;
  int s = find3(b, sb.cum);
  int lb = b - sb.cum[s];
  const unsigned short* qkv = sb.qkv[s];
  const int* srcs = sb.srcs[s];
  float* sc = sb.sc[s];
  int wid = threadIdx.x >> 6, lane = threadIdx.x & 63;
  int n = (lb << 2) | wid;
  float mx = -1e30f, sm = 0.f;
  if (n < sb.N[s]) {
    int beg = sb.rowptr[s][n], end = sb.rowptr[s][n + 1];
    if (beg < end) {
      ushort8v qv = *(const ushort8v*)(qkv + (size_t)n * 1536 + (lane << 3));
      float qf[8];
      #pragma unroll
      for (int j = 0; j < 8; ++j) qf[j] = b2f(qv[j]);
      int i = beg;
      for (; i + 2 <= end; i += 2) {       // 2-edge ILP
        int s0 = srcs[i], s1 = srcs[i + 1];
        ushort8v k0 = *(const ushort8v*)(qkv + (size_t)s0 * 1536 + 512 + (lane << 3));
        ushort8v k1 = *(const ushort8v*)(qkv + (size_t)s1 * 1536 + 512 + (lane << 3));
        float p0 = 0.f, p1 = 0.f;
        #pragma unroll
        for (int j = 0; j < 8; ++j) { p0 += qf[j] * b2f(k0[j]); p1 += qf[j] * b2f(k1[j]); }
        p0 += __shfl_xor(p0, 1); p1 += __shfl_xor(p1, 1);
        p0 += __shfl_xor(p0, 2); p1 += __shfl_xor(p1, 2);
        p0 += __shfl_xor(p0, 4); p1 += __shfl_xor(p1, 4);
        p0 *= 0.125f; p1 *= 0.125f;
        float nm = fmaxf(mx, fmaxf(p0, p1));
        sm = sm * __expf(mx - nm) + __expf(p0 - nm) + __expf(p1 - nm);
        mx = nm;
        if (!(lane & 7)) {
          sc[(size_t)i * 8 + (lane >> 3)] = p0;
          sc[(size_t)(i + 1) * 8 + (lane >> 3)] = p1;
        }
      }
      if (i < end) {
        int s0 = srcs[i];
        ushort8v k0 = *(const ushort8v*)(qkv + (size_t)s0 * 1536 + 512 + (lane << 3));
        float p0 = 0.f;
        #pragma unroll
        for (int j = 0; j < 8; ++j) p0 += qf[j] * b2f(k0[j]);
        p0 += __shfl_xor(p0, 1);
        p0 += __shfl_xor(p0, 2);
        p0 += __shfl_xor(p0, 4);
        p0 *= 0.125f;
        float nm = fmaxf(mx, p0);
        sm = sm * __expf(mx - nm) + __expf(p0 - nm);
        mx = nm;
        if (!(lane & 7)) sc[(size_t)i * 8 + (lane >> 3)] = p0;
      }
    }
  }
  if (!(lane & 7)) {
    size_t slot = ((size_t)lb << 2) | wid;
    sb.pm[s][slot * 8 + (lane >> 3)] = mx;
    sb.ps[s][slot * 8 + (lane >> 3)] = sm;
  }
}

// ============ (max,sum) pair block reduce ==================================
__device__ __forceinline__ void pair_reduce_block(
    float (&m)[8], float (&s)[8], float* redm, float* reds)
{
  int lane = threadIdx.x & 63, wid = threadIdx.x >> 6;
  #pragma unroll
  for (int h = 0; h < 8; ++h)
    #pragma unroll
    for (int off = 1; off < 64; off <<= 1) {
      float om = __shfl_xor(m[h], off);
      float os = __shfl_xor(s[h], off);
      float M = fmaxf(m[h], om);
      s[h] = s[h] * __expf(m[h] - M) + os * __expf(om - M);
      m[h] = M;
    }
  if (lane == 0) {
    #pragma unroll
    for (int h = 0; h < 8; ++h) { redm[h * 4 + wid] = m[h]; reds[h * 4 + wid] = s[h]; }
  }
  __syncthreads();
  if (threadIdx.x == 0) {
    #pragma unroll
    for (int h = 0; h < 8; ++h) {
      float M = redm[h * 4], S = reds[h * 4];
      #pragma unroll
      for (int w = 1; w < 4; ++w) {
        float om = redm[h * 4 + w], os = reds[h * 4 + w];
        float nM = fmaxf(M, om);
        S = S * __expf(M - nM) + os * __expf(om - nM);
        M = nM;
      }
      m[h] = M; s[h] = S;
    }
  }
}

// stage-1 parallel combine, batched: 256 blocks per stream (grid = 768)
__global__ __launch_bounds__(256) void gms_part_b_kernel(
    MB mb, float* pm2, float* ps2)
{
  __shared__ float redm[32], reds[32];
  int s = blockIdx.x >> 8, j = blockIdx.x & 255;
  const float* pm = mb.pm[s];
  const float* ps = mb.ps[s];
  float m[8], sv[8];
  #pragma unroll
  for (int h = 0; h < 8; ++h) { m[h] = -1e30f; sv[h] = 0.f; }
  for (int i = j * 256 + threadIdx.x; i < mb.nslots[s]; i += 65536) {
    #pragma unroll
    for (int h = 0; h < 8; ++h) {
      float mi = pm[(size_t)i * 8 + h], si = ps[(size_t)i * 8 + h];
      float M = fmaxf(m[h], mi);
      sv[h] = sv[h] * __expf(m[h] - M) + si * __expf(mi - M);
      m[h] = M;
    }
  }
  pair_reduce_block(m, sv, redm, reds);
  if (threadIdx.x == 0) {
    #pragma unroll
    for (int h = 0; h < 8; ++h) {
      pm2[(s * 256 + j) * 8 + h] = m[h];
      ps2[(s * 256 + j) * 8 + h] = sv[h];
    }
  }
}

// stage-2 final combine, batched: 3 blocks (one per stream)
__global__ __launch_bounds__(256) void gms_final_b_kernel(
    const float* pm2, const float* ps2, float* gmax, float* ginv)
{
  __shared__ float redm[32], reds[32];
  int s = blockIdx.x;
  float m[8], sv[8];
  #pragma unroll
  for (int h = 0; h < 8; ++h) {
    m[h]  = pm2[(s * 256 + threadIdx.x) * 8 + h];
    sv[h] = ps2[(s * 256 + threadIdx.x) * 8 + h];
  }
  pair_reduce_block(m, sv, redm, reds);
  if (threadIdx.x == 0) {
    #pragma unroll
    for (int h = 0; h < 8; ++h) { gmax[s * 8 + h] = m[h]; ginv[s * 8 + h] = 1.0f / sv[h]; }
  }
}

// =============================== CSR build, batched ========================
__global__ __launch_bounds__(256) void hist_b_kernel(HB hb)
{
  int b = blockIdx.x;
  int s = find3(b, hb.cum);
  int e = (b - hb.cum[s]) * 256 + threadIdx.x;
  if (e < hb.E[s]) atomicAdd(&hb.deg[s][hb.ei[s][hb.E[s] + e]], 1);
}

__global__ __launch_bounds__(1024) void scan_part_b_kernel(PB pb, int* bsums)
{
  __shared__ int wsum[16];
  int b = blockIdx.x;
  int s = (b >= pb.nbcum[1]) + (b >= pb.nbcum[2]);
  int lb = b - pb.nbcum[s];
  int i = lb * 1024 + threadIdx.x;
  int lane = threadIdx.x & 63, wid = threadIdx.x >> 6;
  int sv = (i < pb.N[s]) ? pb.deg[s][i] : 0;
  #pragma unroll
  for (int off = 1; off < 64; off <<= 1) {
    int t = __shfl_up(sv, off);
    if (lane >= off) sv += t;
  }
  if (lane == 63) wsum[wid] = sv;
  __syncthreads();
  if (threadIdx.x < 16) {
    int ws = wsum[threadIdx.x];
    #pragma unroll
    for (int off = 1; off < 16; off <<= 1) {
      int t = __shfl_up(ws, off);
      if (threadIdx.x >= off) ws += t;
    }
    wsum[threadIdx.x] = ws;
  }
  __syncthreads();
  if (wid > 0) sv += wsum[wid - 1];
  if (i < pb.N[s]) pb.rowptr[s][i + 1] = sv;
  if (threadIdx.x == 1023) bsums[s * 64 + lb] = sv;
}

__global__ __launch_bounds__(64) void scan_bsums_b_kernel(
    int* bsums, int nb0, int nb1, int nb2)
{
  int s = blockIdx.x;
  int nb = (s == 0) ? nb0 : (s == 1) ? nb1 : nb2;
  int* bs = bsums + s * 64;
  int lane = threadIdx.x;
  int v = (lane < nb) ? bs[lane] : 0;
  #pragma unroll
  for (int off = 1; off < 64; off <<= 1) {
    int t = __shfl_up(v, off);
    if (lane >= off) v += t;
  }
  int ex = __shfl_up(v, 1);
  if (lane == 0) ex = 0;
  if (lane < nb) bs[lane] = ex;     // exclusive offsets, in place
}

__global__ __launch_bounds__(1024) void scan_add_b_kernel(
    PB pb, const int* bsums)
{
  int b = blockIdx.x;
  int s = (b >= pb.nbcum[1]) + (b >= pb.nbcum[2]);
  int lb = b - pb.nbcum[s];
  int i = lb * 1024 + threadIdx.x;
  if (lb == 0 && threadIdx.x == 0) pb.rowptr[s][0] = 0;
  if (i < pb.N[s] && lb > 0) pb.rowptr[s][i + 1] += bsums[s * 64 + lb];
}

__global__ __launch_bounds__(256) void scatter_b_kernel(HB hb)
{
  int b = blockIdx.x;
  int s = find3(b, hb.cum);
  int e = (b - hb.cum[s]) * 256 + threadIdx.x;
  if (e < hb.E[s]) {
    const int* ei = hb.ei[s];
    int dst = ei[hb.E[s] + e];
    int pos = atomicAdd(&hb.deg[s][dst], 1);
    hb.srcs[s][hb.rowptr[s][dst] + pos] = ei[e];
  }
}

// == aggregate: agg[n] = sum_i exp(sc_i - gmax)*ginv * v[srcs[i]], batched ==
__global__ __launch_bounds__(256) void aggregate_b_kernel(
    AB ab, const float* gmaxg, const float* ginvg)
{
  int b = blockIdx.x;
  int s = find3(b, ab.cum);
  int lb = b - ab.cum[s];
  int wid = threadIdx.x >> 6, lane = threadIdx.x & 63;
  int n = (lb << 2) | wid;
  if (n >= ab.N[s]) return;
  const unsigned short* qkv = ab.qkv[s];
  const float* sc = ab.sc[s];
  const int* srcs = ab.srcs[s];
  int beg = ab.rowptr[s][n], end = ab.rowptr[s][n + 1];
  int h = lane >> 3;
  float gm  = gmaxg[s * 8 + h];
  float inv = ginvg[s * 8 + h];
  float acc[8] = {0.f,0.f,0.f,0.f,0.f,0.f,0.f,0.f};
  int i = beg;
  for (; i + 4 <= end; i += 4) {       // 4-edge ILP
    int s0 = srcs[i], s1 = srcs[i + 1], s2 = srcs[i + 2], s3 = srcs[i + 3];
    float w0 = __expf(sc[(size_t)i * 8 + h] - gm) * inv;
    float w1 = __expf(sc[(size_t)(i + 1) * 8 + h] - gm) * inv;
    float w2 = __expf(sc[(size_t)(i + 2) * 8 + h] - gm) * inv;
    float w3 = __expf(sc[(size_t)(i + 3) * 8 + h] - gm) * inv;
    ushort8v v0 = *(const ushort8v*)(qkv + (size_t)s0 * 1536 + 1024 + (lane << 3));
    ushort8v v1 = *(const ushort8v*)(qkv + (size_t)s1 * 1536 + 1024 + (lane << 3));
    ushort8v v2 = *(const ushort8v*)(qkv + (size_t)s2 * 1536 + 1024 + (lane << 3));
    ushort8v v3 = *(const ushort8v*)(qkv + (size_t)s3 * 1536 + 1024 + (lane << 3));
    #pragma unroll
    for (int j = 0; j < 8; ++j)
      acc[j] += (w0 * b2f(v0[j]) + w1 * b2f(v1[j]))
              + (w2 * b2f(v2[j]) + w3 * b2f(v3[j]));
  }
  for (; i < end; ++i) {
    int s0 = srcs[i];
    float w0 = __expf(sc[(size_t)i * 8 + h] - gm) * inv;
    ushort8v v0 = *(const ushort8v*)(qkv + (size_t)s0 * 1536 + 1024 + (lane << 3));
    #pragma unroll
    for (int j = 0; j < 8; ++j) acc[j] += w0 * b2f(v0[j]);
  }
  ushort8v o;
  #pragma unroll
  for (int j = 0; j < 8; ++j) o[j] = f2b(acc[j]);
  *(ushort8v*)(ab.agg[s] + (size_t)n * 512 + (lane << 3)) = o;
}

// ============== LN(proj + resid)*g + bt, bf16 residual, batched ============
__global__ __launch_bounds__(256) void ln_b_kernel(LB lb_)
{
  int b = blockIdx.x;
  int s = find3(b, lb_.cum);
  int lb = b - lb_.cum[s];
  int wid = threadIdx.x >> 6, lane = threadIdx.x & 63;
  int n = (lb << 2) | wid;
  if (n >= lb_.N[s]) return;
  size_t base = (size_t)n * 512 + (lane << 3);
  ushort8v pv = *(const ushort8v*)(lb_.proj[s] + base);
  ushort8v xv = *(const ushort8v*)(lb_.xb[s] + base);
  float y[8];
  #pragma unroll
  for (int j = 0; j < 8; ++j) y[j] = b2f(pv[j]) + b2f(xv[j]);
  float sum = 0.f;
  #pragma unroll
  for (int j = 0; j < 8; ++j) sum += y[j];
  #pragma unroll
  for (int off = 1; off < 64; off <<= 1) sum += __shfl_xor(sum, off);
  float mean = sum * (1.f / 512.f);
  float vs = 0.f;
  #pragma unroll
  for (int j = 0; j < 8; ++j) { float d = y[j] - mean; vs += d * d; }
  #pragma unroll
  for (int off = 1; off < 64; off <<= 1) vs += __shfl_xor(vs, off);
  float rstd = rsqrtf(vs * (1.f / 512.f) + 1e-5f);
  int gi = lane << 3;
  ushort8v ob;
  #pragma unroll
  for (int j = 0; j < 8; ++j)
    ob[j] = f2b((y[j] - mean) * rstd * lb_.g[s][gi + j] + lb_.bt[s][gi + j]);
  *(ushort8v*)(lb_.xb[s] + base) = ob;
}

// ================================ driver ====================================
extern "C" void kernel_launch(void* const* d_in, const int* in_sizes, int n_in,
                              void* d_out, int out_size, void* d_ws, size_t ws_size,
                              hipStream_t stream)
{
  (void)n_in; (void)out_size;
  const float* feat[3] = {(const float*)d_in[0], (const float*)d_in[1], (const float*)d_in[2]};
  const float* emb[3]  = {(const float*)d_in[3], (const float*)d_in[4], (const float*)d_in[5]};
  const float* pos[3]  = {(const float*)d_in[6], (const float*)d_in[7], (const float*)d_in[8]};
  const float* W[3]  = {(const float*)d_in[9],  (const float*)d_in[13], (const float*)d_in[17]};
  const float* Bb[3] = {(const float*)d_in[10], (const float*)d_in[14], (const float*)d_in[18]};
  const float* G[3]  = {(const float*)d_in[11], (const float*)d_in[15], (const float*)d_in[19]};
  const float* Bt[3] = {(const float*)d_in[12], (const float*)d_in[16], (const float*)d_in[20]};
  const float* headW = (const float*)d_in[21];
  const float* headB = (const float*)d_in[22];
  const int* ei[3] = {(const int*)d_in[23], (const int*)d_in[24], (const int*)d_in[25]};

  int Ns[3], Es[3];
  for (int s = 0; s < 3; ++s) { Ns[s] = in_sizes[s] / 512; Es[s] = in_sizes[23 + s] / 2; }

  long long Noff[4] = {0}, Eoff[4] = {0}, Roff[4] = {0}, Poff[4] = {0};
  for (int s = 0; s < 3; ++s) {
    Noff[s + 1] = Noff[s] + Ns[s];
    Eoff[s + 1] = Eoff[s] + Es[s];
    Roff[s + 1] = Roff[s] + Ns[s] + 1;
    Poff[s + 1] = Poff[s] + ((Ns[s] + 3) / 4) * 4;
  }

  char* base = (char*)d_ws;
  size_t off = 0;
  auto carve = [&](size_t bytes) -> char* {
    char* r = base + off;
    off += (bytes + 255) & ~(size_t)255;
    return r;
  };
  unsigned short* WT   = (unsigned short*)carve((size_t)27 * 262144 * 2);
  unsigned short* XB   = (unsigned short*)carve((size_t)Noff[3] * 512 * 2);
  unsigned short* QKV  = (unsigned short*)carve((size_t)Noff[3] * 1536 * 2);
  float*          SC   = (float*)carve((size_t)Eoff[3] * 8 * 4);
  unsigned short* AGG  = (unsigned short*)carve((size_t)Noff[3] * 512 * 2);
  int*   ROWPTR = (int*)carve((size_t)Roff[3] * 4);
  int*   DEG    = (int*)carve((size_t)Noff[3] * 4);
  int*   SRCS   = (int*)carve((size_t)Eoff[3] * 4);
  int*   BSUMS  = (int*)carve(3 * 64 * 4);
  float* PARTM  = (float*)carve((size_t)Poff[3] * 8 * 4);
  float* PARTS1 = (float*)carve((size_t)Poff[3] * 8 * 4);
  float* PARTM2 = (float*)carve(3 * 256 * 8 * 4);
  float* PARTS2 = (float*)carve(3 * 256 * 8 * 4);
  float* GMAX   = (float*)carve(256);
  float* GINV   = (float*)carve(256);
  if (off > ws_size) return;     // insufficient workspace: fail loudly

  unsigned short* XBs[3];  unsigned short* QKVs[3]; float* SCs[3];
  unsigned short* AGGs[3]; int* ROWPTRs[3]; int* DEGs[3]; int* SRCSs[3];
  float* PMs[3]; float* PSs[3];
  for (int s = 0; s < 3; ++s) {
    XBs[s]  = XB  + Noff[s] * 512;
    QKVs[s] = QKV + Noff[s] * 1536;
    SCs[s]  = SC  + Eoff[s] * 8;
    AGGs[s] = AGG + Noff[s] * 512;
    ROWPTRs[s] = ROWPTR + Roff[s];
    DEGs[s] = DEG + Noff[s];
    SRCSs[s] = SRCS + Eoff[s];
    PMs[s] = PARTM + Poff[s] * 8;
    PSs[s] = PARTS1 + Poff[s] * 8;
  }

  // 1) weights -> bf16 transposed + column-permuted (27 matrices, 1 launch)
  transpose_all_kernel<<<dim3(16, 16, 27), dim3(32, 8), 0, stream>>>(
      W[0], W[1], W[2], headW, WT);

  // 2) init (batched)
  IB ib;
  for (int s = 0; s < 3; ++s) {
    ib.a[s] = (const float4*)feat[s]; ib.b[s] = (const float4*)emb[s];
    ib.c[s] = (const float4*)pos[s];  ib.xb[s] = XBs[s];
  }
  ib.cum[0] = 0;
  for (int s = 0; s < 3; ++s) ib.cum[s + 1] = ib.cum[s] + (long long)Ns[s] * 128;
  init_b_kernel<<<2048, 256, 0, stream>>>(ib);

  // 3) CSR build (batched; one memset covers all streams)
  HB hb;
  hb.cum[0] = 0;
  for (int s = 0; s < 3; ++s) {
    hb.ei[s] = ei[s]; hb.E[s] = Es[s];
    hb.cum[s + 1] = hb.cum[s] + (Es[s] + 255) / 256;
    hb.deg[s] = DEGs[s]; hb.rowptr[s] = ROWPTRs[s]; hb.srcs[s] = SRCSs[s];
  }
  PB pb;
  pb.nbcum[0] = 0;
  for (int s = 0; s < 3; ++s) {
    pb.deg[s] = DEGs[s]; pb.rowptr[s] = ROWPTRs[s]; pb.N[s] = Ns[s];
    pb.nbcum[s + 1] = pb.nbcum[s] + (Ns[s] + 1023) / 1024;
  }
  hipMemsetAsync(DEG, 0, (size_t)Noff[3] * 4, stream);
  hist_b_kernel<<<hb.cum[3], 256, 0, stream>>>(hb);
  scan_part_b_kernel<<<pb.nbcum[3], 1024, 0, stream>>>(pb, BSUMS);
  scan_bsums_b_kernel<<<3, 64, 0, stream>>>(
      BSUMS, (Ns[0] + 1023) / 1024, (Ns[1] + 1023) / 1024, (Ns[2] + 1023) / 1024);
  scan_add_b_kernel<<<pb.nbcum[3], 1024, 0, stream>>>(pb, BSUMS);
  hipMemsetAsync(DEG, 0, (size_t)Noff[3] * 4, stream);
  scatter_b_kernel<<<hb.cum[3], 256, 0, stream>>>(hb);

  // shared batch geometry
  int nsbcum[4] = {0}, mtcum[4] = {0}, mtscum[4] = {0};
  for (int s = 0; s < 3; ++s) {
    nsbcum[s + 1] = nsbcum[s] + (Ns[s] + 3) / 4;
    mtcum[s + 1]  = mtcum[s]  + ((Ns[s] + 255) >> 8) * 6;    // big QKV (1536)
    mtscum[s + 1] = mtscum[s] + ((Ns[s] + 127) >> 7) * 4;    // small (512)
  }

  MB mb;
  for (int s = 0; s < 3; ++s) {
    mb.pm[s] = PMs[s]; mb.ps[s] = PSs[s];
    mb.nslots[s] = ((Ns[s] + 3) / 4) * 4;
  }

  // 4) layers (layer-major across streams)
  for (int l = 0; l < 2; ++l) {
    GB qg;
    for (int s = 0; s < 3; ++s) {
      qg.A[s] = XBs[s];
      qg.BT[s] = WT + (size_t)(s * 8 + l * 4) * 262144;
      qg.bias[s] = Bb[s] + (size_t)l * 2048;
      qg.C[s] = QKVs[s];
      qg.M[s] = Ns[s];
      qg.cum[s] = mtcum[s];
    }
    qg.cum[3] = mtcum[3];
    gemm_big_kernel<1><<<mtcum[3], 512, 0, stream>>>(qg, 1536);

    SB sb;
    for (int s = 0; s < 3; ++s) {
      sb.qkv[s] = QKVs[s]; sb.srcs[s] = SRCSs[s]; sb.rowptr[s] = ROWPTRs[s];
      sb.sc[s] = SCs[s]; sb.pm[s] = PMs[s]; sb.ps[s] = PSs[s];
      sb.N[s] = Ns[s]; sb.cum[s] = nsbcum[s];
    }
    sb.cum[3] = nsbcum[3];
    scores_b_kernel<<<nsbcum[3], 256, 0, stream>>>(sb);

    gms_part_b_kernel<<<768, 256, 0, stream>>>(mb, PARTM2, PARTS2);
    gms_final_b_kernel<<<3, 256, 0, stream>>>(PARTM2, PARTS2, GMAX, GINV);

    AB ab;
    for (int s = 0; s < 3; ++s) {
      ab.qkv[s] = QKVs[s]; ab.sc[s] = SCs[s]; ab.srcs[s] = SRCSs[s];
      ab.rowptr[s] = ROWPTRs[s]; ab.agg[s] = AGGs[s];
      ab.N[s] = Ns[s]; ab.cum[s] = nsbcum[s];
    }
    ab.cum[3] = nsbcum[3];
    aggregate_b_kernel<<<nsbcum[3], 256, 0, stream>>>(ab, GMAX, GINV);

    GB pg;
    for (int s = 0; s < 3; ++s) {
      pg.A[s] = AGGs[s];
      pg.BT[s] = WT + (size_t)(s * 8 + l * 4 + 3) * 262144;
      pg.bias[s] = Bb[s] + (size_t)(l * 2048 + 1536);
      pg.C[s] = QKVs[s];                      // PROJ aliases QKV (q/k/v dead)
      pg.M[s] = Ns[s];
      pg.cum[s] = mtscum[s];
    }
    pg.cum[3] = mtscum[3];
    gemm_sm_kernel<1><<<mtscum[3], 256, 0, stream>>>(pg, 512);

    LB lb;
    for (int s = 0; s < 3; ++s) {
      lb.proj[s] = QKVs[s]; lb.g[s] = G[s] + (size_t)l * 512;
      lb.bt[s] = Bt[s] + (size_t)l * 512; lb.xb[s] = XBs[s];
      lb.N[s] = Ns[s]; lb.cum[s] = nsbcum[s];
    }
    lb.cum[3] = nsbcum[3];
    ln_b_kernel<<<nsbcum[3], 256, 0, stream>>>(lb);
  }

  // 5) head (batched small GEMM, f32 out)
  GB hg;
  size_t out_off = 0;
  for (int s = 0; s < 3; ++s) {
    hg.A[s] = XBs[s];
    hg.BT[s] = WT + (size_t)(24 + s) * 262144;
    hg.bias[s] = headB + (size_t)s * 512;
    hg.C[s] = (float*)d_out + out_off;
    hg.M[s] = Ns[s];
    hg.cum[s] = mtscum[s];
    out_off += (size_t)Ns[s] * 512;
  }
  hg.cum[3] = mtscum[3];
  gemm_sm_kernel<0><<<mtscum[3], 256, 0, stream>>>(hg, 512);
}